// Round 4
// baseline (2544.116 us; speedup 1.0000x reference)
//
#include <hip/hip_runtime.h>
#include <math.h>

#define NPTS 16384
#define KNB 20

// ---------------- workspace layout (bytes, all naturally 256-aligned) ----------------
static const size_t OFF_F0   = 0;                                   // N x float4
static const size_t OFF_SSQ0 = OFF_F0   + (size_t)NPTS*4*4;         // N f32
static const size_t OFF_IDX1 = OFF_SSQ0 + (size_t)NPTS*4;           // N*20 i32
static const size_t OFF_XMX1 = OFF_IDX1 + (size_t)NPTS*KNB*4;       // N*64 f32
static const size_t OFF_XMN1 = OFF_XMX1 + (size_t)NPTS*64*4;        // N*64 f32
static const size_t OFF_SUM1 = OFF_XMN1 + (size_t)NPTS*64*4;        // 128 f32 (sum,sumsq)
static const size_t OFF_X1   = OFF_SUM1 + 512;                      // N*64 f32
static const size_t OFF_SSQ1 = OFF_X1   + (size_t)NPTS*64*4;        // N f32
static const size_t OFF_IDX2 = OFF_SSQ1 + (size_t)NPTS*4;           // N*20 i32 (global idx)
static const size_t OFF_XMX2 = OFF_IDX2 + (size_t)NPTS*KNB*4;       // N*128 f32
static const size_t OFF_XMN2 = OFF_XMX2 + (size_t)NPTS*128*4;       // N*128 f32
static const size_t OFF_SUM2 = OFF_XMN2 + (size_t)NPTS*128*4;       // 256 f32
static const size_t OFF_X2   = OFF_SUM2 + 1024;                     // N*128 f32
static const size_t OFF_SUMF = OFF_X2   + (size_t)NPTS*128*4;       // 512 f32
static const size_t OFF_HPMX = OFF_SUMF + 2048;                     // 8*256 u32 (float bits)
static const size_t OFF_HPMN = OFF_HPMX + 8*256*4;                  // 8*256 u32
// knn chunk-partials ALIAS dead regions:
//  part1 (4 chunks x N x 20 float2 = 10 MB) -> OFF_XMX2 (xmx2/xmn2 written later by mlp2)
//  part2 (2 chunks x N x 20 float2 =  5 MB) -> OFF_XMX1 (xmx1/xmn1 dead after bn1apply)

// ---------------- helpers ----------------
__device__ __forceinline__ float dot4f(float4 a, float4 b) {
  return a.x*b.x + a.y*b.y + a.z*b.z + a.w*b.w;
}

// fixed-order 64-d dot: used for BOTH row norms and cross dots so that
// d(i,i) == (sq - 2*sq) + sq == 0 exactly (self always selected, like jax top_k)
__device__ __forceinline__ float dot64v(const float* a, const float4* b4) {
  float s = 0.f;
  #pragma unroll
  for (int d4 = 0; d4 < 16; ++d4) {
    float4 b = b4[d4];
    s += a[4*d4+0]*b.x + a[4*d4+1]*b.y + a[4*d4+2]*b.z + a[4*d4+3]*b.w;
  }
  return s;
}

// sorted top-K (ascending) insertion; all indices static after unroll -> stays in VGPRs
__device__ __forceinline__ void topk_insert(float (&bd)[KNB], int (&bi)[KNB], float d, int j) {
  if (d < bd[KNB-1]) {
    bd[KNB-1] = d; bi[KNB-1] = j;
    #pragma unroll
    for (int s = KNB-1; s > 0; --s) {
      if (bd[s] < bd[s-1]) {
        float td = bd[s]; bd[s] = bd[s-1]; bd[s-1] = td;
        int   ti = bi[s]; bi[s] = bi[s-1]; bi[s-1] = ti;
      }
    }
  }
}

// ---------------- init (atomic accumulators must be reset EVERY launch) ----------------
__global__ void k_init(float* sum1, float* sum2, float* sumF, unsigned* hpmx, unsigned* hpmn) {
  int t = blockIdx.x*256 + threadIdx.x;
  if (t < 128) sum1[t] = 0.f;
  if (t < 256) sum2[t] = 0.f;
  if (t < 512) sumF[t] = 0.f;
  if (t < 2048) { hpmx[t] = 0u; hpmn[t] = 0x7f800000u; }   // relu>=0 -> uint order == float order
}

// ---------------- f0 = [pos,x], ssq0 ----------------
__global__ __launch_bounds__(256) void k_f0(const float* __restrict__ pos, const float* __restrict__ x,
                                            float4* __restrict__ f0, float* __restrict__ ssq) {
  int i = blockIdx.x*256 + threadIdx.x;
  if (i >= NPTS) return;
  float4 f;
  f.x = pos[3*i+0]; f.y = pos[3*i+1]; f.z = pos[3*i+2]; f.w = x[i];
  f0[i] = f;
  ssq[i] = dot4f(f, f);
}

// ---------------- knn1: global 16384-point knn in 4-d, J-split x4 ----------------
// 64 rows x 4 column-partners per block; chunk = blockIdx>>8 scans 4096 candidates.
// Shared skip-threshold T per 4-lane group (lazily refreshed; stale T is safe:
// skipping d >= T means some partner lane already holds 20 row-elements <= d,
// and those survive into the in-kernel partner merge below).
// Per-candidate gated insert: branch is exec-false for the whole wave after
// warm-up -> s_cbranch_execz skip, no chain cost.
__global__ __launch_bounds__(256) void k_knn1(const float4* __restrict__ f0, const float* __restrict__ ssq,
                                              float2* __restrict__ part) {
  __shared__ __align__(16) float4 tf[2048];
  __shared__ float tq[2048];
  int t = threadIdx.x;
  int rowblk = blockIdx.x & 255;
  int chunk  = blockIdx.x >> 8;            // 0..3
  int row = rowblk*64 + (t>>2);
  int q = t & 3;
  float4 fi = f0[row];
  float sqi = ssq[row];
  float bd[KNB]; int bi[KNB];
  #pragma unroll
  for (int s = 0; s < KNB; ++s) { bd[s] = INFINITY; bi[s] = 0; }
  float T = INFINITY;
  for (int tile = 0; tile < 2; ++tile) {
    int base = chunk*4096 + tile*2048;
    __syncthreads();
    for (int v = t; v < 2048; v += 256) { tf[v] = f0[base+v]; tq[v] = ssq[base+v]; }
    __syncthreads();
    for (int s = 0; s < 128; ++s) {
      int jb = s*16 + q;                   // 4 candidates: jb, jb+4, jb+8, jb+12
      float d0 = (sqi - 2.f*dot4f(fi, tf[jb     ])) + tq[jb];
      float d1 = (sqi - 2.f*dot4f(fi, tf[jb +  4])) + tq[jb +  4];
      float d2 = (sqi - 2.f*dot4f(fi, tf[jb +  8])) + tq[jb +  8];
      float d3 = (sqi - 2.f*dot4f(fi, tf[jb + 12])) + tq[jb + 12];
      if (d0 < T) topk_insert(bd, bi, d0, base + jb);
      if (d1 < T) topk_insert(bd, bi, d1, base + jb + 4);
      if (d2 < T) topk_insert(bd, bi, d2, base + jb + 8);
      if (d3 < T) topk_insert(bd, bi, d3, base + jb + 12);
      if ((s & 7) == 7) {                  // lazy refresh: every 32 candidates/lane
        float w = bd[KNB-1];
        w = fminf(w, __shfl_xor(w, 1));
        w = fminf(w, __shfl_xor(w, 2));
        T = w;
      }
    }
  }
  // merge the 4 column-partners of this row IN-KERNEL (round-3 bug: all 4
  // lanes raced on one store); lane q==0 then writes the chunk partial.
  #pragma unroll
  for (int delta = 1; delta <= 2; delta <<= 1) {
    float pd[KNB]; int pi[KNB];
    #pragma unroll
    for (int s=0;s<KNB;s++){ pd[s]=__shfl_xor(bd[s],delta); pi[s]=__shfl_xor(bi[s],delta); }
    #pragma unroll
    for (int s=0;s<KNB;s++) topk_insert(bd, bi, pd[s], pi[s]);
  }
  if (q == 0) {
    float2* p = part + ((size_t)chunk*NPTS + row)*KNB;
    #pragma unroll
    for (int s = 0; s < KNB/2; ++s)
      ((float4*)p)[s] = make_float4(bd[2*s], __int_as_float(bi[2*s]),
                                    bd[2*s+1], __int_as_float(bi[2*s+1]));
  }
}

// ---------------- merge 4 chunk-partials -> idx1 ----------------
__global__ __launch_bounds__(256) void k_merge4(const float2* __restrict__ part, int* __restrict__ idx) {
  int t = threadIdx.x;
  int row = blockIdx.x*64 + (t>>2);
  int q = t & 3;
  float bd[KNB]; int bi[KNB];
  const float4* p = (const float4*)(part + ((size_t)q*NPTS + row)*KNB);
  #pragma unroll
  for (int s = 0; s < KNB/2; ++s) {
    float4 v = p[s];
    bd[2*s] = v.x; bi[2*s] = __float_as_int(v.y);
    bd[2*s+1] = v.z; bi[2*s+1] = __float_as_int(v.w);
  }
  #pragma unroll
  for (int delta = 1; delta <= 2; delta <<= 1) {
    float pd[KNB]; int pi[KNB];
    #pragma unroll
    for (int s=0;s<KNB;s++){ pd[s]=__shfl_xor(bd[s],delta); pi[s]=__shfl_xor(bi[s],delta); }
    #pragma unroll
    for (int s=0;s<KNB;s++) topk_insert(bd, bi, pd[s], pi[s]);
  }
  if (q == 0) {
    #pragma unroll
    for (int s=0;s<KNB;s++) idx[row*KNB+s] = bi[s];
  }
}

// ---------------- merge 2 chunk-partials -> idx2 ----------------
__global__ __launch_bounds__(256) void k_merge2(const float2* __restrict__ part, int* __restrict__ idx) {
  int t = threadIdx.x;
  int row = blockIdx.x*128 + (t>>1);
  int h = t & 1;
  float bd[KNB]; int bi[KNB];
  const float4* p = (const float4*)(part + ((size_t)h*NPTS + row)*KNB);
  #pragma unroll
  for (int s = 0; s < KNB/2; ++s) {
    float4 v = p[s];
    bd[2*s] = v.x; bi[2*s] = __float_as_int(v.y);
    bd[2*s+1] = v.z; bi[2*s+1] = __float_as_int(v.w);
  }
  {
    float pd[KNB]; int pi[KNB];
    #pragma unroll
    for (int s=0;s<KNB;s++){ pd[s]=__shfl_xor(bd[s],1); pi[s]=__shfl_xor(bi[s],1); }
    #pragma unroll
    for (int s=0;s<KNB;s++) topk_insert(bd, bi, pd[s], pi[s]);
  }
  if (h == 0) {
    #pragma unroll
    for (int s=0;s<KNB;s++) idx[row*KNB+s] = bi[s];
  }
}

// ---------------- mlp1: edge MLP 8->64, relu, per-point max/min (pre-BN), channel sums ----------------
// wave per point: lane = channel
__global__ __launch_bounds__(256) void k_mlp1(const float4* __restrict__ f0, const int* __restrict__ idx1,
                                              const float* __restrict__ w1, const float* __restrict__ b1,
                                              float* __restrict__ xmx, float* __restrict__ xmn,
                                              float* __restrict__ sums) {
  __shared__ float rs[256], rs2[256];
  int t = threadIdx.x;
  int c = t & 63;
  int w = t >> 6;
  float wc[8];
  #pragma unroll
  for (int d = 0; d < 8; ++d) wc[d] = w1[d*64 + c];
  float bc = b1[c];
  float s = 0.f, s2 = 0.f;
  for (int p = 0; p < 8; ++p) {
    int i = blockIdx.x*32 + p*4 + w;
    float4 fi = f0[i];
    float mx = -INFINITY, mn = INFINITY;
    #pragma unroll
    for (int k = 0; k < KNB; ++k) {
      int j = idx1[i*KNB + k];
      float4 fj = f0[j];
      float h = bc + fi.x*wc[0] + fi.y*wc[1] + fi.z*wc[2] + fi.w*wc[3]
                   + (fj.x-fi.x)*wc[4] + (fj.y-fi.y)*wc[5] + (fj.z-fi.z)*wc[6] + (fj.w-fi.w)*wc[7];
      h = fmaxf(h, 0.f);
      mx = fmaxf(mx, h); mn = fminf(mn, h);
      s += h; s2 += h*h;
    }
    xmx[i*64+c] = mx; xmn[i*64+c] = mn;
  }
  rs[t] = s; rs2[t] = s2;
  __syncthreads();
  if (t < 64) {
    atomicAdd(&sums[c],      rs[t]+rs[t+64]+rs[t+128]+rs[t+192]);
    atomicAdd(&sums[64+c],   rs2[t]+rs2[t+64]+rs2[t+128]+rs2[t+192]);
  }
}

// ---------------- bn1 apply: x1 = affine(max or min by scale sign) ----------------
__global__ __launch_bounds__(256) void k_bn1apply(const float* __restrict__ sums, const float* __restrict__ g,
                                                  const float* __restrict__ be, const float* __restrict__ xmx,
                                                  const float* __restrict__ xmn, float* __restrict__ x1) {
  __shared__ float sc_s[64], sh_s[64];
  int t = threadIdx.x;
  if (t < 64) {
    float m = sums[t] * (1.f/327680.f);
    float v = sums[64+t] * (1.f/327680.f) - m*m;
    float sc = g[t] / sqrtf(v + 1e-5f);
    sc_s[t] = sc; sh_s[t] = be[t] - m*sc;
  }
  __syncthreads();
  int c = t & 63;
  int i = blockIdx.x*4 + (t>>6);
  float sc = sc_s[c], sh = sh_s[c];
  float val = (sc >= 0.f) ? xmx[i*64+c] : xmn[i*64+c];
  x1[i*64+c] = sc*val + sh;
}

// ---------------- ssq1 (same dot64v ordering as knn2 for exact self-distance) ----------------
__global__ __launch_bounds__(256) void k_ssq1(const float* __restrict__ x1, float* __restrict__ ssq1) {
  int i = blockIdx.x*256 + threadIdx.x;
  alignas(16) float f[64];
  #pragma unroll
  for (int d4 = 0; d4 < 16; ++d4) ((float4*)f)[d4] = ((const float4*)x1)[i*16 + d4];
  ssq1[i] = dot64v(f, (const float4*)f);
}

// ---------------- knn2: per-batch knn over 2048 points in 64-d, J-split x2 ----------------
// 64 rows x 4 partners per block; chunk = blockIdx>>8 scans 1024 candidates.
__global__ __launch_bounds__(256) void k_knn2(const float* __restrict__ x1, const float* __restrict__ ssq1,
                                              float2* __restrict__ part) {
  __shared__ __align__(16) float tf[128][68];   // pad 68 -> row+1 shifts banks by 4 -> conflict-free
  __shared__ float tq[128];
  int t = threadIdx.x;
  int rowblk = blockIdx.x & 255;
  int chunk  = blockIdx.x >> 8;            // 0..1
  int row = rowblk*64 + (t>>2);
  int q = t & 3;
  int cbase = ((row >> 11) << 11) + chunk*1024;  // batch column base + chunk offset
  alignas(16) float fi[64];
  #pragma unroll
  for (int d4 = 0; d4 < 16; ++d4) ((float4*)fi)[d4] = ((const float4*)x1)[row*16 + d4];
  float sqi = ssq1[row];
  float bd[KNB]; int bi[KNB];
  #pragma unroll
  for (int s = 0; s < KNB; ++s) { bd[s] = INFINITY; bi[s] = 0; }
  float T = INFINITY;
  for (int tile = 0; tile < 8; ++tile) {
    int base = cbase + tile*128;
    __syncthreads();
    for (int v = t; v < 128*16; v += 256) {
      int jl = v >> 4, d4 = v & 15;
      *(float4*)&tf[jl][d4*4] = ((const float4*)x1)[(base+jl)*16 + d4];
    }
    if (t < 128) tq[t] = ssq1[base + t];
    __syncthreads();
    for (int s = 0; s < 8; ++s) {
      int jb = s*16 + q;                   // 4 candidates: jb, jb+4, jb+8, jb+12
      float a0 = dot64v(fi, (const float4*)&tf[jb     ][0]);
      float a1 = dot64v(fi, (const float4*)&tf[jb +  4][0]);
      float a2 = dot64v(fi, (const float4*)&tf[jb +  8][0]);
      float a3 = dot64v(fi, (const float4*)&tf[jb + 12][0]);
      float d0 = (sqi - 2.f*a0) + tq[jb];
      float d1 = (sqi - 2.f*a1) + tq[jb +  4];
      float d2 = (sqi - 2.f*a2) + tq[jb +  8];
      float d3 = (sqi - 2.f*a3) + tq[jb + 12];
      if (d0 < T) topk_insert(bd, bi, d0, base + jb);
      if (d1 < T) topk_insert(bd, bi, d1, base + jb + 4);
      if (d2 < T) topk_insert(bd, bi, d2, base + jb + 8);
      if (d3 < T) topk_insert(bd, bi, d3, base + jb + 12);
      if ((s & 3) == 3) {                  // lazy refresh: every 16 candidates/lane
        float w = bd[KNB-1];
        w = fminf(w, __shfl_xor(w, 1));
        w = fminf(w, __shfl_xor(w, 2));
        T = w;
      }
    }
  }
  // in-kernel partner merge (fix of the round-3 write race), then q==0 stores
  #pragma unroll
  for (int delta = 1; delta <= 2; delta <<= 1) {
    float pd[KNB]; int pi[KNB];
    #pragma unroll
    for (int s=0;s<KNB;s++){ pd[s]=__shfl_xor(bd[s],delta); pi[s]=__shfl_xor(bi[s],delta); }
    #pragma unroll
    for (int s=0;s<KNB;s++) topk_insert(bd, bi, pd[s], pi[s]);
  }
  if (q == 0) {
    float2* p = part + ((size_t)chunk*NPTS + row)*KNB;
    #pragma unroll
    for (int s = 0; s < KNB/2; ++s)
      ((float4*)p)[s] = make_float4(bd[2*s], __int_as_float(bi[2*s]),
                                    bd[2*s+1], __int_as_float(bi[2*s+1]));
  }
}

// ---------------- mlp2: edge MLP 128->128, relu, per-point max/min, channel sums ----------------
// w2 staged in LDS (64KB); per point stage 20x128 edge matrix; 256 thr = 128ch x 2 edge-halves
__global__ __launch_bounds__(256) void k_mlp2(const float* __restrict__ x1, const int* __restrict__ idx2,
                                              const float* __restrict__ w2, const float* __restrict__ b2,
                                              float* __restrict__ xmx, float* __restrict__ xmn,
                                              float* __restrict__ sums) {
  __shared__ __align__(16) float w2s[128*128];
  __shared__ __align__(16) float es[KNB*128];
  __shared__ float red[256];
  __shared__ int js[KNB];
  int t = threadIdx.x;
  for (int v = t; v < 128*32; v += 256) ((float4*)w2s)[v] = ((const float4*)w2)[v];
  int c = t & 127, half = t >> 7;
  float bc = b2[c];
  float s = 0.f, s2 = 0.f;
  for (int p = 0; p < 32; ++p) {
    int i = blockIdx.x*32 + p;
    __syncthreads();                              // protects es/red reuse; first iter: w2s ready after next sync
    if (t < KNB) js[t] = idx2[i*KNB + t];
    __syncthreads();
    for (int v = t; v < KNB*32; v += 256) {       // 640 float4 = 20 edges x 32
      int k = v >> 5, d4 = v & 31;
      int j = js[k];
      float4 e;
      if (d4 < 16) {
        e = ((const float4*)x1)[i*16 + d4];
      } else {
        float4 a  = ((const float4*)x1)[j*16 + (d4-16)];
        float4 xi = ((const float4*)x1)[i*16 + (d4-16)];
        e = make_float4(a.x-xi.x, a.y-xi.y, a.z-xi.z, a.w-xi.w);
      }
      ((float4*)es)[v] = e;
    }
    __syncthreads();
    float acc[10];
    #pragma unroll
    for (int k = 0; k < 10; ++k) acc[k] = 0.f;
    int kbase = half*10;
    for (int d4 = 0; d4 < 32; ++d4) {
      float w0 = w2s[(d4*4+0)*128 + c];
      float w1v = w2s[(d4*4+1)*128 + c];
      float w2v = w2s[(d4*4+2)*128 + c];
      float w3 = w2s[(d4*4+3)*128 + c];
      #pragma unroll
      for (int k = 0; k < 10; ++k) {
        float4 e = ((const float4*)es)[(kbase+k)*32 + d4];   // wave-uniform addr -> broadcast
        acc[k] += e.x*w0 + e.y*w1v + e.z*w2v + e.w*w3;
      }
    }
    float mx = -INFINITY, mn = INFINITY;
    #pragma unroll
    for (int k = 0; k < 10; ++k) {
      float h = fmaxf(acc[k] + bc, 0.f);
      mx = fmaxf(mx, h); mn = fminf(mn, h);
      s += h; s2 += h*h;
    }
    red[t] = mx; __syncthreads();
    float omx = fmaxf(mx, red[c+128]);
    __syncthreads();
    red[t] = mn; __syncthreads();
    if (half == 0) {
      xmx[i*128+c] = omx;
      xmn[i*128+c] = fminf(mn, red[c+128]);
    }
  }
  __syncthreads();
  red[t] = s; __syncthreads();
  if (half == 0) atomicAdd(&sums[c], s + red[c+128]);
  __syncthreads();
  red[t] = s2; __syncthreads();
  if (half == 0) atomicAdd(&sums[128+c], s2 + red[c+128]);
}

// ---------------- bn2 apply ----------------
__global__ __launch_bounds__(256) void k_bn2apply(const float* __restrict__ sums, const float* __restrict__ g,
                                                  const float* __restrict__ be, const float* __restrict__ xmx,
                                                  const float* __restrict__ xmn, float* __restrict__ x2) {
  __shared__ float sc_s[128], sh_s[128];
  int t = threadIdx.x;
  if (t < 128) {
    float m = sums[t] * (1.f/327680.f);
    float v = sums[128+t] * (1.f/327680.f) - m*m;
    float sc = g[t] / sqrtf(v + 1e-5f);
    sc_s[t] = sc; sh_s[t] = be[t] - m*sc;
  }
  __syncthreads();
  int c = t & 127;
  int i = blockIdx.x*2 + (t>>7);
  float sc = sc_s[c], sh = sh_s[c];
  float val = (sc >= 0.f) ? xmx[i*128+c] : xmn[i*128+c];
  x2[i*128+c] = sc*val + sh;
}

// ---------------- gemmF: relu([x1|x2] @ wf + bf); channel sums + per-batch max/min only ----------------
// tiles: 64 rows x 64 cols, K=192 fully staged
__global__ __launch_bounds__(256) void k_gemmF(const float* __restrict__ x1, const float* __restrict__ x2,
                                               const float* __restrict__ wf, const float* __restrict__ bf,
                                               float* __restrict__ sumsF, unsigned* __restrict__ hpmx,
                                               unsigned* __restrict__ hpmn) {
  __shared__ float A_s[64*193];                  // pad 193 -> 2-way (free) reads
  __shared__ __align__(16) float B_s[192*64];
  __shared__ float red[1024];
  int t = threadIdx.x;
  int rt = blockIdx.x >> 2;
  int ct = blockIdx.x & 3;
  for (int v = t; v < 64*48; v += 256) {
    int r = v / 48, gg = v - r*48;
    int row = rt*64 + r;
    float4 e = (gg < 16) ? ((const float4*)x1)[row*16 + gg]
                         : ((const float4*)x2)[row*32 + (gg-16)];
    float* p = &A_s[r*193 + gg*4];
    p[0]=e.x; p[1]=e.y; p[2]=e.z; p[3]=e.w;
  }
  for (int v = t; v < 192*16; v += 256) {
    int d = v >> 4, c4 = v & 15;
    *(float4*)&B_s[d*64 + c4*4] = ((const float4*)wf)[d*64 + ct*16 + c4];
  }
  __syncthreads();
  int rg = t & 15, cg = t >> 4;
  float acc[4][4];
  #pragma unroll
  for (int a=0;a<4;a++) { acc[a][0]=0.f; acc[a][1]=0.f; acc[a][2]=0.f; acc[a][3]=0.f; }
  for (int d = 0; d < 192; ++d) {
    float a0 = A_s[(rg*4+0)*193 + d];
    float a1 = A_s[(rg*4+1)*193 + d];
    float a2 = A_s[(rg*4+2)*193 + d];
    float a3 = A_s[(rg*4+3)*193 + d];
    float b0 = B_s[d*64 + cg];
    float b1 = B_s[d*64 + cg + 16];
    float b2 = B_s[d*64 + cg + 32];
    float b3 = B_s[d*64 + cg + 48];
    acc[0][0]+=a0*b0; acc[0][1]+=a0*b1; acc[0][2]+=a0*b2; acc[0][3]+=a0*b3;
    acc[1][0]+=a1*b0; acc[1][1]+=a1*b1; acc[1][2]+=a1*b2; acc[1][3]+=a1*b3;
    acc[2][0]+=a2*b0; acc[2][1]+=a2*b1; acc[2][2]+=a2*b2; acc[2][3]+=a2*b3;
    acc[3][0]+=a3*b0; acc[3][1]+=a3*b1; acc[3][2]+=a3*b2; acc[3][3]+=a3*b3;
  }
  float hv[4][4];
  #pragma unroll
  for (int ss=0; ss<4; ++ss) {
    float bb = bf[ct*64 + cg + ss*16];
    #pragma unroll
    for (int rr=0; rr<4; ++rr) hv[rr][ss] = fmaxf(acc[rr][ss] + bb, 0.f);
  }
  int b = rt >> 5;
  // sum
  #pragma unroll
  for (int ss=0; ss<4; ++ss) red[rg*64 + cg + ss*16] = hv[0][ss]+hv[1][ss]+hv[2][ss]+hv[3][ss];
  __syncthreads();
  if (t < 64) {
    float v = 0.f;
    #pragma unroll
    for (int r=0;r<16;r++) v += red[r*64 + t];
    atomicAdd(&sumsF[ct*64 + t], v);
  }
  __syncthreads();
  // sumsq
  #pragma unroll
  for (int ss=0; ss<4; ++ss) red[rg*64 + cg + ss*16] =
      hv[0][ss]*hv[0][ss]+hv[1][ss]*hv[1][ss]+hv[2][ss]*hv[2][ss]+hv[3][ss]*hv[3][ss];
  __syncthreads();
  if (t < 64) {
    float v = 0.f;
    #pragma unroll
    for (int r=0;r<16;r++) v += red[r*64 + t];
    atomicAdd(&sumsF[256 + ct*64 + t], v);
  }
  __syncthreads();
  // max
  #pragma unroll
  for (int ss=0; ss<4; ++ss) red[rg*64 + cg + ss*16] =
      fmaxf(fmaxf(hv[0][ss],hv[1][ss]), fmaxf(hv[2][ss],hv[3][ss]));
  __syncthreads();
  if (t < 64) {
    float v = -INFINITY;
    #pragma unroll
    for (int r=0;r<16;r++) v = fmaxf(v, red[r*64 + t]);
    atomicMax(&hpmx[b*256 + ct*64 + t], __float_as_uint(v));
  }
  __syncthreads();
  // min
  #pragma unroll
  for (int ss=0; ss<4; ++ss) red[rg*64 + cg + ss*16] =
      fminf(fminf(hv[0][ss],hv[1][ss]), fminf(hv[2][ss],hv[3][ss]));
  __syncthreads();
  if (t < 64) {
    float v = INFINITY;
    #pragma unroll
    for (int r=0;r<16;r++) v = fminf(v, red[r*64 + t]);
    atomicMin(&hpmn[b*256 + ct*64 + t], __float_as_uint(v));
  }
}

// ---------------- head: BNf apply on pooled max/min, 3 small MLPs + BN(8), log_softmax ----------------
__global__ __launch_bounds__(256) void k_head(const float* __restrict__ sumsF, const float* __restrict__ gf,
                                              const float* __restrict__ bef,
                                              const unsigned* __restrict__ hpmx, const unsigned* __restrict__ hpmn,
                                              const float* __restrict__ wo1, const float* __restrict__ bo1,
                                              const float* __restrict__ go1, const float* __restrict__ beo1,
                                              const float* __restrict__ wo2, const float* __restrict__ bo2,
                                              const float* __restrict__ go2, const float* __restrict__ beo2,
                                              const float* __restrict__ wo3, const float* __restrict__ bo3,
                                              float* __restrict__ out) {
  __shared__ float hp[8][256];
  __shared__ float u1[8][128];
  __shared__ float u2[8][64];
  __shared__ float lg[8][16];
  int t = threadIdx.x;
  {
    float m = sumsF[t] * (1.f/16384.f);
    float v = sumsF[256+t] * (1.f/16384.f) - m*m;
    float sc = gf[t] / sqrtf(v + 1e-5f);
    float sh = bef[t] - m*sc;
    for (int b = 0; b < 8; ++b) {
      unsigned bits = (sc >= 0.f) ? hpmx[b*256+t] : hpmn[b*256+t];
      hp[b][t] = sc*__uint_as_float(bits) + sh;
    }
  }
  __syncthreads();
  for (int p = t; p < 1024; p += 256) {
    int b = p >> 7, c = p & 127;
    float z = bo1[c];
    for (int d = 0; d < 256; ++d) z += hp[b][d]*wo1[d*128+c];
    u1[b][c] = fmaxf(z, 0.f);
  }
  __syncthreads();
  if (t < 128) {
    float m = 0.f;
    for (int b=0;b<8;b++) m += u1[b][t];
    m *= 0.125f;
    float v = 0.f;
    for (int b=0;b<8;b++) { float dd = u1[b][t]-m; v += dd*dd; }
    v *= 0.125f;
    float sc = go1[t]/sqrtf(v+1e-5f), sh = beo1[t]-m*sc;
    for (int b=0;b<8;b++) u1[b][t] = sc*u1[b][t]+sh;
  }
  __syncthreads();
  for (int p = t; p < 512; p += 256) {
    int b = p >> 6, c = p & 63;
    float z = bo2[c];
    for (int d = 0; d < 128; ++d) z += u1[b][d]*wo2[d*64+c];
    u2[b][c] = fmaxf(z, 0.f);
  }
  __syncthreads();
  if (t < 64) {
    float m = 0.f;
    for (int b=0;b<8;b++) m += u2[b][t];
    m *= 0.125f;
    float v = 0.f;
    for (int b=0;b<8;b++) { float dd = u2[b][t]-m; v += dd*dd; }
    v *= 0.125f;
    float sc = go2[t]/sqrtf(v+1e-5f), sh = beo2[t]-m*sc;
    for (int b=0;b<8;b++) u2[b][t] = sc*u2[b][t]+sh;
  }
  __syncthreads();
  if (t < 128) {
    int b = t >> 4, c = t & 15;
    float z = bo3[c];
    for (int d = 0; d < 64; ++d) z += u2[b][d]*wo3[d*16+c];
    lg[b][c] = z;
  }
  __syncthreads();
  if (t < 8) {
    float m = -INFINITY;
    for (int j=0;j<16;j++) m = fmaxf(m, lg[t][j]);
    float s = 0.f;
    for (int j=0;j<16;j++) s += expf(lg[t][j]-m);
    float ls = logf(s);
    for (int j=0;j<16;j++) out[t*16+j] = (lg[t][j]-m) - ls;
  }
}

// ---------------- launch ----------------
extern "C" void kernel_launch(void* const* d_in, const int* in_sizes, int n_in,
                              void* d_out, int out_size, void* d_ws, size_t ws_size,
                              hipStream_t stream) {
  (void)in_sizes; (void)n_in; (void)out_size; (void)ws_size;
  const float* pos = (const float*)d_in[0];
  const float* x   = (const float*)d_in[1];
  const float* w1  = (const float*)d_in[3];
  const float* b1  = (const float*)d_in[4];
  const float* g1  = (const float*)d_in[5];
  const float* be1 = (const float*)d_in[6];
  const float* w2  = (const float*)d_in[7];
  const float* b2  = (const float*)d_in[8];
  const float* g2  = (const float*)d_in[9];
  const float* be2 = (const float*)d_in[10];
  const float* wf  = (const float*)d_in[11];
  const float* bf  = (const float*)d_in[12];
  const float* gf  = (const float*)d_in[13];
  const float* bef = (const float*)d_in[14];
  const float* wo1 = (const float*)d_in[15];
  const float* bo1 = (const float*)d_in[16];
  const float* go1 = (const float*)d_in[17];
  const float* beo1= (const float*)d_in[18];
  const float* wo2 = (const float*)d_in[19];
  const float* bo2 = (const float*)d_in[20];
  const float* go2 = (const float*)d_in[21];
  const float* beo2= (const float*)d_in[22];
  const float* wo3 = (const float*)d_in[23];
  const float* bo3 = (const float*)d_in[24];

  char* ws = (char*)d_ws;
  float4*   f0    = (float4*)  (ws + OFF_F0);
  float*    ssq0  = (float*)   (ws + OFF_SSQ0);
  int*      idx1  = (int*)     (ws + OFF_IDX1);
  float*    xmx1  = (float*)   (ws + OFF_XMX1);
  float*    xmn1  = (float*)   (ws + OFF_XMN1);
  float*    sum1  = (float*)   (ws + OFF_SUM1);
  float*    x1    = (float*)   (ws + OFF_X1);
  float*    ssq1  = (float*)   (ws + OFF_SSQ1);
  int*      idx2  = (int*)     (ws + OFF_IDX2);
  float*    xmx2  = (float*)   (ws + OFF_XMX2);
  float*    xmn2  = (float*)   (ws + OFF_XMN2);
  float*    sum2  = (float*)   (ws + OFF_SUM2);
  float*    x2    = (float*)   (ws + OFF_X2);
  float*    sumF  = (float*)   (ws + OFF_SUMF);
  unsigned* hpmx  = (unsigned*)(ws + OFF_HPMX);
  unsigned* hpmn  = (unsigned*)(ws + OFF_HPMN);
  float2*   part1 = (float2*)  (ws + OFF_XMX2);   // dead until mlp2 writes xmx2/xmn2
  float2*   part2 = (float2*)  (ws + OFF_XMX1);   // dead after bn1apply

  k_init    <<<8,    256, 0, stream>>>(sum1, sum2, sumF, hpmx, hpmn);
  k_f0      <<<64,   256, 0, stream>>>(pos, x, f0, ssq0);
  k_knn1    <<<1024, 256, 0, stream>>>(f0, ssq0, part1);
  k_merge4  <<<256,  256, 0, stream>>>(part1, idx1);
  k_mlp1    <<<512,  256, 0, stream>>>(f0, idx1, w1, b1, xmx1, xmn1, sum1);
  k_bn1apply<<<4096, 256, 0, stream>>>(sum1, g1, be1, xmx1, xmn1, x1);
  k_ssq1    <<<64,   256, 0, stream>>>(x1, ssq1);
  k_knn2    <<<512,  256, 0, stream>>>(x1, ssq1, part2);
  k_merge2  <<<128,  256, 0, stream>>>(part2, idx2);
  k_mlp2    <<<512,  256, 0, stream>>>(x1, idx2, w2, b2, xmx2, xmn2, sum2);
  k_bn2apply<<<8192, 256, 0, stream>>>(sum2, g2, be2, xmx2, xmn2, x2);
  k_gemmF   <<<1024, 256, 0, stream>>>(x1, x2, wf, bf, sumF, hpmx, hpmn);
  k_head    <<<1,    256, 0, stream>>>(sumF, gf, bef, hpmx, hpmn,
                                       wo1, bo1, go1, beo1, wo2, bo2, go2, beo2, wo3, bo3,
                                       (float*)d_out);
}

// Round 5
// 1246.813 us; speedup vs baseline: 2.0405x; 2.0405x over previous
//
#include <hip/hip_runtime.h>
#include <math.h>

#define NPTS 16384
#define KNB 20

// ---------------- workspace layout (bytes, all naturally 256-aligned) ----------------
static const size_t OFF_F0   = 0;                                   // N x float4
static const size_t OFF_SSQ0 = OFF_F0   + (size_t)NPTS*4*4;         // N f32
static const size_t OFF_IDX1 = OFF_SSQ0 + (size_t)NPTS*4;           // N*20 i32
static const size_t OFF_XMX1 = OFF_IDX1 + (size_t)NPTS*KNB*4;       // N*64 f32
static const size_t OFF_XMN1 = OFF_XMX1 + (size_t)NPTS*64*4;        // N*64 f32
static const size_t OFF_SUM1 = OFF_XMN1 + (size_t)NPTS*64*4;        // 128 f32 (sum,sumsq)
static const size_t OFF_X1   = OFF_SUM1 + 512;                      // N*64 f32
static const size_t OFF_SSQ1 = OFF_X1   + (size_t)NPTS*64*4;        // N f32
static const size_t OFF_IDX2 = OFF_SSQ1 + (size_t)NPTS*4;           // N*20 i32 (global idx)
static const size_t OFF_XMX2 = OFF_IDX2 + (size_t)NPTS*KNB*4;       // N*128 f32
static const size_t OFF_XMN2 = OFF_XMX2 + (size_t)NPTS*128*4;       // N*128 f32
static const size_t OFF_SUM2 = OFF_XMN2 + (size_t)NPTS*128*4;       // 256 f32
static const size_t OFF_X2   = OFF_SUM2 + 1024;                     // N*128 f32
static const size_t OFF_SUMF = OFF_X2   + (size_t)NPTS*128*4;       // 512 f32
static const size_t OFF_HPMX = OFF_SUMF + 2048;                     // 8*256 u32 (float bits)
static const size_t OFF_HPMN = OFF_HPMX + 8*256*4;                  // 8*256 u32

// ---------------- helpers ----------------
__device__ __forceinline__ float dot4f(float4 a, float4 b) {
  return a.x*b.x + a.y*b.y + a.z*b.z + a.w*b.w;
}

// fixed-order 64-d dot: used for BOTH row norms and cross dots so that
// d(i,i) == (sq - 2*sq) + sq == 0 exactly (self always selected, like jax top_k)
__device__ __forceinline__ float dot64v(const float* a, const float4* b4) {
  float s = 0.f;
  #pragma unroll
  for (int d4 = 0; d4 < 16; ++d4) {
    float4 b = b4[d4];
    s += a[4*d4+0]*b.x + a[4*d4+1]*b.y + a[4*d4+2]*b.z + a[4*d4+3]*b.w;
  }
  return s;
}

// ---------------- branch-free sorting-network top-k machinery ----------------
// compare-exchange: after call, (a,ai) <= (b,bi) by distance
__device__ __forceinline__ void ce(float& a, int& ai, float& b, int& bi) {
  bool sw = b < a;
  float d0 = sw ? b : a;  float d1 = sw ? a : b;
  int   j0 = sw ? bi : ai; int  j1 = sw ? ai : bi;
  a = d0; ai = j0; b = d1; bi = j1;
}

// bitonic sort of 16 (d,idx) pairs, ascending; all indices static after unroll
__device__ __forceinline__ void sort16(float (&d)[16], int (&ix)[16]) {
  #pragma unroll
  for (int k = 2; k <= 16; k <<= 1) {
    #pragma unroll
    for (int j = k >> 1; j > 0; j >>= 1) {
      #pragma unroll
      for (int i = 0; i < 16; ++i) {
        int l = i ^ j;
        if (l > i) {
          if ((i & k) == 0) ce(d[i], ix[i], d[l], ix[l]);
          else              ce(d[l], ix[l], d[i], ix[i]);
        }
      }
    }
  }
}

// bitonic -> ascending cleanup for 32 elements
__device__ __forceinline__ void bimerge32(float (&rd)[32], int (&ri)[32]) {
  #pragma unroll
  for (int j = 16; j > 0; j >>= 1) {
    #pragma unroll
    for (int i = 0; i < 32; ++i) {
      int l = i ^ j;
      if (l > i) ce(rd[i], ri[i], rd[l], ri[l]);
    }
  }
}

// merge sorted-16 batch into sorted-32 running list, keep smallest 32.
// classic: concat run ++ rev(batch padded to 32 w/ inf) is bitonic; the split
// CE(run[16+k], batch[15-k]) leaves run[] bitonic containing the 32 smallest.
__device__ __forceinline__ void merge16(float (&rd)[32], int (&ri)[32],
                                        float (&bd)[16], int (&bi)[16]) {
  #pragma unroll
  for (int k = 0; k < 16; ++k) {
    bool sw = bd[15-k] < rd[16+k];
    rd[16+k] = sw ? bd[15-k] : rd[16+k];
    ri[16+k] = sw ? bi[15-k] : ri[16+k];
  }
  bimerge32(rd, ri);
}

// butterfly cross-lane merge: both partners compute identical union-top-32
__device__ __forceinline__ void mergelane(float (&rd)[32], int (&ri)[32], int mask) {
  float pd[32]; int pi[32];
  #pragma unroll
  for (int s = 0; s < 32; ++s) { pd[s] = __shfl_xor(rd[s], mask); pi[s] = __shfl_xor(ri[s], mask); }
  #pragma unroll
  for (int k = 0; k < 32; ++k) {
    bool sw = pd[31-k] < rd[k];
    rd[k] = sw ? pd[31-k] : rd[k];
    ri[k] = sw ? pi[31-k] : ri[k];
  }
  bimerge32(rd, ri);
}

// ---------------- init (atomic accumulators must be reset EVERY launch) ----------------
__global__ void k_init(float* sum1, float* sum2, float* sumF, unsigned* hpmx, unsigned* hpmn) {
  int t = blockIdx.x*256 + threadIdx.x;
  if (t < 128) sum1[t] = 0.f;
  if (t < 256) sum2[t] = 0.f;
  if (t < 512) sumF[t] = 0.f;
  if (t < 2048) { hpmx[t] = 0u; hpmn[t] = 0x7f800000u; }   // relu>=0 -> uint order == float order
}

// ---------------- f0 = [pos,x], ssq0 ----------------
__global__ __launch_bounds__(256) void k_f0(const float* __restrict__ pos, const float* __restrict__ x,
                                            float4* __restrict__ f0, float* __restrict__ ssq) {
  int i = blockIdx.x*256 + threadIdx.x;
  if (i >= NPTS) return;
  float4 f;
  f.x = pos[3*i+0]; f.y = pos[3*i+1]; f.z = pos[3*i+2]; f.w = x[i];
  f0[i] = f;
  ssq[i] = dot4f(f, f);
}

// ---------------- knn1: global 16384-point knn in 4-d ----------------
// 16 rows/block x 16 lanes/row, grid 1024. Branch-free: each lane keeps a
// sorted-32 register list; candidates in batches of 16 via bitonic networks.
// NO data-dependent branches -> no wave-OR serialization (R1-R4 bottleneck).
__global__ __launch_bounds__(256) void k_knn1(const float4* __restrict__ f0, const float* __restrict__ ssq,
                                              int* __restrict__ idx1) {
  __shared__ __align__(16) float4 tf[1024];
  __shared__ float tq[1024];
  int t = threadIdx.x;
  int row = blockIdx.x*16 + (t>>4);
  int lane = t & 15;
  float4 fi = f0[row];
  float sqi = ssq[row];
  float rd[32]; int ri[32];
  #pragma unroll
  for (int s = 0; s < 32; ++s) { rd[s] = INFINITY; ri[s] = 0; }
  for (int tile = 0; tile < 16; ++tile) {
    int base = tile*1024;
    __syncthreads();
    #pragma unroll
    for (int v = 0; v < 4; ++v) {
      tf[t + v*256] = f0[base + t + v*256];
      tq[t + v*256] = ssq[base + t + v*256];
    }
    __syncthreads();
    #pragma unroll
    for (int b = 0; b < 4; ++b) {
      float bd[16]; int bix[16];
      #pragma unroll
      for (int u = 0; u < 16; ++u) {
        int jl = b*256 + u*16 + lane;
        bd[u] = (sqi - 2.f*dot4f(fi, tf[jl])) + tq[jl];
        bix[u] = base + jl;
      }
      sort16(bd, bix);
      merge16(rd, ri, bd, bix);
    }
  }
  mergelane(rd, ri, 1);
  mergelane(rd, ri, 2);
  mergelane(rd, ri, 4);
  mergelane(rd, ri, 8);
  if (lane == 0) {
    int4* p = (int4*)&idx1[row*KNB];
    p[0] = make_int4(ri[0],ri[1],ri[2],ri[3]);
    p[1] = make_int4(ri[4],ri[5],ri[6],ri[7]);
    p[2] = make_int4(ri[8],ri[9],ri[10],ri[11]);
    p[3] = make_int4(ri[12],ri[13],ri[14],ri[15]);
    p[4] = make_int4(ri[16],ri[17],ri[18],ri[19]);
  }
}

// ---------------- mlp1: edge MLP 8->64, relu, per-point max/min (pre-BN), channel sums ----------------
__global__ __launch_bounds__(256) void k_mlp1(const float4* __restrict__ f0, const int* __restrict__ idx1,
                                              const float* __restrict__ w1, const float* __restrict__ b1,
                                              float* __restrict__ xmx, float* __restrict__ xmn,
                                              float* __restrict__ sums) {
  __shared__ float rs[256], rs2[256];
  int t = threadIdx.x;
  int c = t & 63;
  int w = t >> 6;
  float wc[8];
  #pragma unroll
  for (int d = 0; d < 8; ++d) wc[d] = w1[d*64 + c];
  float bc = b1[c];
  float s = 0.f, s2 = 0.f;
  for (int p = 0; p < 8; ++p) {
    int i = blockIdx.x*32 + p*4 + w;
    float4 fi = f0[i];
    float mx = -INFINITY, mn = INFINITY;
    #pragma unroll
    for (int k = 0; k < KNB; ++k) {
      int j = idx1[i*KNB + k];
      float4 fj = f0[j];
      float h = bc + fi.x*wc[0] + fi.y*wc[1] + fi.z*wc[2] + fi.w*wc[3]
                   + (fj.x-fi.x)*wc[4] + (fj.y-fi.y)*wc[5] + (fj.z-fi.z)*wc[6] + (fj.w-fi.w)*wc[7];
      h = fmaxf(h, 0.f);
      mx = fmaxf(mx, h); mn = fminf(mn, h);
      s += h; s2 += h*h;
    }
    xmx[i*64+c] = mx; xmn[i*64+c] = mn;
  }
  rs[t] = s; rs2[t] = s2;
  __syncthreads();
  if (t < 64) {
    atomicAdd(&sums[c],      rs[t]+rs[t+64]+rs[t+128]+rs[t+192]);
    atomicAdd(&sums[64+c],   rs2[t]+rs2[t+64]+rs2[t+128]+rs2[t+192]);
  }
}

// ---------------- bn1 apply: x1 = affine(max or min by scale sign) ----------------
__global__ __launch_bounds__(256) void k_bn1apply(const float* __restrict__ sums, const float* __restrict__ g,
                                                  const float* __restrict__ be, const float* __restrict__ xmx,
                                                  const float* __restrict__ xmn, float* __restrict__ x1) {
  __shared__ float sc_s[64], sh_s[64];
  int t = threadIdx.x;
  if (t < 64) {
    float m = sums[t] * (1.f/327680.f);
    float v = sums[64+t] * (1.f/327680.f) - m*m;
    float sc = g[t] / sqrtf(v + 1e-5f);
    sc_s[t] = sc; sh_s[t] = be[t] - m*sc;
  }
  __syncthreads();
  int c = t & 63;
  int i = blockIdx.x*4 + (t>>6);
  float sc = sc_s[c], sh = sh_s[c];
  float val = (sc >= 0.f) ? xmx[i*64+c] : xmn[i*64+c];
  x1[i*64+c] = sc*val + sh;
}

// ---------------- ssq1 (same dot64v ordering as knn2 for exact self-distance) ----------------
__global__ __launch_bounds__(256) void k_ssq1(const float* __restrict__ x1, float* __restrict__ ssq1) {
  int i = blockIdx.x*256 + threadIdx.x;
  alignas(16) float f[64];
  #pragma unroll
  for (int d4 = 0; d4 < 16; ++d4) ((float4*)f)[d4] = ((const float4*)x1)[i*16 + d4];
  ssq1[i] = dot64v(f, (const float4*)f);
}

// ---------------- knn2: per-batch knn over 2048 points in 64-d ----------------
// 32 rows/block x 8 lanes/row, grid 512; one 16-batch per 128-candidate tile.
__global__ __launch_bounds__(256) void k_knn2(const float* __restrict__ x1, const float* __restrict__ ssq1,
                                              int* __restrict__ idx2) {
  __shared__ __align__(16) float tf[128][68];   // pad 68 -> conflict-light reads
  __shared__ float tq[128];
  int t = threadIdx.x;
  int row = blockIdx.x*32 + (t>>3);
  int lane = t & 7;
  int cbase = (row >> 11) << 11;                // batch column base
  alignas(16) float fi[64];
  #pragma unroll
  for (int d4 = 0; d4 < 16; ++d4) ((float4*)fi)[d4] = ((const float4*)x1)[row*16 + d4];
  float sqi = ssq1[row];
  float rd[32]; int ri[32];
  #pragma unroll
  for (int s = 0; s < 32; ++s) { rd[s] = INFINITY; ri[s] = 0; }
  for (int tile = 0; tile < 16; ++tile) {
    int base = cbase + tile*128;
    __syncthreads();
    for (int v = t; v < 128*16; v += 256) {
      int jl = v >> 4, d4 = v & 15;
      *(float4*)&tf[jl][d4*4] = ((const float4*)x1)[(base+jl)*16 + d4];
    }
    if (t < 128) tq[t] = ssq1[base + t];
    __syncthreads();
    float bd[16]; int bix[16];
    #pragma unroll
    for (int u = 0; u < 16; ++u) {
      int jl = u*8 + lane;
      bd[u] = (sqi - 2.f*dot64v(fi, (const float4*)&tf[jl][0])) + tq[jl];
      bix[u] = base + jl;
    }
    sort16(bd, bix);
    merge16(rd, ri, bd, bix);
  }
  mergelane(rd, ri, 1);
  mergelane(rd, ri, 2);
  mergelane(rd, ri, 4);
  if (lane == 0) {
    int4* p = (int4*)&idx2[row*KNB];
    p[0] = make_int4(ri[0],ri[1],ri[2],ri[3]);
    p[1] = make_int4(ri[4],ri[5],ri[6],ri[7]);
    p[2] = make_int4(ri[8],ri[9],ri[10],ri[11]);
    p[3] = make_int4(ri[12],ri[13],ri[14],ri[15]);
    p[4] = make_int4(ri[16],ri[17],ri[18],ri[19]);
  }
}

// ---------------- mlp2: edge MLP 128->128, relu, per-point max/min, channel sums ----------------
__global__ __launch_bounds__(256) void k_mlp2(const float* __restrict__ x1, const int* __restrict__ idx2,
                                              const float* __restrict__ w2, const float* __restrict__ b2,
                                              float* __restrict__ xmx, float* __restrict__ xmn,
                                              float* __restrict__ sums) {
  __shared__ __align__(16) float w2s[128*128];
  __shared__ __align__(16) float es[KNB*128];
  __shared__ float red[256];
  __shared__ int js[KNB];
  int t = threadIdx.x;
  for (int v = t; v < 128*32; v += 256) ((float4*)w2s)[v] = ((const float4*)w2)[v];
  int c = t & 127, half = t >> 7;
  float bc = b2[c];
  float s = 0.f, s2 = 0.f;
  for (int p = 0; p < 32; ++p) {
    int i = blockIdx.x*32 + p;
    __syncthreads();
    if (t < KNB) js[t] = idx2[i*KNB + t];
    __syncthreads();
    for (int v = t; v < KNB*32; v += 256) {
      int k = v >> 5, d4 = v & 31;
      int j = js[k];
      float4 e;
      if (d4 < 16) {
        e = ((const float4*)x1)[i*16 + d4];
      } else {
        float4 a  = ((const float4*)x1)[j*16 + (d4-16)];
        float4 xi = ((const float4*)x1)[i*16 + (d4-16)];
        e = make_float4(a.x-xi.x, a.y-xi.y, a.z-xi.z, a.w-xi.w);
      }
      ((float4*)es)[v] = e;
    }
    __syncthreads();
    float acc[10];
    #pragma unroll
    for (int k = 0; k < 10; ++k) acc[k] = 0.f;
    int kbase = half*10;
    for (int d4 = 0; d4 < 32; ++d4) {
      float w0 = w2s[(d4*4+0)*128 + c];
      float w1v = w2s[(d4*4+1)*128 + c];
      float w2v = w2s[(d4*4+2)*128 + c];
      float w3 = w2s[(d4*4+3)*128 + c];
      #pragma unroll
      for (int k = 0; k < 10; ++k) {
        float4 e = ((const float4*)es)[(kbase+k)*32 + d4];
        acc[k] += e.x*w0 + e.y*w1v + e.z*w2v + e.w*w3;
      }
    }
    float mx = -INFINITY, mn = INFINITY;
    #pragma unroll
    for (int k = 0; k < 10; ++k) {
      float h = fmaxf(acc[k] + bc, 0.f);
      mx = fmaxf(mx, h); mn = fminf(mn, h);
      s += h; s2 += h*h;
    }
    red[t] = mx; __syncthreads();
    float omx = fmaxf(mx, red[c+128]);
    __syncthreads();
    red[t] = mn; __syncthreads();
    if (half == 0) {
      xmx[i*128+c] = omx;
      xmn[i*128+c] = fminf(mn, red[c+128]);
    }
  }
  __syncthreads();
  red[t] = s; __syncthreads();
  if (half == 0) atomicAdd(&sums[c], s + red[c+128]);
  __syncthreads();
  red[t] = s2; __syncthreads();
  if (half == 0) atomicAdd(&sums[128+c], s2 + red[c+128]);
}

// ---------------- bn2 apply ----------------
__global__ __launch_bounds__(256) void k_bn2apply(const float* __restrict__ sums, const float* __restrict__ g,
                                                  const float* __restrict__ be, const float* __restrict__ xmx,
                                                  const float* __restrict__ xmn, float* __restrict__ x2) {
  __shared__ float sc_s[128], sh_s[128];
  int t = threadIdx.x;
  if (t < 128) {
    float m = sums[t] * (1.f/327680.f);
    float v = sums[128+t] * (1.f/327680.f) - m*m;
    float sc = g[t] / sqrtf(v + 1e-5f);
    sc_s[t] = sc; sh_s[t] = be[t] - m*sc;
  }
  __syncthreads();
  int c = t & 127;
  int i = blockIdx.x*2 + (t>>7);
  float sc = sc_s[c], sh = sh_s[c];
  float val = (sc >= 0.f) ? xmx[i*128+c] : xmn[i*128+c];
  x2[i*128+c] = sc*val + sh;
}

// ---------------- gemmF: relu([x1|x2] @ wf + bf); channel sums + per-batch max/min only ----------------
__global__ __launch_bounds__(256) void k_gemmF(const float* __restrict__ x1, const float* __restrict__ x2,
                                               const float* __restrict__ wf, const float* __restrict__ bf,
                                               float* __restrict__ sumsF, unsigned* __restrict__ hpmx,
                                               unsigned* __restrict__ hpmn) {
  __shared__ float A_s[64*193];
  __shared__ __align__(16) float B_s[192*64];
  __shared__ float red[1024];
  int t = threadIdx.x;
  int rt = blockIdx.x >> 2;
  int ct = blockIdx.x & 3;
  for (int v = t; v < 64*48; v += 256) {
    int r = v / 48, gg = v - r*48;
    int row = rt*64 + r;
    float4 e = (gg < 16) ? ((const float4*)x1)[row*16 + gg]
                         : ((const float4*)x2)[row*32 + (gg-16)];
    float* p = &A_s[r*193 + gg*4];
    p[0]=e.x; p[1]=e.y; p[2]=e.z; p[3]=e.w;
  }
  for (int v = t; v < 192*16; v += 256) {
    int d = v >> 4, c4 = v & 15;
    *(float4*)&B_s[d*64 + c4*4] = ((const float4*)wf)[d*64 + ct*16 + c4];
  }
  __syncthreads();
  int rg = t & 15, cg = t >> 4;
  float acc[4][4];
  #pragma unroll
  for (int a=0;a<4;a++) { acc[a][0]=0.f; acc[a][1]=0.f; acc[a][2]=0.f; acc[a][3]=0.f; }
  for (int d = 0; d < 192; ++d) {
    float a0 = A_s[(rg*4+0)*193 + d];
    float a1 = A_s[(rg*4+1)*193 + d];
    float a2 = A_s[(rg*4+2)*193 + d];
    float a3 = A_s[(rg*4+3)*193 + d];
    float b0 = B_s[d*64 + cg];
    float b1 = B_s[d*64 + cg + 16];
    float b2 = B_s[d*64 + cg + 32];
    float b3 = B_s[d*64 + cg + 48];
    acc[0][0]+=a0*b0; acc[0][1]+=a0*b1; acc[0][2]+=a0*b2; acc[0][3]+=a0*b3;
    acc[1][0]+=a1*b0; acc[1][1]+=a1*b1; acc[1][2]+=a1*b2; acc[1][3]+=a1*b3;
    acc[2][0]+=a2*b0; acc[2][1]+=a2*b1; acc[2][2]+=a2*b2; acc[2][3]+=a2*b3;
    acc[3][0]+=a3*b0; acc[3][1]+=a3*b1; acc[3][2]+=a3*b2; acc[3][3]+=a3*b3;
  }
  float hv[4][4];
  #pragma unroll
  for (int ss=0; ss<4; ++ss) {
    float bb = bf[ct*64 + cg + ss*16];
    #pragma unroll
    for (int rr=0; rr<4; ++rr) hv[rr][ss] = fmaxf(acc[rr][ss] + bb, 0.f);
  }
  int b = rt >> 5;
  #pragma unroll
  for (int ss=0; ss<4; ++ss) red[rg*64 + cg + ss*16] = hv[0][ss]+hv[1][ss]+hv[2][ss]+hv[3][ss];
  __syncthreads();
  if (t < 64) {
    float v = 0.f;
    #pragma unroll
    for (int r=0;r<16;r++) v += red[r*64 + t];
    atomicAdd(&sumsF[ct*64 + t], v);
  }
  __syncthreads();
  #pragma unroll
  for (int ss=0; ss<4; ++ss) red[rg*64 + cg + ss*16] =
      hv[0][ss]*hv[0][ss]+hv[1][ss]*hv[1][ss]+hv[2][ss]*hv[2][ss]+hv[3][ss]*hv[3][ss];
  __syncthreads();
  if (t < 64) {
    float v = 0.f;
    #pragma unroll
    for (int r=0;r<16;r++) v += red[r*64 + t];
    atomicAdd(&sumsF[256 + ct*64 + t], v);
  }
  __syncthreads();
  #pragma unroll
  for (int ss=0; ss<4; ++ss) red[rg*64 + cg + ss*16] =
      fmaxf(fmaxf(hv[0][ss],hv[1][ss]), fmaxf(hv[2][ss],hv[3][ss]));
  __syncthreads();
  if (t < 64) {
    float v = -INFINITY;
    #pragma unroll
    for (int r=0;r<16;r++) v = fmaxf(v, red[r*64 + t]);
    atomicMax(&hpmx[b*256 + ct*64 + t], __float_as_uint(v));
  }
  __syncthreads();
  #pragma unroll
  for (int ss=0; ss<4; ++ss) red[rg*64 + cg + ss*16] =
      fminf(fminf(hv[0][ss],hv[1][ss]), fminf(hv[2][ss],hv[3][ss]));
  __syncthreads();
  if (t < 64) {
    float v = INFINITY;
    #pragma unroll
    for (int r=0;r<16;r++) v = fminf(v, red[r*64 + t]);
    atomicMin(&hpmn[b*256 + ct*64 + t], __float_as_uint(v));
  }
}

// ---------------- head ----------------
__global__ __launch_bounds__(256) void k_head(const float* __restrict__ sumsF, const float* __restrict__ gf,
                                              const float* __restrict__ bef,
                                              const unsigned* __restrict__ hpmx, const unsigned* __restrict__ hpmn,
                                              const float* __restrict__ wo1, const float* __restrict__ bo1,
                                              const float* __restrict__ go1, const float* __restrict__ beo1,
                                              const float* __restrict__ wo2, const float* __restrict__ bo2,
                                              const float* __restrict__ go2, const float* __restrict__ beo2,
                                              const float* __restrict__ wo3, const float* __restrict__ bo3,
                                              float* __restrict__ out) {
  __shared__ float hp[8][256];
  __shared__ float u1[8][128];
  __shared__ float u2[8][64];
  __shared__ float lg[8][16];
  int t = threadIdx.x;
  {
    float m = sumsF[t] * (1.f/16384.f);
    float v = sumsF[256+t] * (1.f/16384.f) - m*m;
    float sc = gf[t] / sqrtf(v + 1e-5f);
    float sh = bef[t] - m*sc;
    for (int b = 0; b < 8; ++b) {
      unsigned bits = (sc >= 0.f) ? hpmx[b*256+t] : hpmn[b*256+t];
      hp[b][t] = sc*__uint_as_float(bits) + sh;
    }
  }
  __syncthreads();
  for (int p = t; p < 1024; p += 256) {
    int b = p >> 7, c = p & 127;
    float z = bo1[c];
    for (int d = 0; d < 256; ++d) z += hp[b][d]*wo1[d*128+c];
    u1[b][c] = fmaxf(z, 0.f);
  }
  __syncthreads();
  if (t < 128) {
    float m = 0.f;
    for (int b=0;b<8;b++) m += u1[b][t];
    m *= 0.125f;
    float v = 0.f;
    for (int b=0;b<8;b++) { float dd = u1[b][t]-m; v += dd*dd; }
    v *= 0.125f;
    float sc = go1[t]/sqrtf(v+1e-5f), sh = beo1[t]-m*sc;
    for (int b=0;b<8;b++) u1[b][t] = sc*u1[b][t]+sh;
  }
  __syncthreads();
  for (int p = t; p < 512; p += 256) {
    int b = p >> 6, c = p & 63;
    float z = bo2[c];
    for (int d = 0; d < 128; ++d) z += u1[b][d]*wo2[d*64+c];
    u2[b][c] = fmaxf(z, 0.f);
  }
  __syncthreads();
  if (t < 64) {
    float m = 0.f;
    for (int b=0;b<8;b++) m += u2[b][t];
    m *= 0.125f;
    float v = 0.f;
    for (int b=0;b<8;b++) { float dd = u2[b][t]-m; v += dd*dd; }
    v *= 0.125f;
    float sc = go2[t]/sqrtf(v+1e-5f), sh = beo2[t]-m*sc;
    for (int b=0;b<8;b++) u2[b][t] = sc*u2[b][t]+sh;
  }
  __syncthreads();
  if (t < 128) {
    int b = t >> 4, c = t & 15;
    float z = bo3[c];
    for (int d = 0; d < 64; ++d) z += u2[b][d]*wo3[d*16+c];
    lg[b][c] = z;
  }
  __syncthreads();
  if (t < 8) {
    float m = -INFINITY;
    for (int j=0;j<16;j++) m = fmaxf(m, lg[t][j]);
    float s = 0.f;
    for (int j=0;j<16;j++) s += expf(lg[t][j]-m);
    float ls = logf(s);
    for (int j=0;j<16;j++) out[t*16+j] = (lg[t][j]-m) - ls;
  }
}

// ---------------- launch ----------------
extern "C" void kernel_launch(void* const* d_in, const int* in_sizes, int n_in,
                              void* d_out, int out_size, void* d_ws, size_t ws_size,
                              hipStream_t stream) {
  (void)in_sizes; (void)n_in; (void)out_size; (void)ws_size;
  const float* pos = (const float*)d_in[0];
  const float* x   = (const float*)d_in[1];
  const float* w1  = (const float*)d_in[3];
  const float* b1  = (const float*)d_in[4];
  const float* g1  = (const float*)d_in[5];
  const float* be1 = (const float*)d_in[6];
  const float* w2  = (const float*)d_in[7];
  const float* b2  = (const float*)d_in[8];
  const float* g2  = (const float*)d_in[9];
  const float* be2 = (const float*)d_in[10];
  const float* wf  = (const float*)d_in[11];
  const float* bf  = (const float*)d_in[12];
  const float* gf  = (const float*)d_in[13];
  const float* bef = (const float*)d_in[14];
  const float* wo1 = (const float*)d_in[15];
  const float* bo1 = (const float*)d_in[16];
  const float* go1 = (const float*)d_in[17];
  const float* beo1= (const float*)d_in[18];
  const float* wo2 = (const float*)d_in[19];
  const float* bo2 = (const float*)d_in[20];
  const float* go2 = (const float*)d_in[21];
  const float* beo2= (const float*)d_in[22];
  const float* wo3 = (const float*)d_in[23];
  const float* bo3 = (const float*)d_in[24];

  char* ws = (char*)d_ws;
  float4*   f0    = (float4*)  (ws + OFF_F0);
  float*    ssq0  = (float*)   (ws + OFF_SSQ0);
  int*      idx1  = (int*)     (ws + OFF_IDX1);
  float*    xmx1  = (float*)   (ws + OFF_XMX1);
  float*    xmn1  = (float*)   (ws + OFF_XMN1);
  float*    sum1  = (float*)   (ws + OFF_SUM1);
  float*    x1    = (float*)   (ws + OFF_X1);
  float*    ssq1  = (float*)   (ws + OFF_SSQ1);
  int*      idx2  = (int*)     (ws + OFF_IDX2);
  float*    xmx2  = (float*)   (ws + OFF_XMX2);
  float*    xmn2  = (float*)   (ws + OFF_XMN2);
  float*    sum2  = (float*)   (ws + OFF_SUM2);
  float*    x2    = (float*)   (ws + OFF_X2);
  float*    sumF  = (float*)   (ws + OFF_SUMF);
  unsigned* hpmx  = (unsigned*)(ws + OFF_HPMX);
  unsigned* hpmn  = (unsigned*)(ws + OFF_HPMN);

  k_init    <<<8,    256, 0, stream>>>(sum1, sum2, sumF, hpmx, hpmn);
  k_f0      <<<64,   256, 0, stream>>>(pos, x, f0, ssq0);
  k_knn1    <<<1024, 256, 0, stream>>>(f0, ssq0, idx1);
  k_mlp1    <<<512,  256, 0, stream>>>(f0, idx1, w1, b1, xmx1, xmn1, sum1);
  k_bn1apply<<<4096, 256, 0, stream>>>(sum1, g1, be1, xmx1, xmn1, x1);
  k_ssq1    <<<64,   256, 0, stream>>>(x1, ssq1);
  k_knn2    <<<512,  256, 0, stream>>>(x1, ssq1, idx2);
  k_mlp2    <<<512,  256, 0, stream>>>(x1, idx2, w2, b2, xmx2, xmn2, sum2);
  k_bn2apply<<<8192, 256, 0, stream>>>(sum2, g2, be2, xmx2, xmn2, x2);
  k_gemmF   <<<1024, 256, 0, stream>>>(x1, x2, wf, bf, sumF, hpmx, hpmn);
  k_head    <<<1,    256, 0, stream>>>(sumF, gf, bef, hpmx, hpmn,
                                       wo1, bo1, go1, beo1, wo2, bo2, go2, beo2, wo3, bo3,
                                       (float*)d_out);
}

// Round 6
// 974.565 us; speedup vs baseline: 2.6105x; 1.2794x over previous
//
#include <hip/hip_runtime.h>
#include <math.h>

#define NPTS 16384
#define KNB 20
#define SCAP 512

// ---------------- workspace layout (bytes, all naturally 256-aligned) ----------------
static const size_t OFF_F0   = 0;                                   // N x float4
static const size_t OFF_SSQ0 = OFF_F0   + (size_t)NPTS*4*4;         // N f32
static const size_t OFF_IDX1 = OFF_SSQ0 + (size_t)NPTS*4;           // N*20 i32
static const size_t OFF_XMX1 = OFF_IDX1 + (size_t)NPTS*KNB*4;       // N*64 f32
static const size_t OFF_XMN1 = OFF_XMX1 + (size_t)NPTS*64*4;        // N*64 f32
static const size_t OFF_SUM1 = OFF_XMN1 + (size_t)NPTS*64*4;        // 128 f32 (sum,sumsq)
static const size_t OFF_X1   = OFF_SUM1 + 512;                      // N*64 f32
static const size_t OFF_SSQ1 = OFF_X1   + (size_t)NPTS*64*4;        // N f32
static const size_t OFF_IDX2 = OFF_SSQ1 + (size_t)NPTS*4;           // N*20 i32 (global idx)
static const size_t OFF_XMX2 = OFF_IDX2 + (size_t)NPTS*KNB*4;       // N*128 f32
static const size_t OFF_XMN2 = OFF_XMX2 + (size_t)NPTS*128*4;       // N*128 f32
static const size_t OFF_SUM2 = OFF_XMN2 + (size_t)NPTS*128*4;       // 256 f32
static const size_t OFF_X2   = OFF_SUM2 + 1024;                     // N*128 f32
static const size_t OFF_SUMF = OFF_X2   + (size_t)NPTS*128*4;       // 512 f32
static const size_t OFF_HPMX = OFF_SUMF + 2048;                     // 8*256 u32 (float bits)
static const size_t OFF_HPMN = OFF_HPMX + 8*256*4;                  // 8*256 u32

// ---------------- helpers ----------------
__device__ __forceinline__ float dot4f(float4 a, float4 b) {
  return a.x*b.x + a.y*b.y + a.z*b.z + a.w*b.w;
}

// fixed-order 64-d dot: used for BOTH row norms and cross dots so that
// d(i,i) == (sq - 2*sq) + sq == 0 exactly (self always selected, like jax top_k)
__device__ __forceinline__ float dot64v(const float* a, const float4* b4) {
  float s = 0.f;
  #pragma unroll
  for (int d4 = 0; d4 < 16; ++d4) {
    float4 b = b4[d4];
    s += a[4*d4+0]*b.x + a[4*d4+1]*b.y + a[4*d4+2]*b.z + a[4*d4+3]*b.w;
  }
  return s;
}

// ---------------- branch-free sorting-network top-k machinery ----------------
// compare-exchange: after call, (a,ai) <= (b,bi) by distance
__device__ __forceinline__ void ce(float& a, int& ai, float& b, int& bi) {
  bool sw = b < a;
  float d0 = sw ? b : a;  float d1 = sw ? a : b;
  int   j0 = sw ? bi : ai; int  j1 = sw ? ai : bi;
  a = d0; ai = j0; b = d1; bi = j1;
}

// bitonic sort of 16 (d,idx) pairs, ascending; all indices static after unroll
__device__ __forceinline__ void sort16(float (&d)[16], int (&ix)[16]) {
  #pragma unroll
  for (int k = 2; k <= 16; k <<= 1) {
    #pragma unroll
    for (int j = k >> 1; j > 0; j >>= 1) {
      #pragma unroll
      for (int i = 0; i < 16; ++i) {
        int l = i ^ j;
        if (l > i) {
          if ((i & k) == 0) ce(d[i], ix[i], d[l], ix[l]);
          else              ce(d[l], ix[l], d[i], ix[i]);
        }
      }
    }
  }
}

// bitonic -> ascending cleanup for 32 elements
__device__ __forceinline__ void bimerge32(float (&rd)[32], int (&ri)[32]) {
  #pragma unroll
  for (int j = 16; j > 0; j >>= 1) {
    #pragma unroll
    for (int i = 0; i < 32; ++i) {
      int l = i ^ j;
      if (l > i) ce(rd[i], ri[i], rd[l], ri[l]);
    }
  }
}

// merge sorted-16 batch into sorted-32 running list, keep smallest 32.
__device__ __forceinline__ void merge16(float (&rd)[32], int (&ri)[32],
                                        float (&bd)[16], int (&bi)[16]) {
  #pragma unroll
  for (int k = 0; k < 16; ++k) {
    bool sw = bd[15-k] < rd[16+k];
    rd[16+k] = sw ? bd[15-k] : rd[16+k];
    ri[16+k] = sw ? bi[15-k] : ri[16+k];
  }
  bimerge32(rd, ri);
}

// butterfly cross-lane merge: both partners compute identical union-top-32
__device__ __forceinline__ void mergelane(float (&rd)[32], int (&ri)[32], int mask) {
  float pd[32]; int pi[32];
  #pragma unroll
  for (int s = 0; s < 32; ++s) { pd[s] = __shfl_xor(rd[s], mask); pi[s] = __shfl_xor(ri[s], mask); }
  #pragma unroll
  for (int k = 0; k < 32; ++k) {
    bool sw = pd[31-k] < rd[k];
    rd[k] = sw ? pd[31-k] : rd[k];
    ri[k] = sw ? pi[31-k] : ri[k];
  }
  bimerge32(rd, ri);
}

// ---------------- init (atomic accumulators must be reset EVERY launch) ----------------
__global__ void k_init(float* sum1, float* sum2, float* sumF, unsigned* hpmx, unsigned* hpmn) {
  int t = blockIdx.x*256 + threadIdx.x;
  if (t < 128) sum1[t] = 0.f;
  if (t < 256) sum2[t] = 0.f;
  if (t < 512) sumF[t] = 0.f;
  if (t < 2048) { hpmx[t] = 0u; hpmn[t] = 0x7f800000u; }   // relu>=0 -> uint order == float order
}

// ---------------- f0 = [pos,x], ssq0 ----------------
__global__ __launch_bounds__(256) void k_f0(const float* __restrict__ pos, const float* __restrict__ x,
                                            float4* __restrict__ f0, float* __restrict__ ssq) {
  int i = blockIdx.x*256 + threadIdx.x;
  if (i >= NPTS) return;
  float4 f;
  f.x = pos[3*i+0]; f.y = pos[3*i+1]; f.z = pos[3*i+2]; f.w = x[i];
  f0[i] = f;
  ssq[i] = dot4f(f, f);
}

// ---------------- knn1: global 16384-point knn in 4-d, TWO-PHASE exact ----------------
// 8 rows/block x 32 lanes/row, grid 2048.
// Pass 1: exact top-20 of the first 2048 candidates (bitonic machinery) -> T0.
//         Full-set 20th <= subset 20th, so all true top-20 have d <= T0.
// Pass 2: rescan all 16384: distance + compare only; survivors (d<=T0) appended
//         to per-row LDS list via atomic (E[count]=160, cap 512, overflow P~1e-9).
// Pass 3: exact top-20 of survivors with the same machinery.
__global__ __launch_bounds__(256) void k_knn1(const float4* __restrict__ f0, const float* __restrict__ ssq,
                                              int* __restrict__ idx1) {
  __shared__ __align__(16) float4 tf[1024];
  __shared__ float tq[1024];
  __shared__ float2 surv[8][SCAP];
  __shared__ int scnt[8];
  int t = threadIdx.x;
  int r = t >> 5;
  int lane = t & 31;
  int row = blockIdx.x*8 + r;
  if (t < 8) scnt[t] = 0;
  float4 fi = f0[row];
  float sqi = ssq[row];
  float rd[32]; int ri[32];
  #pragma unroll
  for (int s = 0; s < 32; ++s) { rd[s] = INFINITY; ri[s] = 0; }
  // ---- pass 1: sample = candidates [0, 2048)
  for (int tile = 0; tile < 2; ++tile) {
    int base = tile*1024;
    __syncthreads();
    #pragma unroll
    for (int v = 0; v < 4; ++v) { tf[t+v*256] = f0[base+t+v*256]; tq[t+v*256] = ssq[base+t+v*256]; }
    __syncthreads();
    #pragma unroll
    for (int b = 0; b < 2; ++b) {
      float bd[16]; int bix[16];
      #pragma unroll
      for (int u = 0; u < 16; ++u) {
        int jl = b*512 + u*32 + lane;
        bd[u] = (sqi - 2.f*dot4f(fi, tf[jl])) + tq[jl];
        bix[u] = base + jl;
      }
      sort16(bd, bix);
      merge16(rd, ri, bd, bix);
    }
  }
  mergelane(rd, ri, 1); mergelane(rd, ri, 2); mergelane(rd, ri, 4);
  mergelane(rd, ri, 8); mergelane(rd, ri, 16);
  float T0 = rd[19];              // row-uniform after butterfly merges
  // ---- pass 2: filter all 16384 candidates
  for (int tile = 0; tile < 16; ++tile) {
    int base = tile*1024;
    __syncthreads();
    #pragma unroll
    for (int v = 0; v < 4; ++v) { tf[t+v*256] = f0[base+t+v*256]; tq[t+v*256] = ssq[base+t+v*256]; }
    __syncthreads();
    #pragma unroll 4
    for (int s = 0; s < 32; ++s) {
      int jl = s*32 + lane;
      float d = (sqi - 2.f*dot4f(fi, tf[jl])) + tq[jl];
      if (d <= T0) {
        int slot = atomicAdd(&scnt[r], 1);
        if (slot < SCAP) surv[r][slot] = make_float2(d, __int_as_float(base + jl));
      }
    }
  }
  __syncthreads();
  int n = scnt[r] < SCAP ? scnt[r] : SCAP;
  // ---- pass 3: exact top-20 of survivors
  #pragma unroll
  for (int s = 0; s < 32; ++s) { rd[s] = INFINITY; ri[s] = 0; }
  {
    float bd[16]; int bix[16];
    #pragma unroll
    for (int u = 0; u < 16; ++u) {
      int s = u*32 + lane;
      if (s < n) { float2 v = surv[r][s]; bd[u] = v.x; bix[u] = __float_as_int(v.y); }
      else       { bd[u] = INFINITY; bix[u] = 0; }
    }
    sort16(bd, bix);
    merge16(rd, ri, bd, bix);
  }
  mergelane(rd, ri, 1); mergelane(rd, ri, 2); mergelane(rd, ri, 4);
  mergelane(rd, ri, 8); mergelane(rd, ri, 16);
  if (lane == 0) {
    int4* p = (int4*)&idx1[row*KNB];
    p[0] = make_int4(ri[0],ri[1],ri[2],ri[3]);
    p[1] = make_int4(ri[4],ri[5],ri[6],ri[7]);
    p[2] = make_int4(ri[8],ri[9],ri[10],ri[11]);
    p[3] = make_int4(ri[12],ri[13],ri[14],ri[15]);
    p[4] = make_int4(ri[16],ri[17],ri[18],ri[19]);
  }
}

// ---------------- mlp1: edge MLP 8->64, relu, per-point max/min (pre-BN), channel sums ----------------
__global__ __launch_bounds__(256) void k_mlp1(const float4* __restrict__ f0, const int* __restrict__ idx1,
                                              const float* __restrict__ w1, const float* __restrict__ b1,
                                              float* __restrict__ xmx, float* __restrict__ xmn,
                                              float* __restrict__ sums) {
  __shared__ float rs[256], rs2[256];
  int t = threadIdx.x;
  int c = t & 63;
  int w = t >> 6;
  float wc[8];
  #pragma unroll
  for (int d = 0; d < 8; ++d) wc[d] = w1[d*64 + c];
  float bc = b1[c];
  float s = 0.f, s2 = 0.f;
  for (int p = 0; p < 8; ++p) {
    int i = blockIdx.x*32 + p*4 + w;
    float4 fi = f0[i];
    float mx = -INFINITY, mn = INFINITY;
    #pragma unroll
    for (int k = 0; k < KNB; ++k) {
      int j = idx1[i*KNB + k];
      float4 fj = f0[j];
      float h = bc + fi.x*wc[0] + fi.y*wc[1] + fi.z*wc[2] + fi.w*wc[3]
                   + (fj.x-fi.x)*wc[4] + (fj.y-fi.y)*wc[5] + (fj.z-fi.z)*wc[6] + (fj.w-fi.w)*wc[7];
      h = fmaxf(h, 0.f);
      mx = fmaxf(mx, h); mn = fminf(mn, h);
      s += h; s2 += h*h;
    }
    xmx[i*64+c] = mx; xmn[i*64+c] = mn;
  }
  rs[t] = s; rs2[t] = s2;
  __syncthreads();
  if (t < 64) {
    atomicAdd(&sums[c],      rs[t]+rs[t+64]+rs[t+128]+rs[t+192]);
    atomicAdd(&sums[64+c],   rs2[t]+rs2[t+64]+rs2[t+128]+rs2[t+192]);
  }
}

// ---------------- bn1 apply: x1 = affine(max or min by scale sign) ----------------
__global__ __launch_bounds__(256) void k_bn1apply(const float* __restrict__ sums, const float* __restrict__ g,
                                                  const float* __restrict__ be, const float* __restrict__ xmx,
                                                  const float* __restrict__ xmn, float* __restrict__ x1) {
  __shared__ float sc_s[64], sh_s[64];
  int t = threadIdx.x;
  if (t < 64) {
    float m = sums[t] * (1.f/327680.f);
    float v = sums[64+t] * (1.f/327680.f) - m*m;
    float sc = g[t] / sqrtf(v + 1e-5f);
    sc_s[t] = sc; sh_s[t] = be[t] - m*sc;
  }
  __syncthreads();
  int c = t & 63;
  int i = blockIdx.x*4 + (t>>6);
  float sc = sc_s[c], sh = sh_s[c];
  float val = (sc >= 0.f) ? xmx[i*64+c] : xmn[i*64+c];
  x1[i*64+c] = sc*val + sh;
}

// ---------------- ssq1 (same dot64v ordering as knn2 for exact self-distance) ----------------
__global__ __launch_bounds__(256) void k_ssq1(const float* __restrict__ x1, float* __restrict__ ssq1) {
  int i = blockIdx.x*256 + threadIdx.x;
  alignas(16) float f[64];
  #pragma unroll
  for (int d4 = 0; d4 < 16; ++d4) ((float4*)f)[d4] = ((const float4*)x1)[i*16 + d4];
  ssq1[i] = dot64v(f, (const float4*)f);
}

// ---------------- knn2: per-batch knn over 2048 points in 64-d ----------------
// 32 rows/block x 8 lanes/row, grid 512; one 16-batch per 128-candidate tile.
__global__ __launch_bounds__(256) void k_knn2(const float* __restrict__ x1, const float* __restrict__ ssq1,
                                              int* __restrict__ idx2) {
  __shared__ __align__(16) float tf[128][68];   // pad 68 -> conflict-light reads
  __shared__ float tq[128];
  int t = threadIdx.x;
  int row = blockIdx.x*32 + (t>>3);
  int lane = t & 7;
  int cbase = (row >> 11) << 11;                // batch column base
  alignas(16) float fi[64];
  #pragma unroll
  for (int d4 = 0; d4 < 16; ++d4) ((float4*)fi)[d4] = ((const float4*)x1)[row*16 + d4];
  float sqi = ssq1[row];
  float rd[32]; int ri[32];
  #pragma unroll
  for (int s = 0; s < 32; ++s) { rd[s] = INFINITY; ri[s] = 0; }
  for (int tile = 0; tile < 16; ++tile) {
    int base = cbase + tile*128;
    __syncthreads();
    for (int v = t; v < 128*16; v += 256) {
      int jl = v >> 4, d4 = v & 15;
      *(float4*)&tf[jl][d4*4] = ((const float4*)x1)[(base+jl)*16 + d4];
    }
    if (t < 128) tq[t] = ssq1[base + t];
    __syncthreads();
    float bd[16]; int bix[16];
    #pragma unroll
    for (int u = 0; u < 16; ++u) {
      int jl = u*8 + lane;
      bd[u] = (sqi - 2.f*dot64v(fi, (const float4*)&tf[jl][0])) + tq[jl];
      bix[u] = base + jl;
    }
    sort16(bd, bix);
    merge16(rd, ri, bd, bix);
  }
  mergelane(rd, ri, 1);
  mergelane(rd, ri, 2);
  mergelane(rd, ri, 4);
  if (lane == 0) {
    int4* p = (int4*)&idx2[row*KNB];
    p[0] = make_int4(ri[0],ri[1],ri[2],ri[3]);
    p[1] = make_int4(ri[4],ri[5],ri[6],ri[7]);
    p[2] = make_int4(ri[8],ri[9],ri[10],ri[11]);
    p[3] = make_int4(ri[12],ri[13],ri[14],ri[15]);
    p[4] = make_int4(ri[16],ri[17],ri[18],ri[19]);
  }
}

// ---------------- mlp2: edge MLP 128->128, relu, per-point max/min, channel sums ----------------
__global__ __launch_bounds__(256) void k_mlp2(const float* __restrict__ x1, const int* __restrict__ idx2,
                                              const float* __restrict__ w2, const float* __restrict__ b2,
                                              float* __restrict__ xmx, float* __restrict__ xmn,
                                              float* __restrict__ sums) {
  __shared__ __align__(16) float w2s[128*128];
  __shared__ __align__(16) float es[KNB*128];
  __shared__ float red[256];
  __shared__ int js[KNB];
  int t = threadIdx.x;
  for (int v = t; v < 128*32; v += 256) ((float4*)w2s)[v] = ((const float4*)w2)[v];
  int c = t & 127, half = t >> 7;
  float bc = b2[c];
  float s = 0.f, s2 = 0.f;
  for (int p = 0; p < 32; ++p) {
    int i = blockIdx.x*32 + p;
    __syncthreads();
    if (t < KNB) js[t] = idx2[i*KNB + t];
    __syncthreads();
    for (int v = t; v < KNB*32; v += 256) {
      int k = v >> 5, d4 = v & 31;
      int j = js[k];
      float4 e;
      if (d4 < 16) {
        e = ((const float4*)x1)[i*16 + d4];
      } else {
        float4 a  = ((const float4*)x1)[j*16 + (d4-16)];
        float4 xi = ((const float4*)x1)[i*16 + (d4-16)];
        e = make_float4(a.x-xi.x, a.y-xi.y, a.z-xi.z, a.w-xi.w);
      }
      ((float4*)es)[v] = e;
    }
    __syncthreads();
    float acc[10];
    #pragma unroll
    for (int k = 0; k < 10; ++k) acc[k] = 0.f;
    int kbase = half*10;
    for (int d4 = 0; d4 < 32; ++d4) {
      float w0 = w2s[(d4*4+0)*128 + c];
      float w1v = w2s[(d4*4+1)*128 + c];
      float w2v = w2s[(d4*4+2)*128 + c];
      float w3 = w2s[(d4*4+3)*128 + c];
      #pragma unroll
      for (int k = 0; k < 10; ++k) {
        float4 e = ((const float4*)es)[(kbase+k)*32 + d4];
        acc[k] += e.x*w0 + e.y*w1v + e.z*w2v + e.w*w3;
      }
    }
    float mx = -INFINITY, mn = INFINITY;
    #pragma unroll
    for (int k = 0; k < 10; ++k) {
      float h = fmaxf(acc[k] + bc, 0.f);
      mx = fmaxf(mx, h); mn = fminf(mn, h);
      s += h; s2 += h*h;
    }
    red[t] = mx; __syncthreads();
    float omx = fmaxf(mx, red[c+128]);
    __syncthreads();
    red[t] = mn; __syncthreads();
    if (half == 0) {
      xmx[i*128+c] = omx;
      xmn[i*128+c] = fminf(mn, red[c+128]);
    }
  }
  __syncthreads();
  red[t] = s; __syncthreads();
  if (half == 0) atomicAdd(&sums[c], s + red[c+128]);
  __syncthreads();
  red[t] = s2; __syncthreads();
  if (half == 0) atomicAdd(&sums[128+c], s2 + red[c+128]);
}

// ---------------- bn2 apply ----------------
__global__ __launch_bounds__(256) void k_bn2apply(const float* __restrict__ sums, const float* __restrict__ g,
                                                  const float* __restrict__ be, const float* __restrict__ xmx,
                                                  const float* __restrict__ xmn, float* __restrict__ x2) {
  __shared__ float sc_s[128], sh_s[128];
  int t = threadIdx.x;
  if (t < 128) {
    float m = sums[t] * (1.f/327680.f);
    float v = sums[128+t] * (1.f/327680.f) - m*m;
    float sc = g[t] / sqrtf(v + 1e-5f);
    sc_s[t] = sc; sh_s[t] = be[t] - m*sc;
  }
  __syncthreads();
  int c = t & 127;
  int i = blockIdx.x*2 + (t>>7);
  float sc = sc_s[c], sh = sh_s[c];
  float val = (sc >= 0.f) ? xmx[i*128+c] : xmn[i*128+c];
  x2[i*128+c] = sc*val + sh;
}

// ---------------- gemmF: relu([x1|x2] @ wf + bf); channel sums + per-batch max/min only ----------------
__global__ __launch_bounds__(256) void k_gemmF(const float* __restrict__ x1, const float* __restrict__ x2,
                                               const float* __restrict__ wf, const float* __restrict__ bf,
                                               float* __restrict__ sumsF, unsigned* __restrict__ hpmx,
                                               unsigned* __restrict__ hpmn) {
  __shared__ float A_s[64*193];
  __shared__ __align__(16) float B_s[192*64];
  __shared__ float red[1024];
  int t = threadIdx.x;
  int rt = blockIdx.x >> 2;
  int ct = blockIdx.x & 3;
  for (int v = t; v < 64*48; v += 256) {
    int r = v / 48, gg = v - r*48;
    int row = rt*64 + r;
    float4 e = (gg < 16) ? ((const float4*)x1)[row*16 + gg]
                         : ((const float4*)x2)[row*32 + (gg-16)];
    float* p = &A_s[r*193 + gg*4];
    p[0]=e.x; p[1]=e.y; p[2]=e.z; p[3]=e.w;
  }
  for (int v = t; v < 192*16; v += 256) {
    int d = v >> 4, c4 = v & 15;
    *(float4*)&B_s[d*64 + c4*4] = ((const float4*)wf)[d*64 + ct*16 + c4];
  }
  __syncthreads();
  int rg = t & 15, cg = t >> 4;
  float acc[4][4];
  #pragma unroll
  for (int a=0;a<4;a++) { acc[a][0]=0.f; acc[a][1]=0.f; acc[a][2]=0.f; acc[a][3]=0.f; }
  for (int d = 0; d < 192; ++d) {
    float a0 = A_s[(rg*4+0)*193 + d];
    float a1 = A_s[(rg*4+1)*193 + d];
    float a2 = A_s[(rg*4+2)*193 + d];
    float a3 = A_s[(rg*4+3)*193 + d];
    float b0 = B_s[d*64 + cg];
    float b1 = B_s[d*64 + cg + 16];
    float b2 = B_s[d*64 + cg + 32];
    float b3 = B_s[d*64 + cg + 48];
    acc[0][0]+=a0*b0; acc[0][1]+=a0*b1; acc[0][2]+=a0*b2; acc[0][3]+=a0*b3;
    acc[1][0]+=a1*b0; acc[1][1]+=a1*b1; acc[1][2]+=a1*b2; acc[1][3]+=a1*b3;
    acc[2][0]+=a2*b0; acc[2][1]+=a2*b1; acc[2][2]+=a2*b2; acc[2][3]+=a2*b3;
    acc[3][0]+=a3*b0; acc[3][1]+=a3*b1; acc[3][2]+=a3*b2; acc[3][3]+=a3*b3;
  }
  float hv[4][4];
  #pragma unroll
  for (int ss=0; ss<4; ++ss) {
    float bb = bf[ct*64 + cg + ss*16];
    #pragma unroll
    for (int rr=0; rr<4; ++rr) hv[rr][ss] = fmaxf(acc[rr][ss] + bb, 0.f);
  }
  int b = rt >> 5;
  #pragma unroll
  for (int ss=0; ss<4; ++ss) red[rg*64 + cg + ss*16] = hv[0][ss]+hv[1][ss]+hv[2][ss]+hv[3][ss];
  __syncthreads();
  if (t < 64) {
    float v = 0.f;
    #pragma unroll
    for (int r=0;r<16;r++) v += red[r*64 + t];
    atomicAdd(&sumsF[ct*64 + t], v);
  }
  __syncthreads();
  #pragma unroll
  for (int ss=0; ss<4; ++ss) red[rg*64 + cg + ss*16] =
      hv[0][ss]*hv[0][ss]+hv[1][ss]*hv[1][ss]+hv[2][ss]*hv[2][ss]+hv[3][ss]*hv[3][ss];
  __syncthreads();
  if (t < 64) {
    float v = 0.f;
    #pragma unroll
    for (int r=0;r<16;r++) v += red[r*64 + t];
    atomicAdd(&sumsF[256 + ct*64 + t], v);
  }
  __syncthreads();
  #pragma unroll
  for (int ss=0; ss<4; ++ss) red[rg*64 + cg + ss*16] =
      fmaxf(fmaxf(hv[0][ss],hv[1][ss]), fmaxf(hv[2][ss],hv[3][ss]));
  __syncthreads();
  if (t < 64) {
    float v = -INFINITY;
    #pragma unroll
    for (int r=0;r<16;r++) v = fmaxf(v, red[r*64 + t]);
    atomicMax(&hpmx[b*256 + ct*64 + t], __float_as_uint(v));
  }
  __syncthreads();
  #pragma unroll
  for (int ss=0; ss<4; ++ss) red[rg*64 + cg + ss*16] =
      fminf(fminf(hv[0][ss],hv[1][ss]), fminf(hv[2][ss],hv[3][ss]));
  __syncthreads();
  if (t < 64) {
    float v = INFINITY;
    #pragma unroll
    for (int r=0;r<16;r++) v = fminf(v, red[r*64 + t]);
    atomicMin(&hpmn[b*256 + ct*64 + t], __float_as_uint(v));
  }
}

// ---------------- head ----------------
__global__ __launch_bounds__(256) void k_head(const float* __restrict__ sumsF, const float* __restrict__ gf,
                                              const float* __restrict__ bef,
                                              const unsigned* __restrict__ hpmx, const unsigned* __restrict__ hpmn,
                                              const float* __restrict__ wo1, const float* __restrict__ bo1,
                                              const float* __restrict__ go1, const float* __restrict__ beo1,
                                              const float* __restrict__ wo2, const float* __restrict__ bo2,
                                              const float* __restrict__ go2, const float* __restrict__ beo2,
                                              const float* __restrict__ wo3, const float* __restrict__ bo3,
                                              float* __restrict__ out) {
  __shared__ float hp[8][256];
  __shared__ float u1[8][128];
  __shared__ float u2[8][64];
  __shared__ float lg[8][16];
  int t = threadIdx.x;
  {
    float m = sumsF[t] * (1.f/16384.f);
    float v = sumsF[256+t] * (1.f/16384.f) - m*m;
    float sc = gf[t] / sqrtf(v + 1e-5f);
    float sh = bef[t] - m*sc;
    for (int b = 0; b < 8; ++b) {
      unsigned bits = (sc >= 0.f) ? hpmx[b*256+t] : hpmn[b*256+t];
      hp[b][t] = sc*__uint_as_float(bits) + sh;
    }
  }
  __syncthreads();
  for (int p = t; p < 1024; p += 256) {
    int b = p >> 7, c = p & 127;
    float z = bo1[c];
    for (int d = 0; d < 256; ++d) z += hp[b][d]*wo1[d*128+c];
    u1[b][c] = fmaxf(z, 0.f);
  }
  __syncthreads();
  if (t < 128) {
    float m = 0.f;
    for (int b=0;b<8;b++) m += u1[b][t];
    m *= 0.125f;
    float v = 0.f;
    for (int b=0;b<8;b++) { float dd = u1[b][t]-m; v += dd*dd; }
    v *= 0.125f;
    float sc = go1[t]/sqrtf(v+1e-5f), sh = beo1[t]-m*sc;
    for (int b=0;b<8;b++) u1[b][t] = sc*u1[b][t]+sh;
  }
  __syncthreads();
  for (int p = t; p < 512; p += 256) {
    int b = p >> 6, c = p & 63;
    float z = bo2[c];
    for (int d = 0; d < 128; ++d) z += u1[b][d]*wo2[d*64+c];
    u2[b][c] = fmaxf(z, 0.f);
  }
  __syncthreads();
  if (t < 64) {
    float m = 0.f;
    for (int b=0;b<8;b++) m += u2[b][t];
    m *= 0.125f;
    float v = 0.f;
    for (int b=0;b<8;b++) { float dd = u2[b][t]-m; v += dd*dd; }
    v *= 0.125f;
    float sc = go2[t]/sqrtf(v+1e-5f), sh = beo2[t]-m*sc;
    for (int b=0;b<8;b++) u2[b][t] = sc*u2[b][t]+sh;
  }
  __syncthreads();
  if (t < 128) {
    int b = t >> 4, c = t & 15;
    float z = bo3[c];
    for (int d = 0; d < 64; ++d) z += u2[b][d]*wo3[d*16+c];
    lg[b][c] = z;
  }
  __syncthreads();
  if (t < 8) {
    float m = -INFINITY;
    for (int j=0;j<16;j++) m = fmaxf(m, lg[t][j]);
    float s = 0.f;
    for (int j=0;j<16;j++) s += expf(lg[t][j]-m);
    float ls = logf(s);
    for (int j=0;j<16;j++) out[t*16+j] = (lg[t][j]-m) - ls;
  }
}

// ---------------- launch ----------------
extern "C" void kernel_launch(void* const* d_in, const int* in_sizes, int n_in,
                              void* d_out, int out_size, void* d_ws, size_t ws_size,
                              hipStream_t stream) {
  (void)in_sizes; (void)n_in; (void)out_size; (void)ws_size;
  const float* pos = (const float*)d_in[0];
  const float* x   = (const float*)d_in[1];
  const float* w1  = (const float*)d_in[3];
  const float* b1  = (const float*)d_in[4];
  const float* g1  = (const float*)d_in[5];
  const float* be1 = (const float*)d_in[6];
  const float* w2  = (const float*)d_in[7];
  const float* b2  = (const float*)d_in[8];
  const float* g2  = (const float*)d_in[9];
  const float* be2 = (const float*)d_in[10];
  const float* wf  = (const float*)d_in[11];
  const float* bf  = (const float*)d_in[12];
  const float* gf  = (const float*)d_in[13];
  const float* bef = (const float*)d_in[14];
  const float* wo1 = (const float*)d_in[15];
  const float* bo1 = (const float*)d_in[16];
  const float* go1 = (const float*)d_in[17];
  const float* beo1= (const float*)d_in[18];
  const float* wo2 = (const float*)d_in[19];
  const float* bo2 = (const float*)d_in[20];
  const float* go2 = (const float*)d_in[21];
  const float* beo2= (const float*)d_in[22];
  const float* wo3 = (const float*)d_in[23];
  const float* bo3 = (const float*)d_in[24];

  char* ws = (char*)d_ws;
  float4*   f0    = (float4*)  (ws + OFF_F0);
  float*    ssq0  = (float*)   (ws + OFF_SSQ0);
  int*      idx1  = (int*)     (ws + OFF_IDX1);
  float*    xmx1  = (float*)   (ws + OFF_XMX1);
  float*    xmn1  = (float*)   (ws + OFF_XMN1);
  float*    sum1  = (float*)   (ws + OFF_SUM1);
  float*    x1    = (float*)   (ws + OFF_X1);
  float*    ssq1  = (float*)   (ws + OFF_SSQ1);
  int*      idx2  = (int*)     (ws + OFF_IDX2);
  float*    xmx2  = (float*)   (ws + OFF_XMX2);
  float*    xmn2  = (float*)   (ws + OFF_XMN2);
  float*    sum2  = (float*)   (ws + OFF_SUM2);
  float*    x2    = (float*)   (ws + OFF_X2);
  float*    sumF  = (float*)   (ws + OFF_SUMF);
  unsigned* hpmx  = (unsigned*)(ws + OFF_HPMX);
  unsigned* hpmn  = (unsigned*)(ws + OFF_HPMN);

  k_init    <<<8,    256, 0, stream>>>(sum1, sum2, sumF, hpmx, hpmn);
  k_f0      <<<64,   256, 0, stream>>>(pos, x, f0, ssq0);
  k_knn1    <<<2048, 256, 0, stream>>>(f0, ssq0, idx1);
  k_mlp1    <<<512,  256, 0, stream>>>(f0, idx1, w1, b1, xmx1, xmn1, sum1);
  k_bn1apply<<<4096, 256, 0, stream>>>(sum1, g1, be1, xmx1, xmn1, x1);
  k_ssq1    <<<64,   256, 0, stream>>>(x1, ssq1);
  k_knn2    <<<512,  256, 0, stream>>>(x1, ssq1, idx2);
  k_mlp2    <<<512,  256, 0, stream>>>(x1, idx2, w2, b2, xmx2, xmn2, sum2);
  k_bn2apply<<<8192, 256, 0, stream>>>(sum2, g2, be2, xmx2, xmn2, x2);
  k_gemmF   <<<1024, 256, 0, stream>>>(x1, x2, wf, bf, sumF, hpmx, hpmn);
  k_head    <<<1,    256, 0, stream>>>(sumF, gf, bef, hpmx, hpmn,
                                       wo1, bo1, go1, beo1, wo2, bo2, go2, beo2, wo3, bo3,
                                       (float*)d_out);
}

// Round 7
// 774.038 us; speedup vs baseline: 3.2868x; 1.2591x over previous
//
#include <hip/hip_runtime.h>
#include <math.h>

#define NPTS 16384
#define KNB 20
#define SCAP 512

typedef __attribute__((ext_vector_type(8))) short short8;
typedef __attribute__((ext_vector_type(4))) float f32x4;

// ---------------- workspace layout (bytes, all naturally 256-aligned) ----------------
static const size_t OFF_F0   = 0;                                   // N x float4
static const size_t OFF_SSQ0 = OFF_F0   + (size_t)NPTS*4*4;         // N f32
static const size_t OFF_IDX1 = OFF_SSQ0 + (size_t)NPTS*4;           // N*20 i32
static const size_t OFF_XMX1 = OFF_IDX1 + (size_t)NPTS*KNB*4;       // N*64 f32
static const size_t OFF_XMN1 = OFF_XMX1 + (size_t)NPTS*64*4;        // N*64 f32
static const size_t OFF_SUM1 = OFF_XMN1 + (size_t)NPTS*64*4;        // 128 f32 (sum,sumsq)
static const size_t OFF_X1   = OFF_SUM1 + 512;                      // N*64 f32
static const size_t OFF_SSQ1 = OFF_X1   + (size_t)NPTS*64*4;        // N f32
static const size_t OFF_IDX2 = OFF_SSQ1 + (size_t)NPTS*4;           // N*20 i32 (global idx)
static const size_t OFF_XMX2 = OFF_IDX2 + (size_t)NPTS*KNB*4;       // N*128 f32
static const size_t OFF_XMN2 = OFF_XMX2 + (size_t)NPTS*128*4;       // N*128 f32
static const size_t OFF_SUM2 = OFF_XMN2 + (size_t)NPTS*128*4;       // 256 f32
static const size_t OFF_X2   = OFF_SUM2 + 1024;                     // N*128 f32
static const size_t OFF_SUMF = OFF_X2   + (size_t)NPTS*128*4;       // 512 f32
static const size_t OFF_HPMX = OFF_SUMF + 2048;                     // 8*256 u32 (float bits)
static const size_t OFF_HPMN = OFF_HPMX + 8*256*4;                  // 8*256 u32

// ---------------- helpers ----------------
__device__ __forceinline__ float dot4f(float4 a, float4 b) {
  return a.x*b.x + a.y*b.y + a.z*b.z + a.w*b.w;
}

// fixed-order 64-d dot: used for BOTH row norms and cross dots so that
// d(i,i) == (sq - 2*sq) + sq == 0 exactly (self always selected, like jax top_k)
__device__ __forceinline__ float dot64v(const float* a, const float4* b4) {
  float s = 0.f;
  #pragma unroll
  for (int d4 = 0; d4 < 16; ++d4) {
    float4 b = b4[d4];
    s += a[4*d4+0]*b.x + a[4*d4+1]*b.y + a[4*d4+2]*b.z + a[4*d4+3]*b.w;
  }
  return s;
}

// f32 -> bf16 (RNE)
__device__ __forceinline__ short f2bf(float x) {
  union { float f; unsigned u; } v; v.f = x;
  unsigned r = (v.u + 0x7FFFu + ((v.u >> 16) & 1u)) >> 16;
  return (short)r;
}

// ---------------- branch-free sorting-network top-k machinery ----------------
__device__ __forceinline__ void ce(float& a, int& ai, float& b, int& bi) {
  bool sw = b < a;
  float d0 = sw ? b : a;  float d1 = sw ? a : b;
  int   j0 = sw ? bi : ai; int  j1 = sw ? ai : bi;
  a = d0; ai = j0; b = d1; bi = j1;
}

__device__ __forceinline__ void sort16(float (&d)[16], int (&ix)[16]) {
  #pragma unroll
  for (int k = 2; k <= 16; k <<= 1) {
    #pragma unroll
    for (int j = k >> 1; j > 0; j >>= 1) {
      #pragma unroll
      for (int i = 0; i < 16; ++i) {
        int l = i ^ j;
        if (l > i) {
          if ((i & k) == 0) ce(d[i], ix[i], d[l], ix[l]);
          else              ce(d[l], ix[l], d[i], ix[i]);
        }
      }
    }
  }
}

__device__ __forceinline__ void bimerge32(float (&rd)[32], int (&ri)[32]) {
  #pragma unroll
  for (int j = 16; j > 0; j >>= 1) {
    #pragma unroll
    for (int i = 0; i < 32; ++i) {
      int l = i ^ j;
      if (l > i) ce(rd[i], ri[i], rd[l], ri[l]);
    }
  }
}

__device__ __forceinline__ void merge16(float (&rd)[32], int (&ri)[32],
                                        float (&bd)[16], int (&bi)[16]) {
  #pragma unroll
  for (int k = 0; k < 16; ++k) {
    bool sw = bd[15-k] < rd[16+k];
    rd[16+k] = sw ? bd[15-k] : rd[16+k];
    ri[16+k] = sw ? bi[15-k] : ri[16+k];
  }
  bimerge32(rd, ri);
}

__device__ __forceinline__ void mergelane(float (&rd)[32], int (&ri)[32], int mask) {
  float pd[32]; int pi[32];
  #pragma unroll
  for (int s = 0; s < 32; ++s) { pd[s] = __shfl_xor(rd[s], mask); pi[s] = __shfl_xor(ri[s], mask); }
  #pragma unroll
  for (int k = 0; k < 32; ++k) {
    bool sw = pd[31-k] < rd[k];
    rd[k] = sw ? pd[31-k] : rd[k];
    ri[k] = sw ? pi[31-k] : ri[k];
  }
  bimerge32(rd, ri);
}

// ---------------- init (atomic accumulators must be reset EVERY launch) ----------------
__global__ void k_init(float* sum1, float* sum2, float* sumF, unsigned* hpmx, unsigned* hpmn) {
  int t = blockIdx.x*256 + threadIdx.x;
  if (t < 128) sum1[t] = 0.f;
  if (t < 256) sum2[t] = 0.f;
  if (t < 512) sumF[t] = 0.f;
  if (t < 2048) { hpmx[t] = 0u; hpmn[t] = 0x7f800000u; }   // relu>=0 -> uint order == float order
}

// ---------------- f0 = [pos,x], ssq0 ----------------
__global__ __launch_bounds__(256) void k_f0(const float* __restrict__ pos, const float* __restrict__ x,
                                            float4* __restrict__ f0, float* __restrict__ ssq) {
  int i = blockIdx.x*256 + threadIdx.x;
  if (i >= NPTS) return;
  float4 f;
  f.x = pos[3*i+0]; f.y = pos[3*i+1]; f.z = pos[3*i+2]; f.w = x[i];
  f0[i] = f;
  ssq[i] = dot4f(f, f);
}

// ---------------- knn1: global 16384-point knn in 4-d, TWO-PHASE exact ----------------
__global__ __launch_bounds__(256) void k_knn1(const float4* __restrict__ f0, const float* __restrict__ ssq,
                                              int* __restrict__ idx1) {
  __shared__ __align__(16) float4 tf[1024];
  __shared__ float tq[1024];
  __shared__ float2 surv[8][SCAP];
  __shared__ int scnt[8];
  int t = threadIdx.x;
  int r = t >> 5;
  int lane = t & 31;
  int row = blockIdx.x*8 + r;
  if (t < 8) scnt[t] = 0;
  float4 fi = f0[row];
  float sqi = ssq[row];
  float rd[32]; int ri[32];
  #pragma unroll
  for (int s = 0; s < 32; ++s) { rd[s] = INFINITY; ri[s] = 0; }
  // ---- pass 1: sample = candidates [0, 2048)
  for (int tile = 0; tile < 2; ++tile) {
    int base = tile*1024;
    __syncthreads();
    #pragma unroll
    for (int v = 0; v < 4; ++v) { tf[t+v*256] = f0[base+t+v*256]; tq[t+v*256] = ssq[base+t+v*256]; }
    __syncthreads();
    #pragma unroll
    for (int b = 0; b < 2; ++b) {
      float bd[16]; int bix[16];
      #pragma unroll
      for (int u = 0; u < 16; ++u) {
        int jl = b*512 + u*32 + lane;
        bd[u] = (sqi - 2.f*dot4f(fi, tf[jl])) + tq[jl];
        bix[u] = base + jl;
      }
      sort16(bd, bix);
      merge16(rd, ri, bd, bix);
    }
  }
  mergelane(rd, ri, 1); mergelane(rd, ri, 2); mergelane(rd, ri, 4);
  mergelane(rd, ri, 8); mergelane(rd, ri, 16);
  float T0 = rd[19];              // row-uniform after butterfly merges
  // ---- pass 2: filter all 16384 candidates
  for (int tile = 0; tile < 16; ++tile) {
    int base = tile*1024;
    __syncthreads();
    #pragma unroll
    for (int v = 0; v < 4; ++v) { tf[t+v*256] = f0[base+t+v*256]; tq[t+v*256] = ssq[base+t+v*256]; }
    __syncthreads();
    #pragma unroll 4
    for (int s = 0; s < 32; ++s) {
      int jl = s*32 + lane;
      float d = (sqi - 2.f*dot4f(fi, tf[jl])) + tq[jl];
      if (d <= T0) {
        int slot = atomicAdd(&scnt[r], 1);
        if (slot < SCAP) surv[r][slot] = make_float2(d, __int_as_float(base + jl));
      }
    }
  }
  __syncthreads();
  int n = scnt[r] < SCAP ? scnt[r] : SCAP;
  // ---- pass 3: exact top-20 of survivors
  #pragma unroll
  for (int s = 0; s < 32; ++s) { rd[s] = INFINITY; ri[s] = 0; }
  {
    float bd[16]; int bix[16];
    #pragma unroll
    for (int u = 0; u < 16; ++u) {
      int s = u*32 + lane;
      if (s < n) { float2 v = surv[r][s]; bd[u] = v.x; bix[u] = __float_as_int(v.y); }
      else       { bd[u] = INFINITY; bix[u] = 0; }
    }
    sort16(bd, bix);
    merge16(rd, ri, bd, bix);
  }
  mergelane(rd, ri, 1); mergelane(rd, ri, 2); mergelane(rd, ri, 4);
  mergelane(rd, ri, 8); mergelane(rd, ri, 16);
  if (lane == 0) {
    int4* p = (int4*)&idx1[row*KNB];
    p[0] = make_int4(ri[0],ri[1],ri[2],ri[3]);
    p[1] = make_int4(ri[4],ri[5],ri[6],ri[7]);
    p[2] = make_int4(ri[8],ri[9],ri[10],ri[11]);
    p[3] = make_int4(ri[12],ri[13],ri[14],ri[15]);
    p[4] = make_int4(ri[16],ri[17],ri[18],ri[19]);
  }
}

// ---------------- mlp1: edge MLP 8->64, relu, per-point max/min (pre-BN), channel sums ----------------
__global__ __launch_bounds__(256) void k_mlp1(const float4* __restrict__ f0, const int* __restrict__ idx1,
                                              const float* __restrict__ w1, const float* __restrict__ b1,
                                              float* __restrict__ xmx, float* __restrict__ xmn,
                                              float* __restrict__ sums) {
  __shared__ float rs[256], rs2[256];
  int t = threadIdx.x;
  int c = t & 63;
  int w = t >> 6;
  float wc[8];
  #pragma unroll
  for (int d = 0; d < 8; ++d) wc[d] = w1[d*64 + c];
  float bc = b1[c];
  float s = 0.f, s2 = 0.f;
  for (int p = 0; p < 8; ++p) {
    int i = blockIdx.x*32 + p*4 + w;
    float4 fi = f0[i];
    float mx = -INFINITY, mn = INFINITY;
    #pragma unroll
    for (int k = 0; k < KNB; ++k) {
      int j = idx1[i*KNB + k];
      float4 fj = f0[j];
      float h = bc + fi.x*wc[0] + fi.y*wc[1] + fi.z*wc[2] + fi.w*wc[3]
                   + (fj.x-fi.x)*wc[4] + (fj.y-fi.y)*wc[5] + (fj.z-fi.z)*wc[6] + (fj.w-fi.w)*wc[7];
      h = fmaxf(h, 0.f);
      mx = fmaxf(mx, h); mn = fminf(mn, h);
      s += h; s2 += h*h;
    }
    xmx[i*64+c] = mx; xmn[i*64+c] = mn;
  }
  rs[t] = s; rs2[t] = s2;
  __syncthreads();
  if (t < 64) {
    atomicAdd(&sums[c],      rs[t]+rs[t+64]+rs[t+128]+rs[t+192]);
    atomicAdd(&sums[64+c],   rs2[t]+rs2[t+64]+rs2[t+128]+rs2[t+192]);
  }
}

// ---------------- bn1 apply: x1 = affine(max or min by scale sign) ----------------
__global__ __launch_bounds__(256) void k_bn1apply(const float* __restrict__ sums, const float* __restrict__ g,
                                                  const float* __restrict__ be, const float* __restrict__ xmx,
                                                  const float* __restrict__ xmn, float* __restrict__ x1) {
  __shared__ float sc_s[64], sh_s[64];
  int t = threadIdx.x;
  if (t < 64) {
    float m = sums[t] * (1.f/327680.f);
    float v = sums[64+t] * (1.f/327680.f) - m*m;
    float sc = g[t] / sqrtf(v + 1e-5f);
    sc_s[t] = sc; sh_s[t] = be[t] - m*sc;
  }
  __syncthreads();
  int c = t & 63;
  int i = blockIdx.x*4 + (t>>6);
  float sc = sc_s[c], sh = sh_s[c];
  float val = (sc >= 0.f) ? xmx[i*64+c] : xmn[i*64+c];
  x1[i*64+c] = sc*val + sh;
}

// ---------------- ssq1 (same dot64v ordering as knn2 for exact self-distance) ----------------
__global__ __launch_bounds__(256) void k_ssq1(const float* __restrict__ x1, float* __restrict__ ssq1) {
  int i = blockIdx.x*256 + threadIdx.x;
  alignas(16) float f[64];
  #pragma unroll
  for (int d4 = 0; d4 < 16; ++d4) ((float4*)f)[d4] = ((const float4*)x1)[i*16 + d4];
  ssq1[i] = dot64v(f, (const float4*)f);
}

// ---------------- knn2: per-batch knn over 2048 points in 64-d ----------------
__global__ __launch_bounds__(256) void k_knn2(const float* __restrict__ x1, const float* __restrict__ ssq1,
                                              int* __restrict__ idx2) {
  __shared__ __align__(16) float tf[128][68];   // pad 68 -> conflict-light reads
  __shared__ float tq[128];
  int t = threadIdx.x;
  int row = blockIdx.x*32 + (t>>3);
  int lane = t & 7;
  int cbase = (row >> 11) << 11;                // batch column base
  alignas(16) float fi[64];
  #pragma unroll
  for (int d4 = 0; d4 < 16; ++d4) ((float4*)fi)[d4] = ((const float4*)x1)[row*16 + d4];
  float sqi = ssq1[row];
  float rd[32]; int ri[32];
  #pragma unroll
  for (int s = 0; s < 32; ++s) { rd[s] = INFINITY; ri[s] = 0; }
  for (int tile = 0; tile < 16; ++tile) {
    int base = cbase + tile*128;
    __syncthreads();
    for (int v = t; v < 128*16; v += 256) {
      int jl = v >> 4, d4 = v & 15;
      *(float4*)&tf[jl][d4*4] = ((const float4*)x1)[(base+jl)*16 + d4];
    }
    if (t < 128) tq[t] = ssq1[base + t];
    __syncthreads();
    float bd[16]; int bix[16];
    #pragma unroll
    for (int u = 0; u < 16; ++u) {
      int jl = u*8 + lane;
      bd[u] = (sqi - 2.f*dot64v(fi, (const float4*)&tf[jl][0])) + tq[jl];
      bix[u] = base + jl;
    }
    sort16(bd, bix);
    merge16(rd, ri, bd, bix);
  }
  mergelane(rd, ri, 1);
  mergelane(rd, ri, 2);
  mergelane(rd, ri, 4);
  if (lane == 0) {
    int4* p = (int4*)&idx2[row*KNB];
    p[0] = make_int4(ri[0],ri[1],ri[2],ri[3]);
    p[1] = make_int4(ri[4],ri[5],ri[6],ri[7]);
    p[2] = make_int4(ri[8],ri[9],ri[10],ri[11]);
    p[3] = make_int4(ri[12],ri[13],ri[14],ri[15]);
    p[4] = make_int4(ri[16],ri[17],ri[18],ri[19]);
  }
}

// ---------------- mlp2: edge MLP 128->128 via bf16 MFMA (fp32 accum) ----------------
// 4 points/block (each padded to 32 edge-rows), 4 waves; wave w owns output cols
// [w*32, w*32+32). E and W^T staged in LDS as bf16 with 136-short row pitch
// (272B -> b128 frag reads conflict-free). C/D layout (m89-verified):
// col = lane&15, row = (lane>>4)*4 + reg. Rows >= 20 are zero-padded and masked
// out of max/min/sums. x2 path is continuous (no top-k downstream) -> bf16 safe.
__global__ __launch_bounds__(256) void k_mlp2(const float* __restrict__ x1, const int* __restrict__ idx2,
                                              const float* __restrict__ w2, const float* __restrict__ b2,
                                              float* __restrict__ xmx, float* __restrict__ xmn,
                                              float* __restrict__ sums) {
  __shared__ __align__(16) short WT[128*136];     // WT[c][k] = bf16(w2[k][c])
  __shared__ __align__(16) short Elds[4*32*136];  // [p][row][k]
  __shared__ int js[4][KNB];
  int t = threadIdx.x;
  // stage W^T (coalesced read, scattered one-time LDS write)
  for (int v = t; v < 128*32; v += 256) {
    int d = v >> 5, c4 = (v & 31)*4;
    float4 w = ((const float4*)w2)[v];
    WT[(c4+0)*136 + d] = f2bf(w.x);
    WT[(c4+1)*136 + d] = f2bf(w.y);
    WT[(c4+2)*136 + d] = f2bf(w.z);
    WT[(c4+3)*136 + d] = f2bf(w.w);
  }
  if (t < 4*KNB) js[t/KNB][t%KNB] = idx2[blockIdx.x*4*KNB + t];
  __syncthreads();
  // stage E (bf16): 4 pts x 32 rows x 16 chunks of 8 values
  #pragma unroll
  for (int cc = 0; cc < 8; ++cc) {
    int v = t + cc*256;
    int p  = v >> 9;
    int rr = (v >> 4) & 31;
    int kc = v & 15;
    short8 outv = {0,0,0,0,0,0,0,0};
    if (rr < KNB) {
      int i = blockIdx.x*4 + p;
      float4 a0, a1;
      if (kc < 8) {
        a0 = ((const float4*)x1)[i*16 + kc*2];
        a1 = ((const float4*)x1)[i*16 + kc*2 + 1];
      } else {
        int j = js[p][rr];
        int kk = kc - 8;
        float4 j0 = ((const float4*)x1)[j*16 + kk*2];
        float4 j1 = ((const float4*)x1)[j*16 + kk*2 + 1];
        float4 i0 = ((const float4*)x1)[i*16 + kk*2];
        float4 i1 = ((const float4*)x1)[i*16 + kk*2 + 1];
        a0 = make_float4(j0.x-i0.x, j0.y-i0.y, j0.z-i0.z, j0.w-i0.w);
        a1 = make_float4(j1.x-i1.x, j1.y-i1.y, j1.z-i1.z, j1.w-i1.w);
      }
      outv[0]=f2bf(a0.x); outv[1]=f2bf(a0.y); outv[2]=f2bf(a0.z); outv[3]=f2bf(a0.w);
      outv[4]=f2bf(a1.x); outv[5]=f2bf(a1.y); outv[6]=f2bf(a1.z); outv[7]=f2bf(a1.w);
    }
    *(short8*)&Elds[p*4352 + rr*136 + kc*8] = outv;
  }
  __syncthreads();
  // compute
  int w = t >> 6, l = t & 63;
  int colA = w*32 + (l & 15);
  int colB = colA + 16;
  short8 bf[2][4];
  #pragma unroll
  for (int n = 0; n < 2; ++n)
    #pragma unroll
    for (int kb = 0; kb < 4; ++kb) {
      int col = w*32 + n*16 + (l & 15);
      int k0 = kb*32 + (l >> 4)*8;
      bf[n][kb] = *(short8*)&WT[col*136 + k0];
    }
  float bc0 = b2[colA], bc1 = b2[colB];
  float sT0=0.f, qT0=0.f, sT1=0.f, qT1=0.f;
  #pragma unroll
  for (int p = 0; p < 4; ++p) {
    int i = blockIdx.x*4 + p;
    float mx0=-INFINITY, mn0=INFINITY, s0=0.f, q0=0.f;
    float mx1=-INFINITY, mn1=INFINITY, s1=0.f, q1=0.f;
    #pragma unroll
    for (int m = 0; m < 2; ++m) {
      short8 af[4];
      #pragma unroll
      for (int kb = 0; kb < 4; ++kb) {
        int row = m*16 + (l & 15);
        int k0 = kb*32 + (l >> 4)*8;
        af[kb] = *(short8*)&Elds[p*4352 + row*136 + k0];
      }
      f32x4 acc0 = {0.f,0.f,0.f,0.f};
      f32x4 acc1 = {0.f,0.f,0.f,0.f};
      #pragma unroll
      for (int kb = 0; kb < 4; ++kb) {
        acc0 = __builtin_amdgcn_mfma_f32_16x16x32_bf16(af[kb], bf[0][kb], acc0, 0, 0, 0);
        acc1 = __builtin_amdgcn_mfma_f32_16x16x32_bf16(af[kb], bf[1][kb], acc1, 0, 0, 0);
      }
      int rbase = (l >> 4)*4 + m*16;
      #pragma unroll
      for (int reg = 0; reg < 4; ++reg) {
        bool valid = (rbase + reg) < KNB;
        float h0 = fmaxf(acc0[reg] + bc0, 0.f);
        float h1 = fmaxf(acc1[reg] + bc1, 0.f);
        if (valid) {
          mx0 = fmaxf(mx0, h0); mn0 = fminf(mn0, h0); s0 += h0; q0 += h0*h0;
          mx1 = fmaxf(mx1, h1); mn1 = fminf(mn1, h1); s1 += h1; q1 += h1*h1;
        }
      }
    }
    // butterfly over the 4 lane-groups sharing each col
    #pragma unroll
    for (int dlt = 16; dlt <= 32; dlt <<= 1) {
      mx0 = fmaxf(mx0, __shfl_xor(mx0, dlt)); mn0 = fminf(mn0, __shfl_xor(mn0, dlt));
      s0 += __shfl_xor(s0, dlt);              q0 += __shfl_xor(q0, dlt);
      mx1 = fmaxf(mx1, __shfl_xor(mx1, dlt)); mn1 = fminf(mn1, __shfl_xor(mn1, dlt));
      s1 += __shfl_xor(s1, dlt);              q1 += __shfl_xor(q1, dlt);
    }
    if (l < 16) {
      xmx[i*128 + colA] = mx0; xmx[i*128 + colB] = mx1;
      xmn[i*128 + colA] = mn0; xmn[i*128 + colB] = mn1;
    }
    sT0 += s0; qT0 += q0; sT1 += s1; qT1 += q1;
  }
  if (l < 16) {
    atomicAdd(&sums[colA], sT0);       atomicAdd(&sums[colB], sT1);
    atomicAdd(&sums[128 + colA], qT0); atomicAdd(&sums[128 + colB], qT1);
  }
}

// ---------------- bn2 apply ----------------
__global__ __launch_bounds__(256) void k_bn2apply(const float* __restrict__ sums, const float* __restrict__ g,
                                                  const float* __restrict__ be, const float* __restrict__ xmx,
                                                  const float* __restrict__ xmn, float* __restrict__ x2) {
  __shared__ float sc_s[128], sh_s[128];
  int t = threadIdx.x;
  if (t < 128) {
    float m = sums[t] * (1.f/327680.f);
    float v = sums[128+t] * (1.f/327680.f) - m*m;
    float sc = g[t] / sqrtf(v + 1e-5f);
    sc_s[t] = sc; sh_s[t] = be[t] - m*sc;
  }
  __syncthreads();
  int c = t & 127;
  int i = blockIdx.x*2 + (t>>7);
  float sc = sc_s[c], sh = sh_s[c];
  float val = (sc >= 0.f) ? xmx[i*128+c] : xmn[i*128+c];
  x2[i*128+c] = sc*val + sh;
}

// ---------------- gemmF: relu([x1|x2] @ wf + bf); channel sums + per-batch max/min only ----------------
__global__ __launch_bounds__(256) void k_gemmF(const float* __restrict__ x1, const float* __restrict__ x2,
                                               const float* __restrict__ wf, const float* __restrict__ bf,
                                               float* __restrict__ sumsF, unsigned* __restrict__ hpmx,
                                               unsigned* __restrict__ hpmn) {
  __shared__ float A_s[64*193];
  __shared__ __align__(16) float B_s[192*64];
  __shared__ float red[1024];
  int t = threadIdx.x;
  int rt = blockIdx.x >> 2;
  int ct = blockIdx.x & 3;
  for (int v = t; v < 64*48; v += 256) {
    int r = v / 48, gg = v - r*48;
    int row = rt*64 + r;
    float4 e = (gg < 16) ? ((const float4*)x1)[row*16 + gg]
                         : ((const float4*)x2)[row*32 + (gg-16)];
    float* p = &A_s[r*193 + gg*4];
    p[0]=e.x; p[1]=e.y; p[2]=e.z; p[3]=e.w;
  }
  for (int v = t; v < 192*16; v += 256) {
    int d = v >> 4, c4 = v & 15;
    *(float4*)&B_s[d*64 + c4*4] = ((const float4*)wf)[d*64 + ct*16 + c4];
  }
  __syncthreads();
  int rg = t & 15, cg = t >> 4;
  float acc[4][4];
  #pragma unroll
  for (int a=0;a<4;a++) { acc[a][0]=0.f; acc[a][1]=0.f; acc[a][2]=0.f; acc[a][3]=0.f; }
  for (int d = 0; d < 192; ++d) {
    float a0 = A_s[(rg*4+0)*193 + d];
    float a1 = A_s[(rg*4+1)*193 + d];
    float a2 = A_s[(rg*4+2)*193 + d];
    float a3 = A_s[(rg*4+3)*193 + d];
    float b0 = B_s[d*64 + cg];
    float b1 = B_s[d*64 + cg + 16];
    float b2 = B_s[d*64 + cg + 32];
    float b3 = B_s[d*64 + cg + 48];
    acc[0][0]+=a0*b0; acc[0][1]+=a0*b1; acc[0][2]+=a0*b2; acc[0][3]+=a0*b3;
    acc[1][0]+=a1*b0; acc[1][1]+=a1*b1; acc[1][2]+=a1*b2; acc[1][3]+=a1*b3;
    acc[2][0]+=a2*b0; acc[2][1]+=a2*b1; acc[2][2]+=a2*b2; acc[2][3]+=a2*b3;
    acc[3][0]+=a3*b0; acc[3][1]+=a3*b1; acc[3][2]+=a3*b2; acc[3][3]+=a3*b3;
  }
  float hv[4][4];
  #pragma unroll
  for (int ss=0; ss<4; ++ss) {
    float bb = bf[ct*64 + cg + ss*16];
    #pragma unroll
    for (int rr=0; rr<4; ++rr) hv[rr][ss] = fmaxf(acc[rr][ss] + bb, 0.f);
  }
  int b = rt >> 5;
  #pragma unroll
  for (int ss=0; ss<4; ++ss) red[rg*64 + cg + ss*16] = hv[0][ss]+hv[1][ss]+hv[2][ss]+hv[3][ss];
  __syncthreads();
  if (t < 64) {
    float v = 0.f;
    #pragma unroll
    for (int r=0;r<16;r++) v += red[r*64 + t];
    atomicAdd(&sumsF[ct*64 + t], v);
  }
  __syncthreads();
  #pragma unroll
  for (int ss=0; ss<4; ++ss) red[rg*64 + cg + ss*16] =
      hv[0][ss]*hv[0][ss]+hv[1][ss]*hv[1][ss]+hv[2][ss]*hv[2][ss]+hv[3][ss]*hv[3][ss];
  __syncthreads();
  if (t < 64) {
    float v = 0.f;
    #pragma unroll
    for (int r=0;r<16;r++) v += red[r*64 + t];
    atomicAdd(&sumsF[256 + ct*64 + t], v);
  }
  __syncthreads();
  #pragma unroll
  for (int ss=0; ss<4; ++ss) red[rg*64 + cg + ss*16] =
      fmaxf(fmaxf(hv[0][ss],hv[1][ss]), fmaxf(hv[2][ss],hv[3][ss]));
  __syncthreads();
  if (t < 64) {
    float v = -INFINITY;
    #pragma unroll
    for (int r=0;r<16;r++) v = fmaxf(v, red[r*64 + t]);
    atomicMax(&hpmx[b*256 + ct*64 + t], __float_as_uint(v));
  }
  __syncthreads();
  #pragma unroll
  for (int ss=0; ss<4; ++ss) red[rg*64 + cg + ss*16] =
      fminf(fminf(hv[0][ss],hv[1][ss]), fminf(hv[2][ss],hv[3][ss]));
  __syncthreads();
  if (t < 64) {
    float v = INFINITY;
    #pragma unroll
    for (int r=0;r<16;r++) v = fminf(v, red[r*64 + t]);
    atomicMin(&hpmn[b*256 + ct*64 + t], __float_as_uint(v));
  }
}

// ---------------- head ----------------
__global__ __launch_bounds__(256) void k_head(const float* __restrict__ sumsF, const float* __restrict__ gf,
                                              const float* __restrict__ bef,
                                              const unsigned* __restrict__ hpmx, const unsigned* __restrict__ hpmn,
                                              const float* __restrict__ wo1, const float* __restrict__ bo1,
                                              const float* __restrict__ go1, const float* __restrict__ beo1,
                                              const float* __restrict__ wo2, const float* __restrict__ bo2,
                                              const float* __restrict__ go2, const float* __restrict__ beo2,
                                              const float* __restrict__ wo3, const float* __restrict__ bo3,
                                              float* __restrict__ out) {
  __shared__ float hp[8][256];
  __shared__ float u1[8][128];
  __shared__ float u2[8][64];
  __shared__ float lg[8][16];
  int t = threadIdx.x;
  {
    float m = sumsF[t] * (1.f/16384.f);
    float v = sumsF[256+t] * (1.f/16384.f) - m*m;
    float sc = gf[t] / sqrtf(v + 1e-5f);
    float sh = bef[t] - m*sc;
    for (int b = 0; b < 8; ++b) {
      unsigned bits = (sc >= 0.f) ? hpmx[b*256+t] : hpmn[b*256+t];
      hp[b][t] = sc*__uint_as_float(bits) + sh;
    }
  }
  __syncthreads();
  for (int p = t; p < 1024; p += 256) {
    int b = p >> 7, c = p & 127;
    float z = bo1[c];
    for (int d = 0; d < 256; ++d) z += hp[b][d]*wo1[d*128+c];
    u1[b][c] = fmaxf(z, 0.f);
  }
  __syncthreads();
  if (t < 128) {
    float m = 0.f;
    for (int b=0;b<8;b++) m += u1[b][t];
    m *= 0.125f;
    float v = 0.f;
    for (int b=0;b<8;b++) { float dd = u1[b][t]-m; v += dd*dd; }
    v *= 0.125f;
    float sc = go1[t]/sqrtf(v+1e-5f), sh = beo1[t]-m*sc;
    for (int b=0;b<8;b++) u1[b][t] = sc*u1[b][t]+sh;
  }
  __syncthreads();
  for (int p = t; p < 512; p += 256) {
    int b = p >> 6, c = p & 63;
    float z = bo2[c];
    for (int d = 0; d < 128; ++d) z += u1[b][d]*wo2[d*64+c];
    u2[b][c] = fmaxf(z, 0.f);
  }
  __syncthreads();
  if (t < 64) {
    float m = 0.f;
    for (int b=0;b<8;b++) m += u2[b][t];
    m *= 0.125f;
    float v = 0.f;
    for (int b=0;b<8;b++) { float dd = u2[b][t]-m; v += dd*dd; }
    v *= 0.125f;
    float sc = go2[t]/sqrtf(v+1e-5f), sh = beo2[t]-m*sc;
    for (int b=0;b<8;b++) u2[b][t] = sc*u2[b][t]+sh;
  }
  __syncthreads();
  if (t < 128) {
    int b = t >> 4, c = t & 15;
    float z = bo3[c];
    for (int d = 0; d < 64; ++d) z += u2[b][d]*wo3[d*16+c];
    lg[b][c] = z;
  }
  __syncthreads();
  if (t < 8) {
    float m = -INFINITY;
    for (int j=0;j<16;j++) m = fmaxf(m, lg[t][j]);
    float s = 0.f;
    for (int j=0;j<16;j++) s += expf(lg[t][j]-m);
    float ls = logf(s);
    for (int j=0;j<16;j++) out[t*16+j] = (lg[t][j]-m) - ls;
  }
}

// ---------------- launch ----------------
extern "C" void kernel_launch(void* const* d_in, const int* in_sizes, int n_in,
                              void* d_out, int out_size, void* d_ws, size_t ws_size,
                              hipStream_t stream) {
  (void)in_sizes; (void)n_in; (void)out_size; (void)ws_size;
  const float* pos = (const float*)d_in[0];
  const float* x   = (const float*)d_in[1];
  const float* w1  = (const float*)d_in[3];
  const float* b1  = (const float*)d_in[4];
  const float* g1  = (const float*)d_in[5];
  const float* be1 = (const float*)d_in[6];
  const float* w2  = (const float*)d_in[7];
  const float* b2  = (const float*)d_in[8];
  const float* g2  = (const float*)d_in[9];
  const float* be2 = (const float*)d_in[10];
  const float* wf  = (const float*)d_in[11];
  const float* bf  = (const float*)d_in[12];
  const float* gf  = (const float*)d_in[13];
  const float* bef = (const float*)d_in[14];
  const float* wo1 = (const float*)d_in[15];
  const float* bo1 = (const float*)d_in[16];
  const float* go1 = (const float*)d_in[17];
  const float* beo1= (const float*)d_in[18];
  const float* wo2 = (const float*)d_in[19];
  const float* bo2 = (const float*)d_in[20];
  const float* go2 = (const float*)d_in[21];
  const float* beo2= (const float*)d_in[22];
  const float* wo3 = (const float*)d_in[23];
  const float* bo3 = (const float*)d_in[24];

  char* ws = (char*)d_ws;
  float4*   f0    = (float4*)  (ws + OFF_F0);
  float*    ssq0  = (float*)   (ws + OFF_SSQ0);
  int*      idx1  = (int*)     (ws + OFF_IDX1);
  float*    xmx1  = (float*)   (ws + OFF_XMX1);
  float*    xmn1  = (float*)   (ws + OFF_XMN1);
  float*    sum1  = (float*)   (ws + OFF_SUM1);
  float*    x1    = (float*)   (ws + OFF_X1);
  float*    ssq1  = (float*)   (ws + OFF_SSQ1);
  int*      idx2  = (int*)     (ws + OFF_IDX2);
  float*    xmx2  = (float*)   (ws + OFF_XMX2);
  float*    xmn2  = (float*)   (ws + OFF_XMN2);
  float*    sum2  = (float*)   (ws + OFF_SUM2);
  float*    x2    = (float*)   (ws + OFF_X2);
  float*    sumF  = (float*)   (ws + OFF_SUMF);
  unsigned* hpmx  = (unsigned*)(ws + OFF_HPMX);
  unsigned* hpmn  = (unsigned*)(ws + OFF_HPMN);

  k_init    <<<8,    256, 0, stream>>>(sum1, sum2, sumF, hpmx, hpmn);
  k_f0      <<<64,   256, 0, stream>>>(pos, x, f0, ssq0);
  k_knn1    <<<2048, 256, 0, stream>>>(f0, ssq0, idx1);
  k_mlp1    <<<512,  256, 0, stream>>>(f0, idx1, w1, b1, xmx1, xmn1, sum1);
  k_bn1apply<<<4096, 256, 0, stream>>>(sum1, g1, be1, xmx1, xmn1, x1);
  k_ssq1    <<<64,   256, 0, stream>>>(x1, ssq1);
  k_knn2    <<<512,  256, 0, stream>>>(x1, ssq1, idx2);
  k_mlp2    <<<4096, 256, 0, stream>>>(x1, idx2, w2, b2, xmx2, xmn2, sum2);
  k_bn2apply<<<8192, 256, 0, stream>>>(sum2, g2, be2, xmx2, xmn2, x2);
  k_gemmF   <<<1024, 256, 0, stream>>>(x1, x2, wf, bf, sumF, hpmx, hpmn);
  k_head    <<<1,    256, 0, stream>>>(sumF, gf, bef, hpmx, hpmn,
                                       wo1, bo1, go1, beo1, wo2, bo2, go2, beo2, wo3, bo3,
                                       (float*)d_out);
}

// Round 8
// 682.833 us; speedup vs baseline: 3.7258x; 1.1336x over previous
//
#include <hip/hip_runtime.h>
#include <math.h>

#define NPTS 16384
#define KNB 20
#define SCAP 512

typedef __attribute__((ext_vector_type(8))) short short8;
typedef __attribute__((ext_vector_type(4))) float f32x4;

// ---------------- workspace layout (bytes, all naturally 256-aligned) ----------------
static const size_t OFF_F0   = 0;                                   // N x float4
static const size_t OFF_SSQ0 = OFF_F0   + (size_t)NPTS*4*4;         // N f32
static const size_t OFF_IDX1 = OFF_SSQ0 + (size_t)NPTS*4;           // N*20 i32
static const size_t OFF_XMX1 = OFF_IDX1 + (size_t)NPTS*KNB*4;       // N*64 f32
static const size_t OFF_XMN1 = OFF_XMX1 + (size_t)NPTS*64*4;        // N*64 f32
static const size_t OFF_SUM1 = OFF_XMN1 + (size_t)NPTS*64*4;        // 128 f32 (sum,sumsq)
static const size_t OFF_X1   = OFF_SUM1 + 512;                      // N*64 f32
static const size_t OFF_SSQ1 = OFF_X1   + (size_t)NPTS*64*4;        // N f32
static const size_t OFF_IDX2 = OFF_SSQ1 + (size_t)NPTS*4;           // N*20 i32 (global idx)
static const size_t OFF_XMX2 = OFF_IDX2 + (size_t)NPTS*KNB*4;       // N*128 f32
static const size_t OFF_XMN2 = OFF_XMX2 + (size_t)NPTS*128*4;       // N*128 f32
static const size_t OFF_SUM2 = OFF_XMN2 + (size_t)NPTS*128*4;       // 256 f32
static const size_t OFF_X2   = OFF_SUM2 + 1024;                     // N*128 f32
static const size_t OFF_SUMF = OFF_X2   + (size_t)NPTS*128*4;       // 512 f32
static const size_t OFF_HPMX = OFF_SUMF + 2048;                     // 8*256 u32 (float bits)
static const size_t OFF_HPMN = OFF_HPMX + 8*256*4;                  // 8*256 u32
// WT_g (bf16 W^T for mlp2, 32 KB) ALIASES xmx1 (dead after bn1apply; wprep runs after bn1apply)

// ---------------- helpers ----------------
__device__ __forceinline__ float dot4f(float4 a, float4 b) {
  return a.x*b.x + a.y*b.y + a.z*b.z + a.w*b.w;
}

__device__ __forceinline__ float dot64v(const float* a, const float4* b4) {
  float s = 0.f;
  #pragma unroll
  for (int d4 = 0; d4 < 16; ++d4) {
    float4 b = b4[d4];
    s += a[4*d4+0]*b.x + a[4*d4+1]*b.y + a[4*d4+2]*b.z + a[4*d4+3]*b.w;
  }
  return s;
}

// f32 -> bf16 (RNE)
__device__ __forceinline__ short f2bf(float x) {
  union { float f; unsigned u; } v; v.f = x;
  unsigned r = (v.u + 0x7FFFu + ((v.u >> 16) & 1u)) >> 16;
  return (short)r;
}

// ---------------- branch-free sorting-network top-k machinery (with indices) ----------------
__device__ __forceinline__ void ce(float& a, int& ai, float& b, int& bi) {
  bool sw = b < a;
  float d0 = sw ? b : a;  float d1 = sw ? a : b;
  int   j0 = sw ? bi : ai; int  j1 = sw ? ai : bi;
  a = d0; ai = j0; b = d1; bi = j1;
}

__device__ __forceinline__ void sort16(float (&d)[16], int (&ix)[16]) {
  #pragma unroll
  for (int k = 2; k <= 16; k <<= 1) {
    #pragma unroll
    for (int j = k >> 1; j > 0; j >>= 1) {
      #pragma unroll
      for (int i = 0; i < 16; ++i) {
        int l = i ^ j;
        if (l > i) {
          if ((i & k) == 0) ce(d[i], ix[i], d[l], ix[l]);
          else              ce(d[l], ix[l], d[i], ix[i]);
        }
      }
    }
  }
}

__device__ __forceinline__ void bimerge32(float (&rd)[32], int (&ri)[32]) {
  #pragma unroll
  for (int j = 16; j > 0; j >>= 1) {
    #pragma unroll
    for (int i = 0; i < 32; ++i) {
      int l = i ^ j;
      if (l > i) ce(rd[i], ri[i], rd[l], ri[l]);
    }
  }
}

__device__ __forceinline__ void merge16(float (&rd)[32], int (&ri)[32],
                                        float (&bd)[16], int (&bi)[16]) {
  #pragma unroll
  for (int k = 0; k < 16; ++k) {
    bool sw = bd[15-k] < rd[16+k];
    rd[16+k] = sw ? bd[15-k] : rd[16+k];
    ri[16+k] = sw ? bi[15-k] : ri[16+k];
  }
  bimerge32(rd, ri);
}

__device__ __forceinline__ void mergelane(float (&rd)[32], int (&ri)[32], int mask) {
  float pd[32]; int pi[32];
  #pragma unroll
  for (int s = 0; s < 32; ++s) { pd[s] = __shfl_xor(rd[s], mask); pi[s] = __shfl_xor(ri[s], mask); }
  #pragma unroll
  for (int k = 0; k < 32; ++k) {
    bool sw = pd[31-k] < rd[k];
    rd[k] = sw ? pd[31-k] : rd[k];
    ri[k] = sw ? pi[31-k] : ri[k];
  }
  bimerge32(rd, ri);
}

// ---------------- value-only versions (threshold computation, 2 ops/CE) ----------------
__device__ __forceinline__ void vce(float& a, float& b) {
  float lo = fminf(a, b);
  b = fmaxf(a, b);
  a = lo;
}

__device__ __forceinline__ void vsort16(float (&d)[16]) {
  #pragma unroll
  for (int k = 2; k <= 16; k <<= 1) {
    #pragma unroll
    for (int j = k >> 1; j > 0; j >>= 1) {
      #pragma unroll
      for (int i = 0; i < 16; ++i) {
        int l = i ^ j;
        if (l > i) {
          if ((i & k) == 0) vce(d[i], d[l]);
          else              vce(d[l], d[i]);
        }
      }
    }
  }
}

__device__ __forceinline__ void vbimerge32(float (&rd)[32]) {
  #pragma unroll
  for (int j = 16; j > 0; j >>= 1) {
    #pragma unroll
    for (int i = 0; i < 32; ++i) {
      int l = i ^ j;
      if (l > i) vce(rd[i], rd[l]);
    }
  }
}

__device__ __forceinline__ void vmerge16(float (&rd)[32], float (&bd)[16]) {
  #pragma unroll
  for (int k = 0; k < 16; ++k) rd[16+k] = fminf(rd[16+k], bd[15-k]);
  vbimerge32(rd);
}

__device__ __forceinline__ void vmergelane(float (&rd)[32], int mask) {
  float pd[32];
  #pragma unroll
  for (int s = 0; s < 32; ++s) pd[s] = __shfl_xor(rd[s], mask);
  #pragma unroll
  for (int k = 0; k < 32; ++k) rd[k] = fminf(rd[k], pd[31-k]);
  vbimerge32(rd);
}

// ---------------- init (atomic accumulators must be reset EVERY launch) ----------------
__global__ void k_init(float* sum1, float* sum2, float* sumF, unsigned* hpmx, unsigned* hpmn) {
  int t = blockIdx.x*256 + threadIdx.x;
  if (t < 128) sum1[t] = 0.f;
  if (t < 256) sum2[t] = 0.f;
  if (t < 512) sumF[t] = 0.f;
  if (t < 2048) { hpmx[t] = 0u; hpmn[t] = 0x7f800000u; }   // relu>=0 -> uint order == float order
}

// ---------------- f0 = [pos,x], ssq0 ----------------
__global__ __launch_bounds__(256) void k_f0(const float* __restrict__ pos, const float* __restrict__ x,
                                            float4* __restrict__ f0, float* __restrict__ ssq) {
  int i = blockIdx.x*256 + threadIdx.x;
  if (i >= NPTS) return;
  float4 f;
  f.x = pos[3*i+0]; f.y = pos[3*i+1]; f.z = pos[3*i+2]; f.w = x[i];
  f0[i] = f;
  ssq[i] = dot4f(f, f);
}

// ---------------- knn1 v3: global-direct two-phase exact (no LDS tiles) ----------------
// 8 rows x 32 lanes, grid 2048. f0+ssq (384 KB) is L2-resident -> read direct.
// Pass 1: value-only exact 20th of sample [0,2048) -> per-row threshold T.
// Pass 2: candidate-major (each thread owns candidate j, reads it ONCE, tests
//         all 8 rows from registers; rare predicated LDS append). 8x less
//         traffic than row-major tiles.
// Pass 3: exact index top-20 of <=512 survivors (bitonic network).
__global__ __launch_bounds__(256) void k_knn1(const float4* __restrict__ f0, const float* __restrict__ ssq,
                                              int* __restrict__ idx1) {
  __shared__ float2 surv[8][SCAP];
  __shared__ int scnt[8];
  __shared__ float rowT[8];
  int t = threadIdx.x;
  int r = t >> 5;
  int lane = t & 31;
  int row = blockIdx.x*8 + r;
  if (t < 8) scnt[t] = 0;
  float4 fi = f0[row];
  float sqi = ssq[row];
  // ---- pass 1: value-only top-32 of sample
  {
    float rd[32];
    #pragma unroll
    for (int s = 0; s < 32; ++s) rd[s] = INFINITY;
    #pragma unroll
    for (int b = 0; b < 4; ++b) {
      float bd[16];
      #pragma unroll
      for (int u = 0; u < 16; ++u) {
        int j = b*512 + u*32 + lane;
        float4 c = f0[j];
        bd[u] = (sqi - 2.f*dot4f(fi, c)) + ssq[j];
      }
      vsort16(bd);
      vmerge16(rd, bd);
    }
    vmergelane(rd, 1); vmergelane(rd, 2); vmergelane(rd, 4);
    vmergelane(rd, 8); vmergelane(rd, 16);
    if (lane == 0) rowT[r] = rd[19];
  }
  __syncthreads();
  // ---- pass 2: candidate-major filter over all 16384
  {
    float4 fr[8]; float sr[8], Tr[8];
    #pragma unroll
    for (int q = 0; q < 8; ++q) {
      fr[q] = f0[blockIdx.x*8 + q];
      sr[q] = ssq[blockIdx.x*8 + q];
      Tr[q] = rowT[q];
    }
    #pragma unroll 4
    for (int k = 0; k < 64; ++k) {
      int j = k*256 + t;
      float4 c = f0[j];
      float cq = ssq[j];
      #pragma unroll
      for (int q = 0; q < 8; ++q) {
        float d = (sr[q] - 2.f*dot4f(fr[q], c)) + cq;
        if (d <= Tr[q]) {
          int slot = atomicAdd(&scnt[q], 1);
          if (slot < SCAP) surv[q][slot] = make_float2(d, __int_as_float(j));
        }
      }
    }
  }
  __syncthreads();
  int n = scnt[r] < SCAP ? scnt[r] : SCAP;
  // ---- pass 3: exact index top-20 of survivors
  float rd[32]; int ri[32];
  #pragma unroll
  for (int s = 0; s < 32; ++s) { rd[s] = INFINITY; ri[s] = 0; }
  {
    float bd[16]; int bix[16];
    #pragma unroll
    for (int u = 0; u < 16; ++u) {
      int s = u*32 + lane;
      if (s < n) { float2 v = surv[r][s]; bd[u] = v.x; bix[u] = __float_as_int(v.y); }
      else       { bd[u] = INFINITY; bix[u] = 0; }
    }
    sort16(bd, bix);
    merge16(rd, ri, bd, bix);
  }
  mergelane(rd, ri, 1); mergelane(rd, ri, 2); mergelane(rd, ri, 4);
  mergelane(rd, ri, 8); mergelane(rd, ri, 16);
  if (lane == 0) {
    int4* p = (int4*)&idx1[row*KNB];
    p[0] = make_int4(ri[0],ri[1],ri[2],ri[3]);
    p[1] = make_int4(ri[4],ri[5],ri[6],ri[7]);
    p[2] = make_int4(ri[8],ri[9],ri[10],ri[11]);
    p[3] = make_int4(ri[12],ri[13],ri[14],ri[15]);
    p[4] = make_int4(ri[16],ri[17],ri[18],ri[19]);
  }
}

// ---------------- mlp1: edge MLP 8->64, relu, per-point max/min (pre-BN), channel sums ----------------
__global__ __launch_bounds__(256) void k_mlp1(const float4* __restrict__ f0, const int* __restrict__ idx1,
                                              const float* __restrict__ w1, const float* __restrict__ b1,
                                              float* __restrict__ xmx, float* __restrict__ xmn,
                                              float* __restrict__ sums) {
  __shared__ float rs[256], rs2[256];
  int t = threadIdx.x;
  int c = t & 63;
  int w = t >> 6;
  float wc[8];
  #pragma unroll
  for (int d = 0; d < 8; ++d) wc[d] = w1[d*64 + c];
  float bc = b1[c];
  float s = 0.f, s2 = 0.f;
  for (int p = 0; p < 8; ++p) {
    int i = blockIdx.x*32 + p*4 + w;
    float4 fi = f0[i];
    float mx = -INFINITY, mn = INFINITY;
    #pragma unroll
    for (int k = 0; k < KNB; ++k) {
      int j = idx1[i*KNB + k];
      float4 fj = f0[j];
      float h = bc + fi.x*wc[0] + fi.y*wc[1] + fi.z*wc[2] + fi.w*wc[3]
                   + (fj.x-fi.x)*wc[4] + (fj.y-fi.y)*wc[5] + (fj.z-fi.z)*wc[6] + (fj.w-fi.w)*wc[7];
      h = fmaxf(h, 0.f);
      mx = fmaxf(mx, h); mn = fminf(mn, h);
      s += h; s2 += h*h;
    }
    xmx[i*64+c] = mx; xmn[i*64+c] = mn;
  }
  rs[t] = s; rs2[t] = s2;
  __syncthreads();
  if (t < 64) {
    atomicAdd(&sums[c],      rs[t]+rs[t+64]+rs[t+128]+rs[t+192]);
    atomicAdd(&sums[64+c],   rs2[t]+rs2[t+64]+rs2[t+128]+rs2[t+192]);
  }
}

// ---------------- bn1 apply: x1 = affine(max or min by scale sign) ----------------
__global__ __launch_bounds__(256) void k_bn1apply(const float* __restrict__ sums, const float* __restrict__ g,
                                                  const float* __restrict__ be, const float* __restrict__ xmx,
                                                  const float* __restrict__ xmn, float* __restrict__ x1) {
  __shared__ float sc_s[64], sh_s[64];
  int t = threadIdx.x;
  if (t < 64) {
    float m = sums[t] * (1.f/327680.f);
    float v = sums[64+t] * (1.f/327680.f) - m*m;
    float sc = g[t] / sqrtf(v + 1e-5f);
    sc_s[t] = sc; sh_s[t] = be[t] - m*sc;
  }
  __syncthreads();
  int c = t & 63;
  int i = blockIdx.x*4 + (t>>6);
  float sc = sc_s[c], sh = sh_s[c];
  float val = (sc >= 0.f) ? xmx[i*64+c] : xmn[i*64+c];
  x1[i*64+c] = sc*val + sh;
}

// ---------------- wprep: WT_g[c*128+k] = bf16(w2[k][c]) (once, not per mlp2 block) ----------------
__global__ __launch_bounds__(256) void k_wprep(const float* __restrict__ w2, short* __restrict__ wtg) {
  int t = blockIdx.x*256 + threadIdx.x;   // grid 64 -> 16384
  int c = t >> 7, k = t & 127;
  wtg[c*128 + k] = f2bf(w2[k*128 + c]);
}

// ---------------- ssq1 (same dot64v ordering as knn2 for exact self-distance) ----------------
__global__ __launch_bounds__(256) void k_ssq1(const float* __restrict__ x1, float* __restrict__ ssq1) {
  int i = blockIdx.x*256 + threadIdx.x;
  alignas(16) float f[64];
  #pragma unroll
  for (int d4 = 0; d4 < 16; ++d4) ((float4*)f)[d4] = ((const float4*)x1)[i*16 + d4];
  ssq1[i] = dot64v(f, (const float4*)f);
}

// ---------------- knn2: per-batch knn over 2048 points in 64-d ----------------
__global__ __launch_bounds__(256) void k_knn2(const float* __restrict__ x1, const float* __restrict__ ssq1,
                                              int* __restrict__ idx2) {
  __shared__ __align__(16) float tf[128][68];   // pad 68 -> conflict-light reads
  __shared__ float tq[128];
  int t = threadIdx.x;
  int row = blockIdx.x*32 + (t>>3);
  int lane = t & 7;
  int cbase = (row >> 11) << 11;                // batch column base
  alignas(16) float fi[64];
  #pragma unroll
  for (int d4 = 0; d4 < 16; ++d4) ((float4*)fi)[d4] = ((const float4*)x1)[row*16 + d4];
  float sqi = ssq1[row];
  float rd[32]; int ri[32];
  #pragma unroll
  for (int s = 0; s < 32; ++s) { rd[s] = INFINITY; ri[s] = 0; }
  for (int tile = 0; tile < 16; ++tile) {
    int base = cbase + tile*128;
    __syncthreads();
    for (int v = t; v < 128*16; v += 256) {
      int jl = v >> 4, d4 = v & 15;
      *(float4*)&tf[jl][d4*4] = ((const float4*)x1)[(base+jl)*16 + d4];
    }
    if (t < 128) tq[t] = ssq1[base + t];
    __syncthreads();
    float bd[16]; int bix[16];
    #pragma unroll
    for (int u = 0; u < 16; ++u) {
      int jl = u*8 + lane;
      bd[u] = (sqi - 2.f*dot64v(fi, (const float4*)&tf[jl][0])) + tq[jl];
      bix[u] = base + jl;
    }
    sort16(bd, bix);
    merge16(rd, ri, bd, bix);
  }
  mergelane(rd, ri, 1);
  mergelane(rd, ri, 2);
  mergelane(rd, ri, 4);
  if (lane == 0) {
    int4* p = (int4*)&idx2[row*KNB];
    p[0] = make_int4(ri[0],ri[1],ri[2],ri[3]);
    p[1] = make_int4(ri[4],ri[5],ri[6],ri[7]);
    p[2] = make_int4(ri[8],ri[9],ri[10],ri[11]);
    p[3] = make_int4(ri[12],ri[13],ri[14],ri[15]);
    p[4] = make_int4(ri[16],ri[17],ri[18],ri[19]);
  }
}

// ---------------- mlp2: edge MLP 128->128 via bf16 MFMA (fp32 accum) ----------------
// 4 points/block (each padded to 32 edge-rows), 4 waves; wave w owns output cols
// [w*32, w*32+32). E staged in LDS bf16 (136-short pitch); B-frags loaded
// DIRECTLY from global WT_g (L2-resident 32 KB, once per wave) -> no W staging,
// no transpose conflicts, LDS 70->35 KB (4 blocks/CU).
__global__ __launch_bounds__(256) void k_mlp2(const float* __restrict__ x1, const int* __restrict__ idx2,
                                              const short* __restrict__ wtg, const float* __restrict__ b2,
                                              float* __restrict__ xmx, float* __restrict__ xmn,
                                              float* __restrict__ sums) {
  __shared__ __align__(16) short Elds[4*32*136];  // [p][row][k]
  __shared__ int js[4][KNB];
  int t = threadIdx.x;
  if (t < 4*KNB) js[t/KNB][t%KNB] = idx2[blockIdx.x*4*KNB + t];
  __syncthreads();
  // stage E (bf16): 4 pts x 32 rows x 16 chunks of 8 values
  #pragma unroll
  for (int cc = 0; cc < 8; ++cc) {
    int v = t + cc*256;
    int p  = v >> 9;
    int rr = (v >> 4) & 31;
    int kc = v & 15;
    short8 outv = {0,0,0,0,0,0,0,0};
    if (rr < KNB) {
      int i = blockIdx.x*4 + p;
      float4 a0, a1;
      if (kc < 8) {
        a0 = ((const float4*)x1)[i*16 + kc*2];
        a1 = ((const float4*)x1)[i*16 + kc*2 + 1];
      } else {
        int j = js[p][rr];
        int kk = kc - 8;
        float4 j0 = ((const float4*)x1)[j*16 + kk*2];
        float4 j1 = ((const float4*)x1)[j*16 + kk*2 + 1];
        float4 i0 = ((const float4*)x1)[i*16 + kk*2];
        float4 i1 = ((const float4*)x1)[i*16 + kk*2 + 1];
        a0 = make_float4(j0.x-i0.x, j0.y-i0.y, j0.z-i0.z, j0.w-i0.w);
        a1 = make_float4(j1.x-i1.x, j1.y-i1.y, j1.z-i1.z, j1.w-i1.w);
      }
      outv[0]=f2bf(a0.x); outv[1]=f2bf(a0.y); outv[2]=f2bf(a0.z); outv[3]=f2bf(a0.w);
      outv[4]=f2bf(a1.x); outv[5]=f2bf(a1.y); outv[6]=f2bf(a1.z); outv[7]=f2bf(a1.w);
    }
    *(short8*)&Elds[p*4352 + rr*136 + kc*8] = outv;
  }
  __syncthreads();
  // compute
  int w = t >> 6, l = t & 63;
  int colA = w*32 + (l & 15);
  int colB = colA + 16;
  short8 bf[2][4];
  #pragma unroll
  for (int n = 0; n < 2; ++n)
    #pragma unroll
    for (int kb = 0; kb < 4; ++kb) {
      int col = w*32 + n*16 + (l & 15);
      int k0 = kb*32 + (l >> 4)*8;
      bf[n][kb] = *(const short8*)&wtg[col*128 + k0];
    }
  float bc0 = b2[colA], bc1 = b2[colB];
  float sT0=0.f, qT0=0.f, sT1=0.f, qT1=0.f;
  #pragma unroll
  for (int p = 0; p < 4; ++p) {
    int i = blockIdx.x*4 + p;
    float mx0=-INFINITY, mn0=INFINITY, s0=0.f, q0=0.f;
    float mx1=-INFINITY, mn1=INFINITY, s1=0.f, q1=0.f;
    #pragma unroll
    for (int m = 0; m < 2; ++m) {
      short8 af[4];
      #pragma unroll
      for (int kb = 0; kb < 4; ++kb) {
        int row = m*16 + (l & 15);
        int k0 = kb*32 + (l >> 4)*8;
        af[kb] = *(short8*)&Elds[p*4352 + row*136 + k0];
      }
      f32x4 acc0 = {0.f,0.f,0.f,0.f};
      f32x4 acc1 = {0.f,0.f,0.f,0.f};
      #pragma unroll
      for (int kb = 0; kb < 4; ++kb) {
        acc0 = __builtin_amdgcn_mfma_f32_16x16x32_bf16(af[kb], bf[0][kb], acc0, 0, 0, 0);
        acc1 = __builtin_amdgcn_mfma_f32_16x16x32_bf16(af[kb], bf[1][kb], acc1, 0, 0, 0);
      }
      int rbase = (l >> 4)*4 + m*16;
      #pragma unroll
      for (int reg = 0; reg < 4; ++reg) {
        bool valid = (rbase + reg) < KNB;
        float h0 = fmaxf(acc0[reg] + bc0, 0.f);
        float h1 = fmaxf(acc1[reg] + bc1, 0.f);
        if (valid) {
          mx0 = fmaxf(mx0, h0); mn0 = fminf(mn0, h0); s0 += h0; q0 += h0*h0;
          mx1 = fmaxf(mx1, h1); mn1 = fminf(mn1, h1); s1 += h1; q1 += h1*h1;
        }
      }
    }
    // butterfly over the 4 lane-groups sharing each col
    #pragma unroll
    for (int dlt = 16; dlt <= 32; dlt <<= 1) {
      mx0 = fmaxf(mx0, __shfl_xor(mx0, dlt)); mn0 = fminf(mn0, __shfl_xor(mn0, dlt));
      s0 += __shfl_xor(s0, dlt);              q0 += __shfl_xor(q0, dlt);
      mx1 = fmaxf(mx1, __shfl_xor(mx1, dlt)); mn1 = fminf(mn1, __shfl_xor(mn1, dlt));
      s1 += __shfl_xor(s1, dlt);              q1 += __shfl_xor(q1, dlt);
    }
    if (l < 16) {
      xmx[i*128 + colA] = mx0; xmx[i*128 + colB] = mx1;
      xmn[i*128 + colA] = mn0; xmn[i*128 + colB] = mn1;
    }
    sT0 += s0; qT0 += q0; sT1 += s1; qT1 += q1;
  }
  if (l < 16) {
    atomicAdd(&sums[colA], sT0);       atomicAdd(&sums[colB], sT1);
    atomicAdd(&sums[128 + colA], qT0); atomicAdd(&sums[128 + colB], qT1);
  }
}

// ---------------- bn2 apply ----------------
__global__ __launch_bounds__(256) void k_bn2apply(const float* __restrict__ sums, const float* __restrict__ g,
                                                  const float* __restrict__ be, const float* __restrict__ xmx,
                                                  const float* __restrict__ xmn, float* __restrict__ x2) {
  __shared__ float sc_s[128], sh_s[128];
  int t = threadIdx.x;
  if (t < 128) {
    float m = sums[t] * (1.f/327680.f);
    float v = sums[128+t] * (1.f/327680.f) - m*m;
    float sc = g[t] / sqrtf(v + 1e-5f);
    sc_s[t] = sc; sh_s[t] = be[t] - m*sc;
  }
  __syncthreads();
  int c = t & 127;
  int i = blockIdx.x*2 + (t>>7);
  float sc = sc_s[c], sh = sh_s[c];
  float val = (sc >= 0.f) ? xmx[i*128+c] : xmn[i*128+c];
  x2[i*128+c] = sc*val + sh;
}

// ---------------- gemmF: relu([x1|x2] @ wf + bf); channel sums + per-batch max/min only ----------------
__global__ __launch_bounds__(256) void k_gemmF(const float* __restrict__ x1, const float* __restrict__ x2,
                                               const float* __restrict__ wf, const float* __restrict__ bf,
                                               float* __restrict__ sumsF, unsigned* __restrict__ hpmx,
                                               unsigned* __restrict__ hpmn) {
  __shared__ float A_s[64*193];
  __shared__ __align__(16) float B_s[192*64];
  __shared__ float red[1024];
  int t = threadIdx.x;
  int rt = blockIdx.x >> 2;
  int ct = blockIdx.x & 3;
  for (int v = t; v < 64*48; v += 256) {
    int r = v / 48, gg = v - r*48;
    int row = rt*64 + r;
    float4 e = (gg < 16) ? ((const float4*)x1)[row*16 + gg]
                         : ((const float4*)x2)[row*32 + (gg-16)];
    float* p = &A_s[r*193 + gg*4];
    p[0]=e.x; p[1]=e.y; p[2]=e.z; p[3]=e.w;
  }
  for (int v = t; v < 192*16; v += 256) {
    int d = v >> 4, c4 = v & 15;
    *(float4*)&B_s[d*64 + c4*4] = ((const float4*)wf)[d*64 + ct*16 + c4];
  }
  __syncthreads();
  int rg = t & 15, cg = t >> 4;
  float acc[4][4];
  #pragma unroll
  for (int a=0;a<4;a++) { acc[a][0]=0.f; acc[a][1]=0.f; acc[a][2]=0.f; acc[a][3]=0.f; }
  for (int d = 0; d < 192; ++d) {
    float a0 = A_s[(rg*4+0)*193 + d];
    float a1 = A_s[(rg*4+1)*193 + d];
    float a2 = A_s[(rg*4+2)*193 + d];
    float a3 = A_s[(rg*4+3)*193 + d];
    float b0 = B_s[d*64 + cg];
    float b1 = B_s[d*64 + cg + 16];
    float b2 = B_s[d*64 + cg + 32];
    float b3 = B_s[d*64 + cg + 48];
    acc[0][0]+=a0*b0; acc[0][1]+=a0*b1; acc[0][2]+=a0*b2; acc[0][3]+=a0*b3;
    acc[1][0]+=a1*b0; acc[1][1]+=a1*b1; acc[1][2]+=a1*b2; acc[1][3]+=a1*b3;
    acc[2][0]+=a2*b0; acc[2][1]+=a2*b1; acc[2][2]+=a2*b2; acc[2][3]+=a2*b3;
    acc[3][0]+=a3*b0; acc[3][1]+=a3*b1; acc[3][2]+=a3*b2; acc[3][3]+=a3*b3;
  }
  float hv[4][4];
  #pragma unroll
  for (int ss=0; ss<4; ++ss) {
    float bb = bf[ct*64 + cg + ss*16];
    #pragma unroll
    for (int rr=0; rr<4; ++rr) hv[rr][ss] = fmaxf(acc[rr][ss] + bb, 0.f);
  }
  int b = rt >> 5;
  #pragma unroll
  for (int ss=0; ss<4; ++ss) red[rg*64 + cg + ss*16] = hv[0][ss]+hv[1][ss]+hv[2][ss]+hv[3][ss];
  __syncthreads();
  if (t < 64) {
    float v = 0.f;
    #pragma unroll
    for (int r=0;r<16;r++) v += red[r*64 + t];
    atomicAdd(&sumsF[ct*64 + t], v);
  }
  __syncthreads();
  #pragma unroll
  for (int ss=0; ss<4; ++ss) red[rg*64 + cg + ss*16] =
      hv[0][ss]*hv[0][ss]+hv[1][ss]*hv[1][ss]+hv[2][ss]*hv[2][ss]+hv[3][ss]*hv[3][ss];
  __syncthreads();
  if (t < 64) {
    float v = 0.f;
    #pragma unroll
    for (int r=0;r<16;r++) v += red[r*64 + t];
    atomicAdd(&sumsF[256 + ct*64 + t], v);
  }
  __syncthreads();
  #pragma unroll
  for (int ss=0; ss<4; ++ss) red[rg*64 + cg + ss*16] =
      fmaxf(fmaxf(hv[0][ss],hv[1][ss]), fmaxf(hv[2][ss],hv[3][ss]));
  __syncthreads();
  if (t < 64) {
    float v = -INFINITY;
    #pragma unroll
    for (int r=0;r<16;r++) v = fmaxf(v, red[r*64 + t]);
    atomicMax(&hpmx[b*256 + ct*64 + t], __float_as_uint(v));
  }
  __syncthreads();
  #pragma unroll
  for (int ss=0; ss<4; ++ss) red[rg*64 + cg + ss*16] =
      fminf(fminf(hv[0][ss],hv[1][ss]), fminf(hv[2][ss],hv[3][ss]));
  __syncthreads();
  if (t < 64) {
    float v = INFINITY;
    #pragma unroll
    for (int r=0;r<16;r++) v = fminf(v, red[r*64 + t]);
    atomicMin(&hpmn[b*256 + ct*64 + t], __float_as_uint(v));
  }
}

// ---------------- head ----------------
__global__ __launch_bounds__(256) void k_head(const float* __restrict__ sumsF, const float* __restrict__ gf,
                                              const float* __restrict__ bef,
                                              const unsigned* __restrict__ hpmx, const unsigned* __restrict__ hpmn,
                                              const float* __restrict__ wo1, const float* __restrict__ bo1,
                                              const float* __restrict__ go1, const float* __restrict__ beo1,
                                              const float* __restrict__ wo2, const float* __restrict__ bo2,
                                              const float* __restrict__ go2, const float* __restrict__ beo2,
                                              const float* __restrict__ wo3, const float* __restrict__ bo3,
                                              float* __restrict__ out) {
  __shared__ float hp[8][256];
  __shared__ float u1[8][128];
  __shared__ float u2[8][64];
  __shared__ float lg[8][16];
  int t = threadIdx.x;
  {
    float m = sumsF[t] * (1.f/16384.f);
    float v = sumsF[256+t] * (1.f/16384.f) - m*m;
    float sc = gf[t] / sqrtf(v + 1e-5f);
    float sh = bef[t] - m*sc;
    for (int b = 0; b < 8; ++b) {
      unsigned bits = (sc >= 0.f) ? hpmx[b*256+t] : hpmn[b*256+t];
      hp[b][t] = sc*__uint_as_float(bits) + sh;
    }
  }
  __syncthreads();
  for (int p = t; p < 1024; p += 256) {
    int b = p >> 7, c = p & 127;
    float z = bo1[c];
    for (int d = 0; d < 256; ++d) z += hp[b][d]*wo1[d*128+c];
    u1[b][c] = fmaxf(z, 0.f);
  }
  __syncthreads();
  if (t < 128) {
    float m = 0.f;
    for (int b=0;b<8;b++) m += u1[b][t];
    m *= 0.125f;
    float v = 0.f;
    for (int b=0;b<8;b++) { float dd = u1[b][t]-m; v += dd*dd; }
    v *= 0.125f;
    float sc = go1[t]/sqrtf(v+1e-5f), sh = beo1[t]-m*sc;
    for (int b=0;b<8;b++) u1[b][t] = sc*u1[b][t]+sh;
  }
  __syncthreads();
  for (int p = t; p < 512; p += 256) {
    int b = p >> 6, c = p & 63;
    float z = bo2[c];
    for (int d = 0; d < 128; ++d) z += u1[b][d]*wo2[d*64+c];
    u2[b][c] = fmaxf(z, 0.f);
  }
  __syncthreads();
  if (t < 64) {
    float m = 0.f;
    for (int b=0;b<8;b++) m += u2[b][t];
    m *= 0.125f;
    float v = 0.f;
    for (int b=0;b<8;b++) { float dd = u2[b][t]-m; v += dd*dd; }
    v *= 0.125f;
    float sc = go2[t]/sqrtf(v+1e-5f), sh = beo2[t]-m*sc;
    for (int b=0;b<8;b++) u2[b][t] = sc*u2[b][t]+sh;
  }
  __syncthreads();
  if (t < 128) {
    int b = t >> 4, c = t & 15;
    float z = bo3[c];
    for (int d = 0; d < 64; ++d) z += u2[b][d]*wo3[d*16+c];
    lg[b][c] = z;
  }
  __syncthreads();
  if (t < 8) {
    float m = -INFINITY;
    for (int j=0;j<16;j++) m = fmaxf(m, lg[t][j]);
    float s = 0.f;
    for (int j=0;j<16;j++) s += expf(lg[t][j]-m);
    float ls = logf(s);
    for (int j=0;j<16;j++) out[t*16+j] = (lg[t][j]-m) - ls;
  }
}

// ---------------- launch ----------------
extern "C" void kernel_launch(void* const* d_in, const int* in_sizes, int n_in,
                              void* d_out, int out_size, void* d_ws, size_t ws_size,
                              hipStream_t stream) {
  (void)in_sizes; (void)n_in; (void)out_size; (void)ws_size;
  const float* pos = (const float*)d_in[0];
  const float* x   = (const float*)d_in[1];
  const float* w1  = (const float*)d_in[3];
  const float* b1  = (const float*)d_in[4];
  const float* g1  = (const float*)d_in[5];
  const float* be1 = (const float*)d_in[6];
  const float* w2  = (const float*)d_in[7];
  const float* b2  = (const float*)d_in[8];
  const float* g2  = (const float*)d_in[9];
  const float* be2 = (const float*)d_in[10];
  const float* wf  = (const float*)d_in[11];
  const float* bf  = (const float*)d_in[12];
  const float* gf  = (const float*)d_in[13];
  const float* bef = (const float*)d_in[14];
  const float* wo1 = (const float*)d_in[15];
  const float* bo1 = (const float*)d_in[16];
  const float* go1 = (const float*)d_in[17];
  const float* beo1= (const float*)d_in[18];
  const float* wo2 = (const float*)d_in[19];
  const float* bo2 = (const float*)d_in[20];
  const float* go2 = (const float*)d_in[21];
  const float* beo2= (const float*)d_in[22];
  const float* wo3 = (const float*)d_in[23];
  const float* bo3 = (const float*)d_in[24];

  char* ws = (char*)d_ws;
  float4*   f0    = (float4*)  (ws + OFF_F0);
  float*    ssq0  = (float*)   (ws + OFF_SSQ0);
  int*      idx1  = (int*)     (ws + OFF_IDX1);
  float*    xmx1  = (float*)   (ws + OFF_XMX1);
  float*    xmn1  = (float*)   (ws + OFF_XMN1);
  float*    sum1  = (float*)   (ws + OFF_SUM1);
  float*    x1    = (float*)   (ws + OFF_X1);
  float*    ssq1  = (float*)   (ws + OFF_SSQ1);
  int*      idx2  = (int*)     (ws + OFF_IDX2);
  float*    xmx2  = (float*)   (ws + OFF_XMX2);
  float*    xmn2  = (float*)   (ws + OFF_XMN2);
  float*    sum2  = (float*)   (ws + OFF_SUM2);
  float*    x2    = (float*)   (ws + OFF_X2);
  float*    sumF  = (float*)   (ws + OFF_SUMF);
  unsigned* hpmx  = (unsigned*)(ws + OFF_HPMX);
  unsigned* hpmn  = (unsigned*)(ws + OFF_HPMN);
  short*    wtg   = (short*)   (ws + OFF_XMX1);   // aliases xmx1 (dead after bn1apply)

  k_init    <<<8,    256, 0, stream>>>(sum1, sum2, sumF, hpmx, hpmn);
  k_f0      <<<64,   256, 0, stream>>>(pos, x, f0, ssq0);
  k_knn1    <<<2048, 256, 0, stream>>>(f0, ssq0, idx1);
  k_mlp1    <<<512,  256, 0, stream>>>(f0, idx1, w1, b1, xmx1, xmn1, sum1);
  k_bn1apply<<<4096, 256, 0, stream>>>(sum1, g1, be1, xmx1, xmn1, x1);
  k_wprep   <<<64,   256, 0, stream>>>(w2, wtg);
  k_ssq1    <<<64,   256, 0, stream>>>(x1, ssq1);
  k_knn2    <<<512,  256, 0, stream>>>(x1, ssq1, idx2);
  k_mlp2    <<<4096, 256, 0, stream>>>(x1, idx2, wtg, b2, xmx2, xmn2, sum2);
  k_bn2apply<<<8192, 256, 0, stream>>>(sum2, g2, be2, xmx2, xmn2, x2);
  k_gemmF   <<<1024, 256, 0, stream>>>(x1, x2, wf, bf, sumF, hpmx, hpmn);
  k_head    <<<1,    256, 0, stream>>>(sumF, gf, bef, hpmx, hpmn,
                                       wo1, bo1, go1, beo1, wo2, bo2, go2, beo2, wo3, bo3,
                                       (float*)d_out);
}

// Round 9
// 671.008 us; speedup vs baseline: 3.7915x; 1.0176x over previous
//
#include <hip/hip_runtime.h>
#include <math.h>

#define NPTS 16384
#define KNB 20
#define SCAP 512

typedef __attribute__((ext_vector_type(8))) short short8;
typedef __attribute__((ext_vector_type(4))) float f32x4;

// ---------------- workspace layout (bytes, all naturally 256-aligned) ----------------
static const size_t OFF_F0   = 0;                                   // N x float4
static const size_t OFF_SSQ0 = OFF_F0   + (size_t)NPTS*4*4;         // N f32
static const size_t OFF_IDX1 = OFF_SSQ0 + (size_t)NPTS*4;           // N*20 i32
static const size_t OFF_XMX1 = OFF_IDX1 + (size_t)NPTS*KNB*4;       // N*64 f32
static const size_t OFF_XMN1 = OFF_XMX1 + (size_t)NPTS*64*4;        // N*64 f32
static const size_t OFF_SUM1 = OFF_XMN1 + (size_t)NPTS*64*4;        // 128 f32 (sum,sumsq)
static const size_t OFF_X1   = OFF_SUM1 + 512;                      // N*64 f32
static const size_t OFF_SSQ1 = OFF_X1   + (size_t)NPTS*64*4;        // N f32
static const size_t OFF_IDX2 = OFF_SSQ1 + (size_t)NPTS*4;           // N*20 i32 (global idx)
static const size_t OFF_XMX2 = OFF_IDX2 + (size_t)NPTS*KNB*4;       // N*128 f32
static const size_t OFF_XMN2 = OFF_XMX2 + (size_t)NPTS*128*4;       // N*128 f32
static const size_t OFF_SUM2 = OFF_XMN2 + (size_t)NPTS*128*4;       // 256 f32
static const size_t OFF_X2   = OFF_SUM2 + 1024;                     // N*128 f32
static const size_t OFF_SUMF = OFF_X2   + (size_t)NPTS*128*4;       // 512 f32
static const size_t OFF_HPMX = OFF_SUMF + 2048;                     // 8*256 u32 (float bits)
static const size_t OFF_HPMN = OFF_HPMX + 8*256*4;                  // 8*256 u32
// WT_g (bf16 W^T for mlp2, 32 KB) ALIASES x2 head: x2 is dead until bn2apply,
// which runs AFTER mlp2 has consumed wtg. k_init writes it first thing.

// ---------------- helpers ----------------
__device__ __forceinline__ float dot4f(float4 a, float4 b) {
  return a.x*b.x + a.y*b.y + a.z*b.z + a.w*b.w;
}

__device__ __forceinline__ float dot64v(const float* a, const float4* b4) {
  float s = 0.f;
  #pragma unroll
  for (int d4 = 0; d4 < 16; ++d4) {
    float4 b = b4[d4];
    s += a[4*d4+0]*b.x + a[4*d4+1]*b.y + a[4*d4+2]*b.z + a[4*d4+3]*b.w;
  }
  return s;
}

// f32 -> bf16 (RNE)
__device__ __forceinline__ short f2bf(float x) {
  union { float f; unsigned u; } v; v.f = x;
  unsigned r = (v.u + 0x7FFFu + ((v.u >> 16) & 1u)) >> 16;
  return (short)r;
}

// ---------------- branch-free sorting-network top-k machinery (with indices) ----------------
__device__ __forceinline__ void ce(float& a, int& ai, float& b, int& bi) {
  bool sw = b < a;
  float d0 = sw ? b : a;  float d1 = sw ? a : b;
  int   j0 = sw ? bi : ai; int  j1 = sw ? ai : bi;
  a = d0; ai = j0; b = d1; bi = j1;
}

__device__ __forceinline__ void sort16(float (&d)[16], int (&ix)[16]) {
  #pragma unroll
  for (int k = 2; k <= 16; k <<= 1) {
    #pragma unroll
    for (int j = k >> 1; j > 0; j >>= 1) {
      #pragma unroll
      for (int i = 0; i < 16; ++i) {
        int l = i ^ j;
        if (l > i) {
          if ((i & k) == 0) ce(d[i], ix[i], d[l], ix[l]);
          else              ce(d[l], ix[l], d[i], ix[i]);
        }
      }
    }
  }
}

__device__ __forceinline__ void bimerge32(float (&rd)[32], int (&ri)[32]) {
  #pragma unroll
  for (int j = 16; j > 0; j >>= 1) {
    #pragma unroll
    for (int i = 0; i < 32; ++i) {
      int l = i ^ j;
      if (l > i) ce(rd[i], ri[i], rd[l], ri[l]);
    }
  }
}

__device__ __forceinline__ void merge16(float (&rd)[32], int (&ri)[32],
                                        float (&bd)[16], int (&bi)[16]) {
  #pragma unroll
  for (int k = 0; k < 16; ++k) {
    bool sw = bd[15-k] < rd[16+k];
    rd[16+k] = sw ? bd[15-k] : rd[16+k];
    ri[16+k] = sw ? bi[15-k] : ri[16+k];
  }
  bimerge32(rd, ri);
}

__device__ __forceinline__ void mergelane(float (&rd)[32], int (&ri)[32], int mask) {
  float pd[32]; int pi[32];
  #pragma unroll
  for (int s = 0; s < 32; ++s) { pd[s] = __shfl_xor(rd[s], mask); pi[s] = __shfl_xor(ri[s], mask); }
  #pragma unroll
  for (int k = 0; k < 32; ++k) {
    bool sw = pd[31-k] < rd[k];
    rd[k] = sw ? pd[31-k] : rd[k];
    ri[k] = sw ? pi[31-k] : ri[k];
  }
  bimerge32(rd, ri);
}

// ---------------- value-only versions (threshold computation, 2 ops/CE) ----------------
__device__ __forceinline__ void vce(float& a, float& b) {
  float lo = fminf(a, b);
  b = fmaxf(a, b);
  a = lo;
}

__device__ __forceinline__ void vsort16(float (&d)[16]) {
  #pragma unroll
  for (int k = 2; k <= 16; k <<= 1) {
    #pragma unroll
    for (int j = k >> 1; j > 0; j >>= 1) {
      #pragma unroll
      for (int i = 0; i < 16; ++i) {
        int l = i ^ j;
        if (l > i) {
          if ((i & k) == 0) vce(d[i], d[l]);
          else              vce(d[l], d[i]);
        }
      }
    }
  }
}

__device__ __forceinline__ void vbimerge32(float (&rd)[32]) {
  #pragma unroll
  for (int j = 16; j > 0; j >>= 1) {
    #pragma unroll
    for (int i = 0; i < 32; ++i) {
      int l = i ^ j;
      if (l > i) vce(rd[i], rd[l]);
    }
  }
}

__device__ __forceinline__ void vmerge16(float (&rd)[32], float (&bd)[16]) {
  #pragma unroll
  for (int k = 0; k < 16; ++k) rd[16+k] = fminf(rd[16+k], bd[15-k]);
  vbimerge32(rd);
}

__device__ __forceinline__ void vmergelane(float (&rd)[32], int mask) {
  float pd[32];
  #pragma unroll
  for (int s = 0; s < 32; ++s) pd[s] = __shfl_xor(rd[s], mask);
  #pragma unroll
  for (int k = 0; k < 32; ++k) rd[k] = fminf(rd[k], pd[31-k]);
  vbimerge32(rd);
}

// ---------------- init + f0 + wprep fused (grid 64; accumulators reset EVERY launch) ----------------
__global__ __launch_bounds__(256) void k_init(const float* __restrict__ pos, const float* __restrict__ x,
                                              const float* __restrict__ w2,
                                              float4* __restrict__ f0, float* __restrict__ ssq,
                                              short* __restrict__ wtg,
                                              float* sum1, float* sum2, float* sumF,
                                              unsigned* hpmx, unsigned* hpmn) {
  int gt = blockIdx.x*256 + threadIdx.x;   // 0..16383
  float4 f;
  f.x = pos[3*gt+0]; f.y = pos[3*gt+1]; f.z = pos[3*gt+2]; f.w = x[gt];
  f0[gt] = f;
  ssq[gt] = dot4f(f, f);
  { int c = gt >> 7, k = gt & 127; wtg[c*128 + k] = f2bf(w2[k*128 + c]); }
  if (gt < 128) sum1[gt] = 0.f;
  if (gt < 256) sum2[gt] = 0.f;
  if (gt < 512) sumF[gt] = 0.f;
  if (gt < 2048) { hpmx[gt] = 0u; hpmn[gt] = 0x7f800000u; }   // relu>=0 -> uint order == float order
}

// ---------------- knn1 v3: global-direct two-phase exact (no LDS tiles) ----------------
__global__ __launch_bounds__(256) void k_knn1(const float4* __restrict__ f0, const float* __restrict__ ssq,
                                              int* __restrict__ idx1) {
  __shared__ float2 surv[8][SCAP];
  __shared__ int scnt[8];
  __shared__ float rowT[8];
  int t = threadIdx.x;
  int r = t >> 5;
  int lane = t & 31;
  int row = blockIdx.x*8 + r;
  if (t < 8) scnt[t] = 0;
  float4 fi = f0[row];
  float sqi = ssq[row];
  // ---- pass 1: value-only top-32 of sample [0,2048)
  {
    float rd[32];
    #pragma unroll
    for (int s = 0; s < 32; ++s) rd[s] = INFINITY;
    #pragma unroll
    for (int b = 0; b < 4; ++b) {
      float bd[16];
      #pragma unroll
      for (int u = 0; u < 16; ++u) {
        int j = b*512 + u*32 + lane;
        float4 c = f0[j];
        bd[u] = (sqi - 2.f*dot4f(fi, c)) + ssq[j];
      }
      vsort16(bd);
      vmerge16(rd, bd);
    }
    vmergelane(rd, 1); vmergelane(rd, 2); vmergelane(rd, 4);
    vmergelane(rd, 8); vmergelane(rd, 16);
    if (lane == 0) rowT[r] = rd[19];
  }
  __syncthreads();
  // ---- pass 2: candidate-major filter over all 16384
  {
    float4 fr[8]; float sr[8], Tr[8];
    #pragma unroll
    for (int q = 0; q < 8; ++q) {
      fr[q] = f0[blockIdx.x*8 + q];
      sr[q] = ssq[blockIdx.x*8 + q];
      Tr[q] = rowT[q];
    }
    #pragma unroll 4
    for (int k = 0; k < 64; ++k) {
      int j = k*256 + t;
      float4 c = f0[j];
      float cq = ssq[j];
      #pragma unroll
      for (int q = 0; q < 8; ++q) {
        float d = (sr[q] - 2.f*dot4f(fr[q], c)) + cq;
        if (d <= Tr[q]) {
          int slot = atomicAdd(&scnt[q], 1);
          if (slot < SCAP) surv[q][slot] = make_float2(d, __int_as_float(j));
        }
      }
    }
  }
  __syncthreads();
  int n = scnt[r] < SCAP ? scnt[r] : SCAP;
  // ---- pass 3: exact index top-20 of survivors
  float rd[32]; int ri[32];
  #pragma unroll
  for (int s = 0; s < 32; ++s) { rd[s] = INFINITY; ri[s] = 0; }
  {
    float bd[16]; int bix[16];
    #pragma unroll
    for (int u = 0; u < 16; ++u) {
      int s = u*32 + lane;
      if (s < n) { float2 v = surv[r][s]; bd[u] = v.x; bix[u] = __float_as_int(v.y); }
      else       { bd[u] = INFINITY; bix[u] = 0; }
    }
    sort16(bd, bix);
    merge16(rd, ri, bd, bix);
  }
  mergelane(rd, ri, 1); mergelane(rd, ri, 2); mergelane(rd, ri, 4);
  mergelane(rd, ri, 8); mergelane(rd, ri, 16);
  if (lane == 0) {
    int4* p = (int4*)&idx1[row*KNB];
    p[0] = make_int4(ri[0],ri[1],ri[2],ri[3]);
    p[1] = make_int4(ri[4],ri[5],ri[6],ri[7]);
    p[2] = make_int4(ri[8],ri[9],ri[10],ri[11]);
    p[3] = make_int4(ri[12],ri[13],ri[14],ri[15]);
    p[4] = make_int4(ri[16],ri[17],ri[18],ri[19]);
  }
}

// ---------------- mlp1: edge MLP 8->64, relu, per-point max/min (pre-BN), channel sums ----------------
__global__ __launch_bounds__(256) void k_mlp1(const float4* __restrict__ f0, const int* __restrict__ idx1,
                                              const float* __restrict__ w1, const float* __restrict__ b1,
                                              float* __restrict__ xmx, float* __restrict__ xmn,
                                              float* __restrict__ sums) {
  __shared__ float rs[256], rs2[256];
  int t = threadIdx.x;
  int c = t & 63;
  int w = t >> 6;
  float wc[8];
  #pragma unroll
  for (int d = 0; d < 8; ++d) wc[d] = w1[d*64 + c];
  float bc = b1[c];
  float s = 0.f, s2 = 0.f;
  for (int p = 0; p < 8; ++p) {
    int i = blockIdx.x*32 + p*4 + w;
    float4 fi = f0[i];
    float mx = -INFINITY, mn = INFINITY;
    #pragma unroll
    for (int k = 0; k < KNB; ++k) {
      int j = idx1[i*KNB + k];
      float4 fj = f0[j];
      float h = bc + fi.x*wc[0] + fi.y*wc[1] + fi.z*wc[2] + fi.w*wc[3]
                   + (fj.x-fi.x)*wc[4] + (fj.y-fi.y)*wc[5] + (fj.z-fi.z)*wc[6] + (fj.w-fi.w)*wc[7];
      h = fmaxf(h, 0.f);
      mx = fmaxf(mx, h); mn = fminf(mn, h);
      s += h; s2 += h*h;
    }
    xmx[i*64+c] = mx; xmn[i*64+c] = mn;
  }
  rs[t] = s; rs2[t] = s2;
  __syncthreads();
  if (t < 64) {
    atomicAdd(&sums[c],      rs[t]+rs[t+64]+rs[t+128]+rs[t+192]);
    atomicAdd(&sums[64+c],   rs2[t]+rs2[t+64]+rs2[t+128]+rs2[t+192]);
  }
}

// ---------------- bn1 apply: x1 = affine(max or min by scale sign) ----------------
__global__ __launch_bounds__(256) void k_bn1apply(const float* __restrict__ sums, const float* __restrict__ g,
                                                  const float* __restrict__ be, const float* __restrict__ xmx,
                                                  const float* __restrict__ xmn, float* __restrict__ x1) {
  __shared__ float sc_s[64], sh_s[64];
  int t = threadIdx.x;
  if (t < 64) {
    float m = sums[t] * (1.f/327680.f);
    float v = sums[64+t] * (1.f/327680.f) - m*m;
    float sc = g[t] / sqrtf(v + 1e-5f);
    sc_s[t] = sc; sh_s[t] = be[t] - m*sc;
  }
  __syncthreads();
  int c = t & 63;
  int i = blockIdx.x*4 + (t>>6);
  float sc = sc_s[c], sh = sh_s[c];
  float val = (sc >= 0.f) ? xmx[i*64+c] : xmn[i*64+c];
  x1[i*64+c] = sc*val + sh;
}

// ---------------- ssq1 (same dot64v ordering as knn2 for exact self-distance) ----------------
__global__ __launch_bounds__(256) void k_ssq1(const float* __restrict__ x1, float* __restrict__ ssq1) {
  int i = blockIdx.x*256 + threadIdx.x;
  alignas(16) float f[64];
  #pragma unroll
  for (int d4 = 0; d4 < 16; ++d4) ((float4*)f)[d4] = ((const float4*)x1)[i*16 + d4];
  ssq1[i] = dot64v(f, (const float4*)f);
}

// ---------------- knn2: per-batch knn over 2048 points in 64-d ----------------
__global__ __launch_bounds__(256) void k_knn2(const float* __restrict__ x1, const float* __restrict__ ssq1,
                                              int* __restrict__ idx2) {
  __shared__ __align__(16) float tf[128][68];   // pad 68 -> conflict-light reads
  __shared__ float tq[128];
  int t = threadIdx.x;
  int row = blockIdx.x*32 + (t>>3);
  int lane = t & 7;
  int cbase = (row >> 11) << 11;                // batch column base
  alignas(16) float fi[64];
  #pragma unroll
  for (int d4 = 0; d4 < 16; ++d4) ((float4*)fi)[d4] = ((const float4*)x1)[row*16 + d4];
  float sqi = ssq1[row];
  float rd[32]; int ri[32];
  #pragma unroll
  for (int s = 0; s < 32; ++s) { rd[s] = INFINITY; ri[s] = 0; }
  for (int tile = 0; tile < 16; ++tile) {
    int base = cbase + tile*128;
    __syncthreads();
    for (int v = t; v < 128*16; v += 256) {
      int jl = v >> 4, d4 = v & 15;
      *(float4*)&tf[jl][d4*4] = ((const float4*)x1)[(base+jl)*16 + d4];
    }
    if (t < 128) tq[t] = ssq1[base + t];
    __syncthreads();
    float bd[16]; int bix[16];
    #pragma unroll
    for (int u = 0; u < 16; ++u) {
      int jl = u*8 + lane;
      bd[u] = (sqi - 2.f*dot64v(fi, (const float4*)&tf[jl][0])) + tq[jl];
      bix[u] = base + jl;
    }
    sort16(bd, bix);
    merge16(rd, ri, bd, bix);
  }
  mergelane(rd, ri, 1);
  mergelane(rd, ri, 2);
  mergelane(rd, ri, 4);
  if (lane == 0) {
    int4* p = (int4*)&idx2[row*KNB];
    p[0] = make_int4(ri[0],ri[1],ri[2],ri[3]);
    p[1] = make_int4(ri[4],ri[5],ri[6],ri[7]);
    p[2] = make_int4(ri[8],ri[9],ri[10],ri[11]);
    p[3] = make_int4(ri[12],ri[13],ri[14],ri[15]);
    p[4] = make_int4(ri[16],ri[17],ri[18],ri[19]);
  }
}

// ---------------- mlp2: edge MLP 128->128, shared-xi decomposition ----------------
// e = [x_i | x_j - x_i]: the xi-half of e.W is IDENTICAL for all 20 rows of a
// point -> compute vi[p][c] = b2[c] + xi.W_top[c] once in exact fp32, init the
// MFMA accumulator with it, and run bf16 MFMA only over the 64 diff dims.
// Halves MFMA count + E staging (LDS ~22 KB -> ~7 blocks/CU); numerics
// strictly better than R8 (xi-half now exact).
__global__ __launch_bounds__(256) void k_mlp2(const float* __restrict__ x1, const int* __restrict__ idx2,
                                              const short* __restrict__ wtg, const float* __restrict__ w2,
                                              const float* __restrict__ b2,
                                              float* __restrict__ xmx, float* __restrict__ xmn,
                                              float* __restrict__ sums) {
  __shared__ __align__(16) short Elds[4*32*72];   // diffs only: [p][row][k<64], pitch 72
  __shared__ float xi_s[4][64];
  __shared__ float vi[4][128];
  __shared__ int js[4][KNB];
  int t = threadIdx.x;
  if (t < 4*KNB) js[t/KNB][t%KNB] = idx2[blockIdx.x*4*KNB + t];
  {
    int p = t >> 6, k = t & 63;
    xi_s[p][k] = x1[(blockIdx.x*4 + p)*64 + k];
  }
  __syncthreads();
  // vi[p][c] = b2[c] + sum_{k<64} xi[k]*w2[k][c]  (fp32 exact top-half + bias)
  #pragma unroll
  for (int v2 = 0; v2 < 2; ++v2) {
    int v = t + v2*256;
    int p = v >> 7, c = v & 127;
    float a = b2[c];
    #pragma unroll 8
    for (int k = 0; k < 64; ++k) a += xi_s[p][k] * w2[k*128 + c];
    vi[p][c] = a;
  }
  // stage E diffs (bf16): 4 pts x 32 rows x 8 chunks of 8
  #pragma unroll
  for (int cc = 0; cc < 4; ++cc) {
    int v = t + cc*256;
    int p  = v >> 8;
    int rr = (v >> 3) & 31;
    int kc = v & 7;
    short8 outv = {0,0,0,0,0,0,0,0};
    if (rr < KNB) {
      int j = js[p][rr];
      float4 j0 = ((const float4*)x1)[j*16 + kc*2];
      float4 j1 = ((const float4*)x1)[j*16 + kc*2 + 1];
      const float* xp = &xi_s[p][kc*8];
      outv[0]=f2bf(j0.x-xp[0]); outv[1]=f2bf(j0.y-xp[1]); outv[2]=f2bf(j0.z-xp[2]); outv[3]=f2bf(j0.w-xp[3]);
      outv[4]=f2bf(j1.x-xp[4]); outv[5]=f2bf(j1.y-xp[5]); outv[6]=f2bf(j1.z-xp[6]); outv[7]=f2bf(j1.w-xp[7]);
    }
    *(short8*)&Elds[p*2304 + rr*72 + kc*8] = outv;
  }
  __syncthreads();
  // compute: wave w owns cols [w*32, w*32+32); B-frags from global wtg (bottom half)
  int w = t >> 6, l = t & 63;
  int colA = w*32 + (l & 15);
  int colB = colA + 16;
  short8 bfr[2][2];
  #pragma unroll
  for (int n = 0; n < 2; ++n)
    #pragma unroll
    for (int kb = 0; kb < 2; ++kb) {
      int col = w*32 + n*16 + (l & 15);
      int k0 = 64 + kb*32 + (l >> 4)*8;
      bfr[n][kb] = *(const short8*)&wtg[col*128 + k0];
    }
  float sT0=0.f, qT0=0.f, sT1=0.f, qT1=0.f;
  #pragma unroll
  for (int p = 0; p < 4; ++p) {
    int i = blockIdx.x*4 + p;
    float vA = vi[p][colA], vB = vi[p][colB];
    float mx0=-INFINITY, mn0=INFINITY, s0=0.f, q0=0.f;
    float mx1=-INFINITY, mn1=INFINITY, s1=0.f, q1=0.f;
    #pragma unroll
    for (int m = 0; m < 2; ++m) {
      short8 af[2];
      #pragma unroll
      for (int kb = 0; kb < 2; ++kb) {
        int row = m*16 + (l & 15);
        int k0 = kb*32 + (l >> 4)*8;
        af[kb] = *(short8*)&Elds[p*2304 + row*72 + k0];
      }
      f32x4 acc0 = {vA, vA, vA, vA};
      f32x4 acc1 = {vB, vB, vB, vB};
      #pragma unroll
      for (int kb = 0; kb < 2; ++kb) {
        acc0 = __builtin_amdgcn_mfma_f32_16x16x32_bf16(af[kb], bfr[0][kb], acc0, 0, 0, 0);
        acc1 = __builtin_amdgcn_mfma_f32_16x16x32_bf16(af[kb], bfr[1][kb], acc1, 0, 0, 0);
      }
      int rbase = (l >> 4)*4 + m*16;
      #pragma unroll
      for (int reg = 0; reg < 4; ++reg) {
        bool valid = (rbase + reg) < KNB;
        float h0 = fmaxf(acc0[reg], 0.f);
        float h1 = fmaxf(acc1[reg], 0.f);
        if (valid) {
          mx0 = fmaxf(mx0, h0); mn0 = fminf(mn0, h0); s0 += h0; q0 += h0*h0;
          mx1 = fmaxf(mx1, h1); mn1 = fminf(mn1, h1); s1 += h1; q1 += h1*h1;
        }
      }
    }
    // butterfly over the 4 lane-groups sharing each col
    #pragma unroll
    for (int dlt = 16; dlt <= 32; dlt <<= 1) {
      mx0 = fmaxf(mx0, __shfl_xor(mx0, dlt)); mn0 = fminf(mn0, __shfl_xor(mn0, dlt));
      s0 += __shfl_xor(s0, dlt);              q0 += __shfl_xor(q0, dlt);
      mx1 = fmaxf(mx1, __shfl_xor(mx1, dlt)); mn1 = fminf(mn1, __shfl_xor(mn1, dlt));
      s1 += __shfl_xor(s1, dlt);              q1 += __shfl_xor(q1, dlt);
    }
    if (l < 16) {
      xmx[i*128 + colA] = mx0; xmx[i*128 + colB] = mx1;
      xmn[i*128 + colA] = mn0; xmn[i*128 + colB] = mn1;
    }
    sT0 += s0; qT0 += q0; sT1 += s1; qT1 += q1;
  }
  if (l < 16) {
    atomicAdd(&sums[colA], sT0);       atomicAdd(&sums[colB], sT1);
    atomicAdd(&sums[128 + colA], qT0); atomicAdd(&sums[128 + colB], qT1);
  }
}

// ---------------- bn2 apply ----------------
__global__ __launch_bounds__(256) void k_bn2apply(const float* __restrict__ sums, const float* __restrict__ g,
                                                  const float* __restrict__ be, const float* __restrict__ xmx,
                                                  const float* __restrict__ xmn, float* __restrict__ x2) {
  __shared__ float sc_s[128], sh_s[128];
  int t = threadIdx.x;
  if (t < 128) {
    float m = sums[t] * (1.f/327680.f);
    float v = sums[128+t] * (1.f/327680.f) - m*m;
    float sc = g[t] / sqrtf(v + 1e-5f);
    sc_s[t] = sc; sh_s[t] = be[t] - m*sc;
  }
  __syncthreads();
  int c = t & 127;
  int i = blockIdx.x*2 + (t>>7);
  float sc = sc_s[c], sh = sh_s[c];
  float val = (sc >= 0.f) ? xmx[i*128+c] : xmn[i*128+c];
  x2[i*128+c] = sc*val + sh;
}

// ---------------- gemmF: relu([x1|x2] @ wf + bf); channel sums + per-batch max/min only ----------------
__global__ __launch_bounds__(256) void k_gemmF(const float* __restrict__ x1, const float* __restrict__ x2,
                                               const float* __restrict__ wf, const float* __restrict__ bf,
                                               float* __restrict__ sumsF, unsigned* __restrict__ hpmx,
                                               unsigned* __restrict__ hpmn) {
  __shared__ float A_s[64*193];
  __shared__ __align__(16) float B_s[192*64];
  __shared__ float red[1024];
  int t = threadIdx.x;
  int rt = blockIdx.x >> 2;
  int ct = blockIdx.x & 3;
  for (int v = t; v < 64*48; v += 256) {
    int r = v / 48, gg = v - r*48;
    int row = rt*64 + r;
    float4 e = (gg < 16) ? ((const float4*)x1)[row*16 + gg]
                         : ((const float4*)x2)[row*32 + (gg-16)];
    float* p = &A_s[r*193 + gg*4];
    p[0]=e.x; p[1]=e.y; p[2]=e.z; p[3]=e.w;
  }
  for (int v = t; v < 192*16; v += 256) {
    int d = v >> 4, c4 = v & 15;
    *(float4*)&B_s[d*64 + c4*4] = ((const float4*)wf)[d*64 + ct*16 + c4];
  }
  __syncthreads();
  int rg = t & 15, cg = t >> 4;
  float acc[4][4];
  #pragma unroll
  for (int a=0;a<4;a++) { acc[a][0]=0.f; acc[a][1]=0.f; acc[a][2]=0.f; acc[a][3]=0.f; }
  for (int d = 0; d < 192; ++d) {
    float a0 = A_s[(rg*4+0)*193 + d];
    float a1 = A_s[(rg*4+1)*193 + d];
    float a2 = A_s[(rg*4+2)*193 + d];
    float a3 = A_s[(rg*4+3)*193 + d];
    float b0 = B_s[d*64 + cg];
    float b1 = B_s[d*64 + cg + 16];
    float b2 = B_s[d*64 + cg + 32];
    float b3 = B_s[d*64 + cg + 48];
    acc[0][0]+=a0*b0; acc[0][1]+=a0*b1; acc[0][2]+=a0*b2; acc[0][3]+=a0*b3;
    acc[1][0]+=a1*b0; acc[1][1]+=a1*b1; acc[1][2]+=a1*b2; acc[1][3]+=a1*b3;
    acc[2][0]+=a2*b0; acc[2][1]+=a2*b1; acc[2][2]+=a2*b2; acc[2][3]+=a2*b3;
    acc[3][0]+=a3*b0; acc[3][1]+=a3*b1; acc[3][2]+=a3*b2; acc[3][3]+=a3*b3;
  }
  float hv[4][4];
  #pragma unroll
  for (int ss=0; ss<4; ++ss) {
    float bb = bf[ct*64 + cg + ss*16];
    #pragma unroll
    for (int rr=0; rr<4; ++rr) hv[rr][ss] = fmaxf(acc[rr][ss] + bb, 0.f);
  }
  int b = rt >> 5;
  #pragma unroll
  for (int ss=0; ss<4; ++ss) red[rg*64 + cg + ss*16] = hv[0][ss]+hv[1][ss]+hv[2][ss]+hv[3][ss];
  __syncthreads();
  if (t < 64) {
    float v = 0.f;
    #pragma unroll
    for (int r=0;r<16;r++) v += red[r*64 + t];
    atomicAdd(&sumsF[ct*64 + t], v);
  }
  __syncthreads();
  #pragma unroll
  for (int ss=0; ss<4; ++ss) red[rg*64 + cg + ss*16] =
      hv[0][ss]*hv[0][ss]+hv[1][ss]*hv[1][ss]+hv[2][ss]*hv[2][ss]+hv[3][ss]*hv[3][ss];
  __syncthreads();
  if (t < 64) {
    float v = 0.f;
    #pragma unroll
    for (int r=0;r<16;r++) v += red[r*64 + t];
    atomicAdd(&sumsF[256 + ct*64 + t], v);
  }
  __syncthreads();
  #pragma unroll
  for (int ss=0; ss<4; ++ss) red[rg*64 + cg + ss*16] =
      fmaxf(fmaxf(hv[0][ss],hv[1][ss]), fmaxf(hv[2][ss],hv[3][ss]));
  __syncthreads();
  if (t < 64) {
    float v = -INFINITY;
    #pragma unroll
    for (int r=0;r<16;r++) v = fmaxf(v, red[r*64 + t]);
    atomicMax(&hpmx[b*256 + ct*64 + t], __float_as_uint(v));
  }
  __syncthreads();
  #pragma unroll
  for (int ss=0; ss<4; ++ss) red[rg*64 + cg + ss*16] =
      fminf(fminf(hv[0][ss],hv[1][ss]), fminf(hv[2][ss],hv[3][ss]));
  __syncthreads();
  if (t < 64) {
    float v = INFINITY;
    #pragma unroll
    for (int r=0;r<16;r++) v = fminf(v, red[r*64 + t]);
    atomicMin(&hpmn[b*256 + ct*64 + t], __float_as_uint(v));
  }
}

// ---------------- head ----------------
__global__ __launch_bounds__(256) void k_head(const float* __restrict__ sumsF, const float* __restrict__ gf,
                                              const float* __restrict__ bef,
                                              const unsigned* __restrict__ hpmx, const unsigned* __restrict__ hpmn,
                                              const float* __restrict__ wo1, const float* __restrict__ bo1,
                                              const float* __restrict__ go1, const float* __restrict__ beo1,
                                              const float* __restrict__ wo2, const float* __restrict__ bo2,
                                              const float* __restrict__ go2, const float* __restrict__ beo2,
                                              const float* __restrict__ wo3, const float* __restrict__ bo3,
                                              float* __restrict__ out) {
  __shared__ float hp[8][256];
  __shared__ float u1[8][128];
  __shared__ float u2[8][64];
  __shared__ float lg[8][16];
  int t = threadIdx.x;
  {
    float m = sumsF[t] * (1.f/16384.f);
    float v = sumsF[256+t] * (1.f/16384.f) - m*m;
    float sc = gf[t] / sqrtf(v + 1e-5f);
    float sh = bef[t] - m*sc;
    for (int b = 0; b < 8; ++b) {
      unsigned bits = (sc >= 0.f) ? hpmx[b*256+t] : hpmn[b*256+t];
      hp[b][t] = sc*__uint_as_float(bits) + sh;
    }
  }
  __syncthreads();
  for (int p = t; p < 1024; p += 256) {
    int b = p >> 7, c = p & 127;
    float z = bo1[c];
    for (int d = 0; d < 256; ++d) z += hp[b][d]*wo1[d*128+c];
    u1[b][c] = fmaxf(z, 0.f);
  }
  __syncthreads();
  if (t < 128) {
    float m = 0.f;
    for (int b=0;b<8;b++) m += u1[b][t];
    m *= 0.125f;
    float v = 0.f;
    for (int b=0;b<8;b++) { float dd = u1[b][t]-m; v += dd*dd; }
    v *= 0.125f;
    float sc = go1[t]/sqrtf(v+1e-5f), sh = beo1[t]-m*sc;
    for (int b=0;b<8;b++) u1[b][t] = sc*u1[b][t]+sh;
  }
  __syncthreads();
  for (int p = t; p < 512; p += 256) {
    int b = p >> 6, c = p & 63;
    float z = bo2[c];
    for (int d = 0; d < 128; ++d) z += u1[b][d]*wo2[d*64+c];
    u2[b][c] = fmaxf(z, 0.f);
  }
  __syncthreads();
  if (t < 64) {
    float m = 0.f;
    for (int b=0;b<8;b++) m += u2[b][t];
    m *= 0.125f;
    float v = 0.f;
    for (int b=0;b<8;b++) { float dd = u2[b][t]-m; v += dd*dd; }
    v *= 0.125f;
    float sc = go2[t]/sqrtf(v+1e-5f), sh = beo2[t]-m*sc;
    for (int b=0;b<8;b++) u2[b][t] = sc*u2[b][t]+sh;
  }
  __syncthreads();
  if (t < 128) {
    int b = t >> 4, c = t & 15;
    float z = bo3[c];
    for (int d = 0; d < 64; ++d) z += u2[b][d]*wo3[d*16+c];
    lg[b][c] = z;
  }
  __syncthreads();
  if (t < 8) {
    float m = -INFINITY;
    for (int j=0;j<16;j++) m = fmaxf(m, lg[t][j]);
    float s = 0.f;
    for (int j=0;j<16;j++) s += expf(lg[t][j]-m);
    float ls = logf(s);
    for (int j=0;j<16;j++) out[t*16+j] = (lg[t][j]-m) - ls;
  }
}

// ---------------- launch ----------------
extern "C" void kernel_launch(void* const* d_in, const int* in_sizes, int n_in,
                              void* d_out, int out_size, void* d_ws, size_t ws_size,
                              hipStream_t stream) {
  (void)in_sizes; (void)n_in; (void)out_size; (void)ws_size;
  const float* pos = (const float*)d_in[0];
  const float* x   = (const float*)d_in[1];
  const float* w1  = (const float*)d_in[3];
  const float* b1  = (const float*)d_in[4];
  const float* g1  = (const float*)d_in[5];
  const float* be1 = (const float*)d_in[6];
  const float* w2  = (const float*)d_in[7];
  const float* b2  = (const float*)d_in[8];
  const float* g2  = (const float*)d_in[9];
  const float* be2 = (const float*)d_in[10];
  const float* wf  = (const float*)d_in[11];
  const float* bf  = (const float*)d_in[12];
  const float* gf  = (const float*)d_in[13];
  const float* bef = (const float*)d_in[14];
  const float* wo1 = (const float*)d_in[15];
  const float* bo1 = (const float*)d_in[16];
  const float* go1 = (const float*)d_in[17];
  const float* beo1= (const float*)d_in[18];
  const float* wo2 = (const float*)d_in[19];
  const float* bo2 = (const float*)d_in[20];
  const float* go2 = (const float*)d_in[21];
  const float* beo2= (const float*)d_in[22];
  const float* wo3 = (const float*)d_in[23];
  const float* bo3 = (const float*)d_in[24];

  char* ws = (char*)d_ws;
  float4*   f0    = (float4*)  (ws + OFF_F0);
  float*    ssq0  = (float*)   (ws + OFF_SSQ0);
  int*      idx1  = (int*)     (ws + OFF_IDX1);
  float*    xmx1  = (float*)   (ws + OFF_XMX1);
  float*    xmn1  = (float*)   (ws + OFF_XMN1);
  float*    sum1  = (float*)   (ws + OFF_SUM1);
  float*    x1    = (float*)   (ws + OFF_X1);
  float*    ssq1  = (float*)   (ws + OFF_SSQ1);
  int*      idx2  = (int*)     (ws + OFF_IDX2);
  float*    xmx2  = (float*)   (ws + OFF_XMX2);
  float*    xmn2  = (float*)   (ws + OFF_XMN2);
  float*    sum2  = (float*)   (ws + OFF_SUM2);
  float*    x2    = (float*)   (ws + OFF_X2);
  float*    sumF  = (float*)   (ws + OFF_SUMF);
  unsigned* hpmx  = (unsigned*)(ws + OFF_HPMX);
  unsigned* hpmn  = (unsigned*)(ws + OFF_HPMN);
  short*    wtg   = (short*)   (ws + OFF_X2);    // aliases x2 head (x2 dead until bn2apply)

  k_init    <<<64,   256, 0, stream>>>(pos, x, w2, f0, ssq0, wtg, sum1, sum2, sumF, hpmx, hpmn);
  k_knn1    <<<2048, 256, 0, stream>>>(f0, ssq0, idx1);
  k_mlp1    <<<512,  256, 0, stream>>>(f0, idx1, w1, b1, xmx1, xmn1, sum1);
  k_bn1apply<<<4096, 256, 0, stream>>>(sum1, g1, be1, xmx1, xmn1, x1);
  k_ssq1    <<<64,   256, 0, stream>>>(x1, ssq1);
  k_knn2    <<<512,  256, 0, stream>>>(x1, ssq1, idx2);
  k_mlp2    <<<4096, 256, 0, stream>>>(x1, idx2, wtg, w2, b2, xmx2, xmn2, sum2);
  k_bn2apply<<<8192, 256, 0, stream>>>(sum2, g2, be2, xmx2, xmn2, x2);
  k_gemmF   <<<1024, 256, 0, stream>>>(x1, x2, wf, bf, sumF, hpmx, hpmn);
  k_head    <<<1,    256, 0, stream>>>(sumF, gf, bef, hpmx, hpmn,
                                       wo1, bo1, go1, beo1, wo2, bo2, go2, beo2, wo3, bo3,
                                       (float*)d_out);
}